// Round 9
// baseline (306.786 us; speedup 1.0000x reference)
//
#include <hip/hip_runtime.h>
#include <cstdint>
#include <cstddef>

// ---------------------------------------------------------------------------
// Problem constants: B=2, C=128, D=H=W=32, nh=8, hd=16, L=32
// Tokens: t = b*32768 + d*1024 + h*32 + w   (65536 tokens, 128 channels)
// ---------------------------------------------------------------------------

#define NTOK 65536
#define SPAT 32768

// ws offsets (floats). Same proven map as r7/r8 (136.4 MB).
#define WS_R0     0ull          // 8388608 fp32 (lf)
#define WS_A0     0ull          // 4194304 (8388608 ush)
#define WS_A1     4194304ull    // 4194304
#define WS_MPREB  8388608ull    // 4194304 (8388608 ush)
#define WS_A2     8388608ull    // 4194304 (overlays dead MPREB)
#define WS_XTOKB  12582912ull   // 4194304 (8388608 ush)
#define WS_INT    16777216ull   // 4194304 (8388608 ush): pos_emb bf16 -> x_mod bf16
#define WS_QKVH   20971520ull   // 12582912 (25165824 ush) [h][t][48]
#define WS_CONVP  33554432ull   // 221184 (442368 ush) [tap][dx][ks][l4][co][8]
#define WS_QKVP   33775616ull   // 24576  (49152 ush)
#define WS_WCP    33800192ull   // 8192
#define WS_MODW2P 33808384ull   // 8192
#define WS_PROJP  33816576ull   // 8192
#define WS_BC     33824768ull   // 128
#define WS_RBUF   33824896ull   // 432
#define WS_PS     33825328ull   // 131072
#define WS_PSS    33956400ull   // 131072
#define WS_MU1    34087472ull   // 256
#define WS_RS1    34087728ull   // 256
#define WS_MU2    34087984ull   // 256
#define WS_RS2    34088240ull   // 256
// total 34088496 floats = 136.4 MB

typedef __attribute__((ext_vector_type(8))) short short8;
typedef __attribute__((ext_vector_type(4))) float f32x4;
typedef __attribute__((ext_vector_type(16))) float f32x16;

__device__ __forceinline__ float gelu_f(float x) {
  return 0.5f * x * (1.0f + erff(x * 0.70710678118654752f));
}
__device__ __forceinline__ float sigmoid_f(float x) {
  return 1.0f / (1.0f + expf(-x));
}
__device__ __forceinline__ unsigned short f2bf(float x) {  // RNE f32->bf16
  unsigned int u = __float_as_uint(x);
  unsigned int r = u + 0x7fffu + ((u >> 16) & 1u);
  return (unsigned short)(r >> 16);
}
__device__ __forceinline__ float bf2f(unsigned short u) {
  return __uint_as_float(((unsigned int)u) << 16);
}
// 16 consecutive bf16 -> 16 fp32
__device__ __forceinline__ void bf16x16_load(const unsigned short* p, float* f) {
  const uint4 a = *(const uint4*)p;
  const uint4 b = *(const uint4*)(p + 8);
  const unsigned int w[8] = {a.x, a.y, a.z, a.w, b.x, b.y, b.z, b.w};
  #pragma unroll
  for (int i = 0; i < 8; ++i) {
    f[2 * i] = __uint_as_float(w[i] << 16);
    f[2 * i + 1] = __uint_as_float(w[i] & 0xffff0000u);
  }
}
// async global->LDS, 16B per lane (dest must be wave-uniform base + lane*16)
__device__ __forceinline__ void gload_lds16(const void* g, void* l) {
  __builtin_amdgcn_global_load_lds(
      (const __attribute__((address_space(1))) unsigned int*)g,
      (__attribute__((address_space(3))) unsigned int*)l, 16, 0, 0);
}
__device__ __forceinline__ float dot3(const float* a, const float* b) {
  return a[0] * b[0] + a[1] * b[1] + a[2] * b[2];
}
__device__ __forceinline__ void cross3(const float* a, const float* b, float* c) {
  c[0] = a[1] * b[2] - a[2] * b[1];
  c[1] = a[2] * b[0] - a[0] * b[2];
  c[2] = a[0] * b[1] - a[1] * b[0];
}

// exact port of _r6_to_matrix for one head (6 floats in, 9 out row-major)
__device__ void r6_to_matrix(const float* r6, float* R) {
  float v1[3] = {r6[0], r6[1], r6[2]};
  float n1 = sqrtf(dot3(v1, v1));
  float inv1 = 1.0f / (n1 + 1e-7f);
  v1[0] *= inv1; v1[1] *= inv1; v1[2] *= inv1;
  float v2[3] = {r6[3], r6[4], r6[5]};
  float d = dot3(v2, v1);
  v2[0] -= d * v1[0]; v2[1] -= d * v1[1]; v2[2] -= d * v1[2];
  float n2 = sqrtf(dot3(v2, v2));
  float inv2 = 1.0f / (n2 + 1e-7f);
  v2[0] *= inv2; v2[1] *= inv2; v2[2] *= inv2;
  float v3[3]; cross3(v1, v2, v3);
  float cx[3]; cross3(v2, v3, cx);
  float det = dot3(v1, cx);
  if (det < 0.0f) { v3[0] = -v3[0]; v3[1] = -v3[1]; v3[2] = -v3[2]; }
  R[0] = v1[0]; R[1] = v1[1]; R[2] = v1[2];
  R[3] = v2[0]; R[4] = v2[1]; R[5] = v2[2];
  R[6] = v3[0]; R[7] = v3[1]; R[8] = v3[2];
}

// exact port of _ensure_matrix for one head (9 in row-major, 9 out)
__device__ void ensure_matrix(const float* Rin, float* Ro) {
  float a[3] = {Rin[0] + 1e-6f, Rin[1] + 1e-6f, Rin[2] + 1e-6f};
  float na = fmaxf(sqrtf(dot3(a, a)), 1e-12f);
  float v1[3] = {a[0] / na, a[1] / na, a[2] / na};
  float b0[3] = {Rin[3], Rin[4], Rin[5]};
  float d = dot3(b0, v1);
  float bb[3] = {b0[0] - d * v1[0] + 1e-6f, b0[1] - d * v1[1] + 1e-6f, b0[2] - d * v1[2] + 1e-6f};
  float nb = fmaxf(sqrtf(dot3(bb, bb)), 1e-12f);
  float v2[3] = {bb[0] / nb, bb[1] / nb, bb[2] / nb};
  float v3[3]; cross3(v1, v2, v3);
  float cx[3]; cross3(v2, v3, cx);
  float det = dot3(v1, cx);
  if (det < 0.0f) { v3[0] = -v3[0]; v3[1] = -v3[1]; v3[2] = -v3[2]; }
  float Rn[9] = {v1[0], v1[1], v1[2], v2[0], v2[1], v2[2], v3[0], v3[1], v3[2]};
  float T1[9], T2[9];
  for (int i = 0; i < 3; ++i)
    for (int j = 0; j < 3; ++j) {
      float s = 0.f;
      for (int k = 0; k < 3; ++k) s += Rn[k * 3 + i] * Rn[k * 3 + j];
      T1[i * 3 + j] = s;
    }
  for (int i = 0; i < 3; ++i)
    for (int j = 0; j < 3; ++j) {
      float s = 0.f;
      for (int k = 0; k < 3; ++k) s += T1[i * 3 + k] * Rn[j * 3 + k];
      T2[i * 3 + j] = s;
    }
  for (int i = 0; i < 9; ++i) Ro[i] = 0.5f * (Rn[i] + T2[i]);
}

// y = R_eff x for hd=16 (5 full 3x3 groups + scalar R00 on ch15)
__device__ __forceinline__ void rot16(const float* R, const float* x, float* y) {
  #pragma unroll
  for (int g = 0; g < 5; ++g) {
    float a = x[3 * g], b = x[3 * g + 1], c = x[3 * g + 2];
    y[3 * g + 0] = R[0] * a + R[1] * b + R[2] * c;
    y[3 * g + 1] = R[3] * a + R[4] * b + R[5] * c;
    y[3 * g + 2] = R[6] * a + R[7] * b + R[8] * c;
  }
  y[15] = R[0] * x[15];
}

// ---------------------------------------------------------------------------
// K0: weight packs (+ rotation matrices in block 0)
// ---------------------------------------------------------------------------
__global__ __launch_bounds__(256) void prep_w_kernel(
    const float* __restrict__ lp_w1, const float* __restrict__ qkv_w,
    const float* __restrict__ mod_w1, const float* __restrict__ lp_w2,
    const float* __restrict__ lp_b2, const float* __restrict__ mod_b1,
    const float* __restrict__ mod_w2, const float* __restrict__ proj_w,
    const float* __restrict__ Ad, const float* __restrict__ Ah,
    const float* __restrict__ Aw, const float* __restrict__ Rd,
    const float* __restrict__ Rh, const float* __restrict__ Rw,
    unsigned short* __restrict__ convP, unsigned short* __restrict__ qkvP,
    unsigned short* __restrict__ WcP, unsigned short* __restrict__ modw2P,
    unsigned short* __restrict__ projP, float* __restrict__ bc,
    float* __restrict__ Rbuf) {
  int gid = blockIdx.x * 256 + threadIdx.x;  // 65536 threads
  for (int f = gid; f < 442368; f += 65536) {
    int e = f & 7;
    int co = (f >> 3) & 127;
    int rest = f >> 10;
    int l4 = rest & 3;
    int ks = (rest >> 2) & 3;
    int dxt = rest >> 4;
    int dx = dxt % 3;
    int tap = dxt / 3;
    int dz = tap / 3, dy = tap % 3;
    int ci = ks * 32 + l4 * 8 + e;
    convP[f] = f2bf(lp_w1[(co * 128 + ci) * 27 + dz * 9 + dy * 3 + dx]);
  }
  if (gid < 49152) qkvP[gid] = f2bf(qkv_w[gid]);
  if (gid < 16384) {
    modw2P[gid] = f2bf(mod_w2[gid]);
    projP[gid] = f2bf(proj_w[gid]);
    int o = gid >> 7, i = gid & 127;
    float s = 0.f;
    for (int c = 0; c < 128; ++c) s += mod_w1[o * 128 + c] * lp_w2[c * 128 + i];
    WcP[gid] = f2bf(s);
  }
  if (gid < 128) {
    float s = 0.f;
    for (int c = 0; c < 128; ++c) s += mod_w1[gid * 128 + c] * lp_b2[c];
    bc[gid] = s + mod_b1[gid];
  }
  if (blockIdx.x == 0 && threadIdx.x >= 224 && threadIdx.x < 248) {
    int tid = threadIdx.x - 224;
    int ax = tid >> 3, h = tid & 7;
    const float* A = (ax == 0) ? Ad : ((ax == 1) ? Ah : Aw);
    const float* R = (ax == 0) ? Rd : ((ax == 1) ? Rh : Rw);
    float Rq[9], Rv[9];
    r6_to_matrix(A + h * 6, Rq);
    ensure_matrix(R + h * 9, Rv);
    float* dst = Rbuf + (ax * 8 + h) * 18;
    for (int i = 0; i < 9; ++i) { dst[i] = Rq[i]; dst[9 + i] = Rv[i]; }
  }
}

// ---------------------------------------------------------------------------
// K0c: merged transposes. Per (b,d,h) plane: x -> xtokb bf16, pos_emb -> inT bf16
// ---------------------------------------------------------------------------
__global__ __launch_bounds__(256) void transpose_kernel(const float* __restrict__ x,
                                                        const float* __restrict__ pe,
                                                        unsigned short* __restrict__ xtokb,
                                                        unsigned short* __restrict__ inT) {
  __shared__ float lds[32][132];
  int blk = blockIdx.x;  // b*1024 + d*32 + h
  int b = blk >> 10;
  int dh = blk & 1023;
  int tid = threadIdx.x;
  size_t planebase = ((size_t)b << 22) + ((size_t)dh << 5);
  size_t tb = ((size_t)blk) << 5;
  #pragma unroll
  for (int r = 0; r < 16; ++r) {
    int idx = r * 256 + tid;
    int ci = idx >> 5, w = idx & 31;
    lds[w][ci] = x[planebase + ((size_t)ci << 15) + w];
  }
  __syncthreads();
  #pragma unroll
  for (int r = 0; r < 16; ++r) {
    int idx = r * 256 + tid;
    int w = idx >> 7, ci = idx & 127;
    xtokb[(tb + w) * 128 + ci] = f2bf(lds[w][ci]);
  }
  __syncthreads();
  #pragma unroll
  for (int r = 0; r < 16; ++r) {
    int idx = r * 256 + tid;
    int ci = idx >> 5, w = idx & 31;
    lds[w][ci] = pe[planebase + ((size_t)ci << 15) + w];
  }
  __syncthreads();
  #pragma unroll
  for (int r = 0; r < 16; ++r) {
    int idx = r * 256 + tid;
    int w = idx >> 7, ci = idx & 127;
    inT[(tb + w) * 128 + ci] = f2bf(lds[w][ci]);
  }
}

// ---------------------------------------------------------------------------
// K1: 3x3x3 circular conv via bf16 MFMA, v5.
// Block: 128 tokens (4 h-rows x 32 w) x 128 co; 4 waves 2x2 (64tok x 64co).
// Per-dz staging of a 6-row halo (48KB LDS, global_load_lds, pre-swizzled src),
// 5 barriers total, coalesced B pack, acc 4x4 -> high VGPR for load overlap.
// Fused inorm stats in epilogue.
// ---------------------------------------------------------------------------
__global__ __launch_bounds__(256) void conv_mfma_kernel(
    const unsigned short* __restrict__ inT, const unsigned short* __restrict__ Bp,
    const float* __restrict__ b1, float* __restrict__ out,
    float* __restrict__ ps, float* __restrict__ pss) {
  __shared__ unsigned short Als[24576];  // 48KB: 6 rows x 32 w x 128 ci, swizzled
  __shared__ float sumb[128][2];
  __shared__ float sqb[128][2];
  const int blk = blockIdx.x;             // 512 blocks
  const int b = blk >> 8, d = (blk >> 3) & 31, hg = blk & 7;
  const int h0 = hg << 2;                 // 4 output h-rows
  const int tid = threadIdx.x;
  const int lane = tid & 63;
  const int wid = tid >> 6;
  const int wm = wid >> 1, wn = wid & 1;
  const int l15 = lane & 15, l4 = lane >> 4;

  f32x4 acc[4][4];
  #pragma unroll
  for (int mt = 0; mt < 4; ++mt)
    #pragma unroll
    for (int nt = 0; nt < 4; ++nt)
      #pragma unroll
      for (int r = 0; r < 4; ++r) acc[mt][nt][r] = 0.f;

  int mw[4], mhh[4];
  #pragma unroll
  for (int mt = 0; mt < 4; ++mt) {
    int m = wm * 64 + mt * 16 + l15;
    mhh[mt] = m >> 5;
    mw[mt] = m & 31;
  }
  const size_t tokbase = ((size_t)b << 15) + ((size_t)d << 10) + ((size_t)h0 << 5);

  // stage 6-row halo (h0-1 .. h0+4) of plane (d+dz-1) -> 48KB
  auto stage = [&](int dz) {
    const int zr = (d + dz + 31) & 31;
    #pragma unroll
    for (int p = 0; p < 12; ++p) {
      const int g = p * 256 + tid;        // 3072 chunks of 16B
      const int tok = g >> 4, gi = g & 15;
      const int r = tok >> 5, w = tok & 31;
      const int yr = (h0 + r + 31) & 31;
      const size_t srcbyte = ((((size_t)b << 15) + ((size_t)zr << 10) + ((size_t)yr << 5) + w) << 8)
                             + (size_t)((gi ^ (w & 7)) << 4);
      gload_lds16((const char*)inT + srcbyte, (char*)Als + (size_t)g * 16);
    }
  };

  auto compute = [&](int dz) {
    #pragma unroll
    for (int dy = 0; dy < 3; ++dy) {
      const int tap = dz * 3 + dy;
      #pragma unroll
      for (int dx = 0; dx < 3; ++dx) {
        int abase[4], asw[4];
        #pragma unroll
        for (int mt = 0; mt < 4; ++mt) {
          const int wsft = (mw[mt] + dx + 31) & 31;
          const int stok = (mhh[mt] + dy) * 32 + wsft;
          abase[mt] = stok * 256;
          asw[mt] = (wsft & 7) << 4;
        }
        #pragma unroll
        for (int ks = 0; ks < 4; ++ks) {
          const int k2 = (ks * 32 + l4 * 8) * 2;
          const int bbase = (((tap * 3 + dx) * 4 + ks) * 4 + l4) * 1024;
          short8 afr[4], bfr[4];
          #pragma unroll
          for (int nt = 0; nt < 4; ++nt) {
            const int co = wn * 64 + nt * 16 + l15;
            bfr[nt] = *(const short8*)(Bp + bbase + co * 8);
          }
          #pragma unroll
          for (int mt = 0; mt < 4; ++mt)
            afr[mt] = *(const short8*)((const char*)Als + abase[mt] + (k2 ^ asw[mt]));
          #pragma unroll
          for (int mt = 0; mt < 4; ++mt)
            #pragma unroll
            for (int nt = 0; nt < 4; ++nt)
              acc[mt][nt] = __builtin_amdgcn_mfma_f32_16x16x32_bf16(afr[mt], bfr[nt],
                                                                    acc[mt][nt], 0, 0, 0);
        }
      }
    }
  };

  for (int dz = 0; dz < 3; ++dz) {
    stage(dz);
    __syncthreads();   // stage complete (drains vmcnt)
    compute(dz);
    if (dz < 2) __syncthreads();  // all reads done before next stage overwrites
  }

  // epilogue: bias + store + fused stats partials
  #pragma unroll
  for (int nt = 0; nt < 4; ++nt) {
    const int co = wn * 64 + nt * 16 + l15;
    const float bias = b1[co];
    float s = 0.f, q = 0.f;
    #pragma unroll
    for (int mt = 0; mt < 4; ++mt) {
      #pragma unroll
      for (int r = 0; r < 4; ++r) {
        const int m = wm * 64 + mt * 16 + l4 * 4 + r;
        const float v = acc[mt][nt][r] + bias;
        out[(tokbase + m) * 128 + co] = v;
        s += v; q += v * v;
      }
    }
    s += __shfl_xor(s, 16); s += __shfl_xor(s, 32);
    q += __shfl_xor(q, 16); q += __shfl_xor(q, 32);
    if (l4 == 0) { sumb[co][wm] = s; sqb[co][wm] = q; }
  }
  __syncthreads();
  if (tid < 128) {
    ps[blk * 128 + tid] = sumb[tid][0] + sumb[tid][1];
    pss[blk * 128 + tid] = sqb[tid][0] + sqb[tid][1];
  }
}

// ---------------------------------------------------------------------------
// K2: stats finalize, parallel
// ---------------------------------------------------------------------------
__global__ __launch_bounds__(64) void stats_final_kernel(
    const float* __restrict__ ps, const float* __restrict__ pss,
    float* __restrict__ mu, float* __restrict__ rs, int nb) {
  const int pair = blockIdx.x;  // b*128 + c
  const int b = pair >> 7, c = pair & 127;
  const int lane = threadIdx.x;
  float s = 0.f, ss = 0.f;
  for (int j = lane; j < nb; j += 64) {
    const int idx = ((b * nb + j) << 7) + c;
    s += ps[idx];
    ss += pss[idx];
  }
  #pragma unroll
  for (int o = 32; o > 0; o >>= 1) {
    s += __shfl_xor(s, o);
    ss += __shfl_xor(ss, o);
  }
  if (lane == 0) {
    float m = s * (1.0f / 32768.0f);
    float v = ss * (1.0f / 32768.0f) - m * m;
    mu[pair] = m;
    rs[pair] = rsqrtf(v + 1e-5f);
  }
}

// ---------------------------------------------------------------------------
// K3: 1x1 GEMM via bf16 MFMA, register-only (r7 proven).
// ---------------------------------------------------------------------------
template <int PRE, int AB16, int POST, int STATS>
__global__ __launch_bounds__(256) void gemm_mfma_kernel(
    const void* __restrict__ Avoid, const unsigned short* __restrict__ Wp,
    const float* __restrict__ bias, void* __restrict__ Yvoid, int O,
    const float* __restrict__ mu, const float* __restrict__ rs,
    const unsigned short* __restrict__ xtb, float* __restrict__ ps,
    float* __restrict__ pss) {
  __shared__ float sumb[128][2];
  __shared__ float sqb[128][2];
  const int tid = threadIdx.x;
  const int lane = tid & 63, wid = tid >> 6;
  const int wm = wid >> 1, wn = wid & 1;
  const int l15 = lane & 15, l4 = lane >> 4;
  const int og = blockIdx.x * 128;
  const int t0 = blockIdx.y * 128;
  const int bidx = t0 >> 15;
  const float* Af = (const float*)Avoid;
  const unsigned short* Ab = (const unsigned short*)Avoid;
  float* Yf = (float*)Yvoid;
  unsigned short* Yb = (unsigned short*)Yvoid;

  f32x4 acc[4][4];
  #pragma unroll
  for (int mt = 0; mt < 4; ++mt)
    #pragma unroll
    for (int nt = 0; nt < 4; ++nt)
      #pragma unroll
      for (int r = 0; r < 4; ++r) acc[mt][nt][r] = 0.f;

  #pragma unroll
  for (int ks = 0; ks < 4; ++ks) {
    const int kb = ks * 32 + l4 * 8;
    short8 a[4], bfr[4];
    float4 m0, m1, r0, r1;
    if constexpr (PRE == 1) {
      m0 = *(const float4*)(mu + bidx * 128 + kb);
      m1 = *(const float4*)(mu + bidx * 128 + kb + 4);
      r0 = *(const float4*)(rs + bidx * 128 + kb);
      r1 = *(const float4*)(rs + bidx * 128 + kb + 4);
    }
    #pragma unroll
    for (int mt = 0; mt < 4; ++mt) {
      const int tok = t0 + wm * 64 + mt * 16 + l15;
      float v[16];
      bool have = false;
      if constexpr (AB16 == 1) {
        if constexpr (PRE == 1) {
          bf16x16_load(Ab + (size_t)tok * 128 + kb, v);
          have = true;
        } else {
          a[mt] = *(const short8*)(Ab + (size_t)tok * 128 + kb);
        }
      } else {
        const float* ap = Af + (size_t)tok * 128 + kb;
        float4 v0 = *(const float4*)ap;
        float4 v1 = *(const float4*)(ap + 4);
        v[0] = v0.x; v[1] = v0.y; v[2] = v0.z; v[3] = v0.w;
        v[4] = v1.x; v[5] = v1.y; v[6] = v1.z; v[7] = v1.w;
        have = true;
      }
      if (have) {
        if constexpr (PRE == 1) {
          const float mm[8] = {m0.x, m0.y, m0.z, m0.w, m1.x, m1.y, m1.z, m1.w};
          const float rr[8] = {r0.x, r0.y, r0.z, r0.w, r1.x, r1.y, r1.z, r1.w};
          #pragma unroll
          for (int j = 0; j < 8; ++j) v[j] = gelu_f((v[j] - mm[j]) * rr[j]);
        }
        short8 t;
        #pragma unroll
        for (int j = 0; j < 8; ++j) t[j] = (short)f2bf(v[j]);
        a[mt] = t;
      }
    }
    #pragma unroll
    for (int nt = 0; nt < 4; ++nt) {
      const int o = og + wn * 64 + nt * 16 + l15;
      bfr[nt] = *(const short8*)(Wp + (size_t)o * 128 + kb);
    }
    #pragma unroll
    for (int mt = 0; mt < 4; ++mt)
      #pragma unroll
      for (int nt = 0; nt < 4; ++nt)
        acc[mt][nt] = __builtin_amdgcn_mfma_f32_16x16x32_bf16(a[mt], bfr[nt], acc[mt][nt], 0, 0, 0);
  }

  #pragma unroll
  for (int nt = 0; nt < 4; ++nt) {
    const int o = og + wn * 64 + nt * 16 + l15;
    const float bb = bias[o];
    float s = 0.f, q = 0.f;
    #pragma unroll
    for (int mt = 0; mt < 4; ++mt) {
      #pragma unroll
      for (int r = 0; r < 4; ++r) {
        const int t = t0 + wm * 64 + mt * 16 + l4 * 4 + r;
        const float v = acc[mt][nt][r] + bb;
        if constexpr (POST == 0) {
          Yf[(size_t)t * O + o] = v;
        } else if constexpr (POST == 1) {
          Yb[(size_t)t * 128 + o] = f2bf(sigmoid_f(v) * bf2f(xtb[(size_t)t * 128 + o]));
        } else if constexpr (POST == 2) {
          Yb[(size_t)t * O + o] = f2bf(v);
        } else {
          const int which = o >> 7, hsub = (o & 127) >> 4, ch = o & 15;
          Yb[((size_t)hsub * NTOK + t) * 48 + which * 16 + ch] = f2bf(v);
        }
        if constexpr (STATS) { s += v; q += v * v; }
      }
    }
    if constexpr (STATS) {
      s += __shfl_xor(s, 16); s += __shfl_xor(s, 32);
      q += __shfl_xor(q, 16); q += __shfl_xor(q, 32);
      if (l4 == 0) { sumb[o - og][wm] = s; sqb[o - og][wm] = q; }
    }
  }
  if constexpr (STATS) {
    __syncthreads();
    if (tid < 128) {
      ps[blockIdx.y * 128 + tid] = sumb[tid][0] + sumb[tid][1];
      pss[blockIdx.y * 128 + tid] = sqb[tid][0] + sqb[tid][1];
    }
  }
}

// ---------------------------------------------------------------------------
// K6: final projection over A0+A1+A2 (bf16), swapped orientation -> NCDHW
// ---------------------------------------------------------------------------
__global__ __launch_bounds__(256) void proj_mfma_kernel(
    const unsigned short* __restrict__ A0b, const unsigned short* __restrict__ A1b,
    const unsigned short* __restrict__ A2b, const unsigned short* __restrict__ Wp,
    const float* __restrict__ bias, float* __restrict__ out) {
  const int tid = threadIdx.x;
  const int lane = tid & 63, wid = tid >> 6;
  const int wm = wid >> 1, wn = wid & 1;
  const int l15 = lane & 15, l4 = lane >> 4;
  const int t0 = blockIdx.x * 128;

  f32x4 acc[4][4];
  #pragma unroll
  for (int mt = 0; mt < 4; ++mt)
    #pragma unroll
    for (int nt = 0; nt < 4; ++nt)
      #pragma unroll
      for (int r = 0; r < 4; ++r) acc[mt][nt][r] = 0.f;

  #pragma unroll
  for (int ks = 0; ks < 4; ++ks) {
    const int kb = ks * 32 + l4 * 8;
    short8 a[4], bfr[4];
    #pragma unroll
    for (int mt = 0; mt < 4; ++mt) {
      const int o = wm * 64 + mt * 16 + l15;
      a[mt] = *(const short8*)(Wp + (size_t)o * 128 + kb);
    }
    #pragma unroll
    for (int nt = 0; nt < 4; ++nt) {
      const int tok = t0 + wn * 64 + nt * 16 + l15;
      const size_t off = (size_t)tok * 128 + kb;
      short8 s0 = *(const short8*)(A0b + off);
      short8 s1 = *(const short8*)(A1b + off);
      short8 s2 = *(const short8*)(A2b + off);
      short8 r;
      #pragma unroll
      for (int i = 0; i < 8; ++i) {
        float f = bf2f((unsigned short)s0[i]) + bf2f((unsigned short)s1[i]) +
                  bf2f((unsigned short)s2[i]);
        r[i] = (short)f2bf(f);
      }
      bfr[nt] = r;
    }
    #pragma unroll
    for (int mt = 0; mt < 4; ++mt)
      #pragma unroll
      for (int nt = 0; nt < 4; ++nt)
        acc[mt][nt] = __builtin_amdgcn_mfma_f32_16x16x32_bf16(a[mt], bfr[nt], acc[mt][nt], 0, 0, 0);
  }

  #pragma unroll
  for (int nt = 0; nt < 4; ++nt) {
    const int tok = t0 + wn * 64 + nt * 16 + l15;
    const int dhw = tok & 32767, bB = tok >> 15;
    #pragma unroll
    for (int mt = 0; mt < 4; ++mt) {
      #pragma unroll
      for (int r = 0; r < 4; ++r) {
        const int o = wm * 64 + mt * 16 + l4 * 4 + r;
        out[((size_t)(bB * 128 + o) << 15) + dhw] = acc[mt][nt][r] + bias[o];
      }
    }
  }
}

// ---------------------------------------------------------------------------
// K7: axial attention via MFMA (r8 proven). One wave per (seq, head, axial).
// ---------------------------------------------------------------------------
__global__ __launch_bounds__(64) void attn_mfma_kernel(
    const unsigned short* __restrict__ qkvh, const float* __restrict__ Rbuf,
    const float* __restrict__ pbw, unsigned short* __restrict__ a0,
    unsigned short* __restrict__ a1, unsigned short* __restrict__ a2) {
  __shared__ unsigned short Vt[16 * 40];  // [d][tok], row pad 40 shorts
  __shared__ float Ot[32 * 20];           // [tok][d], row pad 20 floats
  const int axial = blockIdx.z;
  const int head = blockIdx.y;
  const int seq = blockIdx.x;
  unsigned short* dstbuf = (axial == 0) ? a0 : ((axial == 1) ? a1 : a2);
  const int lane = threadIdx.x;
  const int tok = lane & 31, hi = lane >> 5;
  const int b = seq >> 10, rem = seq & 1023;
  const int u = rem >> 5, v = rem & 31;
  int base, stride, comp;
  if (axial == 0)      { base = (b << 15) + (u << 5) + v;         stride = 1024; comp = 2; }
  else if (axial == 1) { base = (b << 15) + (u << 10) + v;        stride = 32;   comp = 1; }
  else                 { base = (b << 15) + (u << 10) + (v << 5); stride = 1;    comp = 0; }
  const float* Rp = Rbuf + (axial * 8 + head) * 18;
  const float rq00 = fabsf(Rp[0]);
  const size_t t_tok = (size_t)base + (size_t)tok * stride;
  const unsigned short* row = qkvh + (size_t)head * ((size_t)NTOK * 48) + t_tok * 48;
  short8 aq = *(const short8*)(row + hi * 8);
  short8 ak = *(const short8*)(row + 16 + hi * 8);
  short8 av = *(const short8*)(row + 32 + hi * 8);
  if (hi) {  // ch15 carries the R00^2 correction
    aq[7] = (short)f2bf(bf2f((unsigned short)aq[7]) * rq00);
    ak[7] = (short)f2bf(bf2f((unsigned short)ak[7]) * rq00);
  }
  #pragma unroll
  for (int e = 0; e < 8; ++e) Vt[(hi * 8 + e) * 40 + tok] = (unsigned short)av[e];
  __syncthreads();
  f32x16 sacc;
  #pragma unroll
  for (int r = 0; r < 16; ++r) sacc[r] = 0.f;
  sacc = __builtin_amdgcn_mfma_f32_32x32x16_bf16(ak, aq, sacc, 0, 0, 0);
  const float wb = pbw[comp];
  float p[16];
  float mmax = -1e30f;
  #pragma unroll
  for (int r = 0; r < 16; ++r) {
    const int kk = (r & 3) + 4 * hi + 8 * (r >> 2);
    const float lin = -1.0f + (2.0f / 31.0f) * (float)kk;
    p[r] = sacc[r] * 0.25f - lin * wb;
    mmax = fmaxf(mmax, p[r]);
  }
  mmax = fmaxf(mmax, __shfl_xor(mmax, 32));
  float sum = 0.f;
  #pragma unroll
  for (int r = 0; r < 16; ++r) { p[r] = expf(p[r] - mmax); sum += p[r]; }
  sum += __shfl_xor(sum, 32);
  const float inv = 1.0f / sum;
  #pragma unroll
  for (int r = 0; r < 16; ++r) p[r] *= inv;
  unsigned pk[8], sw[8];
  #pragma unroll
  for (int j = 0; j < 8; ++j) {
    unsigned r_;
    asm("v_cvt_pk_bf16_f32 %0, %1, %2" : "=v"(r_) : "v"(p[2 * j]), "v"(p[2 * j + 1]));
    pk[j] = r_;
  }
  #pragma unroll
  for (int j = 0; j < 8; ++j) sw[j] = (unsigned)__shfl_xor((int)pk[j], 32);
  uint4 Fu, Gu;
  Fu.x = hi ? sw[2] : pk[0];
  Fu.y = hi ? sw[3] : pk[1];
  Fu.z = hi ? pk[2] : sw[0];
  Fu.w = hi ? pk[3] : sw[1];
  Gu.x = hi ? sw[6] : pk[4];
  Gu.y = hi ? sw[7] : pk[5];
  Gu.z = hi ? pk[6] : sw[4];
  Gu.w = hi ? pk[7] : sw[5];
  short8 Pf = *(short8*)&Fu;
  short8 Pg = *(short8*)&Gu;
  const unsigned short* vrow = Vt + (tok & 15) * 40;
  short8 Bv0 = *(const short8*)(vrow + hi * 8);
  short8 Bv1 = *(const short8*)(vrow + 16 + hi * 8);
  f32x16 oacc;
  #pragma unroll
  for (int r = 0; r < 16; ++r) oacc[r] = 0.f;
  oacc = __builtin_amdgcn_mfma_f32_32x32x16_bf16(Pf, Bv0, oacc, 0, 0, 0);
  oacc = __builtin_amdgcn_mfma_f32_32x32x16_bf16(Pg, Bv1, oacc, 0, 0, 0);
  if (tok < 16) {
    #pragma unroll
    for (int r = 0; r < 16; ++r) {
      const int q = (r & 3) + 4 * hi + 8 * (r >> 2);
      Ot[q * 20 + tok] = oacc[r];
    }
  }
  __syncthreads();
  if (lane < 32) {
    float o16[16], y16[16], Rv[9];
    #pragma unroll
    for (int j = 0; j < 16; ++j) o16[j] = Ot[lane * 20 + j];
    #pragma unroll
    for (int i = 0; i < 9; ++i) Rv[i] = Rp[9 + i];
    rot16(Rv, o16, y16);
    unsigned outw[8];
    #pragma unroll
    for (int j = 0; j < 8; ++j)
      outw[j] = ((unsigned)f2bf(y16[2 * j + 1]) << 16) | (unsigned)f2bf(y16[2 * j]);
    const size_t t2 = (size_t)base + (size_t)lane * stride;
    unsigned short* dst = dstbuf + t2 * 128 + head * 16;
    uint4 o0 = {outw[0], outw[1], outw[2], outw[3]};
    uint4 o1 = {outw[4], outw[5], outw[6], outw[7]};
    *(uint4*)dst = o0;
    *(uint4*)(dst + 8) = o1;
  }
}

// ---------------------------------------------------------------------------
extern "C" void kernel_launch(void* const* d_in, const int* in_sizes, int n_in,
                              void* d_out, int out_size, void* d_ws, size_t ws_size,
                              hipStream_t stream) {
  const float* x       = (const float*)d_in[0];
  const float* pos_emb = (const float*)d_in[1];
  const float* qkv_w   = (const float*)d_in[2];
  const float* qkv_b   = (const float*)d_in[3];
  const float* lp_w1   = (const float*)d_in[4];
  const float* lp_b1   = (const float*)d_in[5];
  const float* lp_w2   = (const float*)d_in[6];
  const float* lp_b2   = (const float*)d_in[7];
  const float* mod_w1  = (const float*)d_in[8];
  const float* mod_b1  = (const float*)d_in[9];
  const float* mod_w2  = (const float*)d_in[10];
  const float* mod_b2  = (const float*)d_in[11];
  // d_in[12] pa_w, d_in[13] pa_b: cancel in softmax (constant along key axis)
  const float* proj_w  = (const float*)d_in[14];
  const float* proj_b  = (const float*)d_in[15];
  const float* pbw     = (const float*)d_in[16];
  // d_in[17] pos_bias_b: cancels in softmax
  const float* Ad      = (const float*)d_in[18];
  const float* Ah      = (const float*)d_in[19];
  const float* Aw      = (const float*)d_in[20];
  const float* Rd      = (const float*)d_in[21];
  const float* Rh      = (const float*)d_in[22];
  const float* Rw      = (const float*)d_in[23];
  // d_in[24..26] t_d/t_h/t_w: cancel in rel (pairwise difference)

  float* ws = (float*)d_ws;
  float* R0     = ws + WS_R0;
  unsigned short* A0b    = (unsigned short*)(ws + WS_A0);
  unsigned short* A1b    = (unsigned short*)(ws + WS_A1);
  unsigned short* A2b    = (unsigned short*)(ws + WS_A2);
  unsigned short* mpreb  = (unsigned short*)(ws + WS_MPREB);
  unsigned short* xtokb  = (unsigned short*)(ws + WS_XTOKB);
  unsigned short* inT    = (unsigned short*)(ws + WS_INT);
  unsigned short* qkvh   = (unsigned short*)(ws + WS_QKVH);
  unsigned short* convP  = (unsigned short*)(ws + WS_CONVP);
  unsigned short* qkvP   = (unsigned short*)(ws + WS_QKVP);
  unsigned short* WcP    = (unsigned short*)(ws + WS_WCP);
  unsigned short* modw2P = (unsigned short*)(ws + WS_MODW2P);
  unsigned short* projP  = (unsigned short*)(ws + WS_PROJP);
  float* bc     = ws + WS_BC;
  float* Rbuf   = ws + WS_RBUF;
  float* ps     = ws + WS_PS;
  float* pss    = ws + WS_PSS;
  float* mu1    = ws + WS_MU1;
  float* rs1    = ws + WS_RS1;
  float* mu2    = ws + WS_MU2;
  float* rs2    = ws + WS_RS2;
  unsigned short* xmodb = inT;  // x_mod bf16 reuses INT region (inT dead after conv)

  prep_w_kernel<<<256, 256, 0, stream>>>(lp_w1, qkv_w, mod_w1, lp_w2, lp_b2, mod_b1,
                                         mod_w2, proj_w, Ad, Ah, Aw, Rd, Rh, Rw,
                                         convP, qkvP, WcP, modw2P, projP, bc, Rbuf);
  transpose_kernel<<<2048, 256, 0, stream>>>(x, pos_emb, xtokb, inT);
  // lf = circular conv3x3x3(pos_emb), fused stats partials (512 blocks)
  conv_mfma_kernel<<<512, 256, 0, stream>>>(inT, convP, lp_b1, R0, ps, pss);
  stats_final_kernel<<<256, 64, 0, stream>>>(ps, pss, mu1, rs1, 256);
  gemm_mfma_kernel<1, 0, 2, 1><<<dim3(1, 512), 256, 0, stream>>>(
      R0, WcP, bc, mpreb, 128, mu1, rs1, nullptr, ps, pss);
  stats_final_kernel<<<256, 64, 0, stream>>>(ps, pss, mu2, rs2, 256);
  gemm_mfma_kernel<1, 1, 1, 0><<<dim3(1, 512), 256, 0, stream>>>(
      mpreb, modw2P, mod_b2, xmodb, 128, mu2, rs2, xtokb, nullptr, nullptr);
  gemm_mfma_kernel<0, 1, 3, 0><<<dim3(3, 512), 256, 0, stream>>>(
      xmodb, qkvP, qkv_b, qkvh, 384, nullptr, nullptr, nullptr, nullptr, nullptr);
  attn_mfma_kernel<<<dim3(2048, 8, 3), 64, 0, stream>>>(qkvh, Rbuf, pbw, A0b, A1b, A2b);
  proj_mfma_kernel<<<512, 256, 0, stream>>>(A0b, A1b, A2b, projP, proj_b, (float*)d_out);
}

// Round 10
// 299.666 us; speedup vs baseline: 1.0238x; 1.0238x over previous
//
#include <hip/hip_runtime.h>
#include <cstdint>
#include <cstddef>

// ---------------------------------------------------------------------------
// Problem constants: B=2, C=128, D=H=W=32, nh=8, hd=16, L=32
// Tokens: t = b*32768 + d*1024 + h*32 + w   (65536 tokens, 128 channels)
// ---------------------------------------------------------------------------

#define NTOK 65536
#define SPAT 32768

// ws offsets (floats). Same proven map as r7/r8 (136.4 MB).
// lf is now bf16 (first half of the old R0 region; dead before A0 overlays it).
#define WS_R0     0ull          // region: lf bf16 (8388608 ush) -> A0/A1
#define WS_A0     0ull          // 4194304 (8388608 ush)
#define WS_A1     4194304ull    // 4194304
#define WS_MPREB  8388608ull    // 4194304 (8388608 ush)
#define WS_A2     8388608ull    // 4194304 (overlays dead MPREB)
#define WS_XTOKB  12582912ull   // 4194304 (8388608 ush)
#define WS_INT    16777216ull   // 4194304 (8388608 ush): pos_emb bf16 -> x_mod bf16
#define WS_QKVH   20971520ull   // 12582912 (25165824 ush) [h][t][48]
#define WS_CONVP  33554432ull   // 221184 (442368 ush) [tap][dx][ks][l4][co][8]
#define WS_QKVP   33775616ull   // 24576  (49152 ush)
#define WS_WCP    33800192ull   // 8192
#define WS_MODW2P 33808384ull   // 8192
#define WS_PROJP  33816576ull   // 8192
#define WS_BC     33824768ull   // 128
#define WS_RBUF   33824896ull   // 432
#define WS_PS     33825328ull   // 131072 (1024 blocks x 128)
#define WS_PSS    33956400ull   // 131072
#define WS_MU1    34087472ull   // 256
#define WS_RS1    34087728ull   // 256
#define WS_MU2    34087984ull   // 256
#define WS_RS2    34088240ull   // 256
// total 34088496 floats = 136.4 MB

typedef __attribute__((ext_vector_type(8))) short short8;
typedef __attribute__((ext_vector_type(4))) float f32x4;
typedef __attribute__((ext_vector_type(16))) float f32x16;

__device__ __forceinline__ float gelu_f(float x) {
  return 0.5f * x * (1.0f + erff(x * 0.70710678118654752f));
}
__device__ __forceinline__ float sigmoid_f(float x) {
  return 1.0f / (1.0f + expf(-x));
}
__device__ __forceinline__ unsigned short f2bf(float x) {  // RNE f32->bf16
  unsigned int u = __float_as_uint(x);
  unsigned int r = u + 0x7fffu + ((u >> 16) & 1u);
  return (unsigned short)(r >> 16);
}
__device__ __forceinline__ float bf2f(unsigned short u) {
  return __uint_as_float(((unsigned int)u) << 16);
}
// 16 consecutive bf16 -> 16 fp32
__device__ __forceinline__ void bf16x16_load(const unsigned short* p, float* f) {
  const uint4 a = *(const uint4*)p;
  const uint4 b = *(const uint4*)(p + 8);
  const unsigned int w[8] = {a.x, a.y, a.z, a.w, b.x, b.y, b.z, b.w};
  #pragma unroll
  for (int i = 0; i < 8; ++i) {
    f[2 * i] = __uint_as_float(w[i] << 16);
    f[2 * i + 1] = __uint_as_float(w[i] & 0xffff0000u);
  }
}
// async global->LDS, 16B per lane (dest must be wave-uniform base + lane*16)
__device__ __forceinline__ void gload_lds16(const void* g, void* l) {
  __builtin_amdgcn_global_load_lds(
      (const __attribute__((address_space(1))) unsigned int*)g,
      (__attribute__((address_space(3))) unsigned int*)l, 16, 0, 0);
}
__device__ __forceinline__ float dot3(const float* a, const float* b) {
  return a[0] * b[0] + a[1] * b[1] + a[2] * b[2];
}
__device__ __forceinline__ void cross3(const float* a, const float* b, float* c) {
  c[0] = a[1] * b[2] - a[2] * b[1];
  c[1] = a[2] * b[0] - a[0] * b[2];
  c[2] = a[0] * b[1] - a[1] * b[0];
}

// exact port of _r6_to_matrix for one head (6 floats in, 9 out row-major)
__device__ void r6_to_matrix(const float* r6, float* R) {
  float v1[3] = {r6[0], r6[1], r6[2]};
  float n1 = sqrtf(dot3(v1, v1));
  float inv1 = 1.0f / (n1 + 1e-7f);
  v1[0] *= inv1; v1[1] *= inv1; v1[2] *= inv1;
  float v2[3] = {r6[3], r6[4], r6[5]};
  float d = dot3(v2, v1);
  v2[0] -= d * v1[0]; v2[1] -= d * v1[1]; v2[2] -= d * v1[2];
  float n2 = sqrtf(dot3(v2, v2));
  float inv2 = 1.0f / (n2 + 1e-7f);
  v2[0] *= inv2; v2[1] *= inv2; v2[2] *= inv2;
  float v3[3]; cross3(v1, v2, v3);
  float cx[3]; cross3(v2, v3, cx);
  float det = dot3(v1, cx);
  if (det < 0.0f) { v3[0] = -v3[0]; v3[1] = -v3[1]; v3[2] = -v3[2]; }
  R[0] = v1[0]; R[1] = v1[1]; R[2] = v1[2];
  R[3] = v2[0]; R[4] = v2[1]; R[5] = v2[2];
  R[6] = v3[0]; R[7] = v3[1]; R[8] = v3[2];
}

// exact port of _ensure_matrix for one head (9 in row-major, 9 out)
__device__ void ensure_matrix(const float* Rin, float* Ro) {
  float a[3] = {Rin[0] + 1e-6f, Rin[1] + 1e-6f, Rin[2] + 1e-6f};
  float na = fmaxf(sqrtf(dot3(a, a)), 1e-12f);
  float v1[3] = {a[0] / na, a[1] / na, a[2] / na};
  float b0[3] = {Rin[3], Rin[4], Rin[5]};
  float d = dot3(b0, v1);
  float bb[3] = {b0[0] - d * v1[0] + 1e-6f, b0[1] - d * v1[1] + 1e-6f, b0[2] - d * v1[2] + 1e-6f};
  float nb = fmaxf(sqrtf(dot3(bb, bb)), 1e-12f);
  float v2[3] = {bb[0] / nb, bb[1] / nb, bb[2] / nb};
  float v3[3]; cross3(v1, v2, v3);
  float cx[3]; cross3(v2, v3, cx);
  float det = dot3(v1, cx);
  if (det < 0.0f) { v3[0] = -v3[0]; v3[1] = -v3[1]; v3[2] = -v3[2]; }
  float Rn[9] = {v1[0], v1[1], v1[2], v2[0], v2[1], v2[2], v3[0], v3[1], v3[2]};
  float T1[9], T2[9];
  for (int i = 0; i < 3; ++i)
    for (int j = 0; j < 3; ++j) {
      float s = 0.f;
      for (int k = 0; k < 3; ++k) s += Rn[k * 3 + i] * Rn[k * 3 + j];
      T1[i * 3 + j] = s;
    }
  for (int i = 0; i < 3; ++i)
    for (int j = 0; j < 3; ++j) {
      float s = 0.f;
      for (int k = 0; k < 3; ++k) s += T1[i * 3 + k] * Rn[j * 3 + k];
      T2[i * 3 + j] = s;
    }
  for (int i = 0; i < 9; ++i) Ro[i] = 0.5f * (Rn[i] + T2[i]);
}

// y = R_eff x for hd=16 (5 full 3x3 groups + scalar R00 on ch15)
__device__ __forceinline__ void rot16(const float* R, const float* x, float* y) {
  #pragma unroll
  for (int g = 0; g < 5; ++g) {
    float a = x[3 * g], b = x[3 * g + 1], c = x[3 * g + 2];
    y[3 * g + 0] = R[0] * a + R[1] * b + R[2] * c;
    y[3 * g + 1] = R[3] * a + R[4] * b + R[5] * c;
    y[3 * g + 2] = R[6] * a + R[7] * b + R[8] * c;
  }
  y[15] = R[0] * x[15];
}

// ---------------------------------------------------------------------------
// K0: weight packs (+ rotation matrices in block 0)
// ---------------------------------------------------------------------------
__global__ __launch_bounds__(256) void prep_w_kernel(
    const float* __restrict__ lp_w1, const float* __restrict__ qkv_w,
    const float* __restrict__ mod_w1, const float* __restrict__ lp_w2,
    const float* __restrict__ lp_b2, const float* __restrict__ mod_b1,
    const float* __restrict__ mod_w2, const float* __restrict__ proj_w,
    const float* __restrict__ Ad, const float* __restrict__ Ah,
    const float* __restrict__ Aw, const float* __restrict__ Rd,
    const float* __restrict__ Rh, const float* __restrict__ Rw,
    unsigned short* __restrict__ convP, unsigned short* __restrict__ qkvP,
    unsigned short* __restrict__ WcP, unsigned short* __restrict__ modw2P,
    unsigned short* __restrict__ projP, float* __restrict__ bc,
    float* __restrict__ Rbuf) {
  int gid = blockIdx.x * 256 + threadIdx.x;  // 65536 threads
  for (int f = gid; f < 442368; f += 65536) {
    int e = f & 7;
    int co = (f >> 3) & 127;
    int rest = f >> 10;
    int l4 = rest & 3;
    int ks = (rest >> 2) & 3;
    int dxt = rest >> 4;
    int dx = dxt % 3;
    int tap = dxt / 3;
    int dz = tap / 3, dy = tap % 3;
    int ci = ks * 32 + l4 * 8 + e;
    convP[f] = f2bf(lp_w1[(co * 128 + ci) * 27 + dz * 9 + dy * 3 + dx]);
  }
  if (gid < 49152) qkvP[gid] = f2bf(qkv_w[gid]);
  if (gid < 16384) {
    modw2P[gid] = f2bf(mod_w2[gid]);
    projP[gid] = f2bf(proj_w[gid]);
    int o = gid >> 7, i = gid & 127;
    float s = 0.f;
    for (int c = 0; c < 128; ++c) s += mod_w1[o * 128 + c] * lp_w2[c * 128 + i];
    WcP[gid] = f2bf(s);
  }
  if (gid < 128) {
    float s = 0.f;
    for (int c = 0; c < 128; ++c) s += mod_w1[gid * 128 + c] * lp_b2[c];
    bc[gid] = s + mod_b1[gid];
  }
  if (blockIdx.x == 0 && threadIdx.x >= 224 && threadIdx.x < 248) {
    int tid = threadIdx.x - 224;
    int ax = tid >> 3, h = tid & 7;
    const float* A = (ax == 0) ? Ad : ((ax == 1) ? Ah : Aw);
    const float* R = (ax == 0) ? Rd : ((ax == 1) ? Rh : Rw);
    float Rq[9], Rv[9];
    r6_to_matrix(A + h * 6, Rq);
    ensure_matrix(R + h * 9, Rv);
    float* dst = Rbuf + (ax * 8 + h) * 18;
    for (int i = 0; i < 9; ++i) { dst[i] = Rq[i]; dst[9 + i] = Rv[i]; }
  }
}

// ---------------------------------------------------------------------------
// K0c: merged transposes. Per (b,d,h) plane: x -> xtokb bf16, pos_emb -> inT bf16
// ---------------------------------------------------------------------------
__global__ __launch_bounds__(256) void transpose_kernel(const float* __restrict__ x,
                                                        const float* __restrict__ pe,
                                                        unsigned short* __restrict__ xtokb,
                                                        unsigned short* __restrict__ inT) {
  __shared__ float lds[32][132];
  int blk = blockIdx.x;  // b*1024 + d*32 + h
  int b = blk >> 10;
  int dh = blk & 1023;
  int tid = threadIdx.x;
  size_t planebase = ((size_t)b << 22) + ((size_t)dh << 5);
  size_t tb = ((size_t)blk) << 5;
  #pragma unroll
  for (int r = 0; r < 16; ++r) {
    int idx = r * 256 + tid;
    int ci = idx >> 5, w = idx & 31;
    lds[w][ci] = x[planebase + ((size_t)ci << 15) + w];
  }
  __syncthreads();
  #pragma unroll
  for (int r = 0; r < 16; ++r) {
    int idx = r * 256 + tid;
    int w = idx >> 7, ci = idx & 127;
    xtokb[(tb + w) * 128 + ci] = f2bf(lds[w][ci]);
  }
  __syncthreads();
  #pragma unroll
  for (int r = 0; r < 16; ++r) {
    int idx = r * 256 + tid;
    int ci = idx >> 5, w = idx & 31;
    lds[w][ci] = pe[planebase + ((size_t)ci << 15) + w];
  }
  __syncthreads();
  #pragma unroll
  for (int r = 0; r < 16; ++r) {
    int idx = r * 256 + tid;
    int w = idx >> 7, ci = idx & 127;
    inT[(tb + w) * 128 + ci] = f2bf(lds[w][ci]);
  }
}

// ---------------------------------------------------------------------------
// K1: 3x3x3 circular conv via bf16 MFMA, v6.
// v4 geometry: 1024 blocks, 64 tokens (2 h-rows) x 128 co; 4 waves 2x2.
// __launch_bounds__(256,4): VGPR<=128 -> 4 blocks/CU resident; blocks desync
// across dz phases so B-load stalls of one block hide under MFMAs of another.
// setprio(1) around MFMA clusters (T5; role diversity now exists).
// lf written bf16 (stats fp32-exact in epilogue, pre-rounding).
// ---------------------------------------------------------------------------
__global__ __launch_bounds__(256, 4) void conv_mfma_kernel(
    const unsigned short* __restrict__ inT, const unsigned short* __restrict__ Bp,
    const float* __restrict__ b1, unsigned short* __restrict__ out,
    float* __restrict__ ps, float* __restrict__ pss) {
  __shared__ unsigned short Als[16384];  // 32KB: 4 rows x 32 w x 128 ci, swizzled
  __shared__ float sumb[128][2];
  __shared__ float sqb[128][2];
  const int blk = blockIdx.x;             // 1024 blocks
  const int b = blk >> 9, d = (blk >> 4) & 31, hg = blk & 15;
  const int h0 = hg << 1;                 // 2 output h-rows
  const int tid = threadIdx.x;
  const int lane = tid & 63;
  const int wid = tid >> 6;
  const int wm = wid >> 1, wn = wid & 1;
  const int l15 = lane & 15, l4 = lane >> 4;

  f32x4 acc[2][4];
  #pragma unroll
  for (int mt = 0; mt < 2; ++mt)
    #pragma unroll
    for (int nt = 0; nt < 4; ++nt)
      #pragma unroll
      for (int r = 0; r < 4; ++r) acc[mt][nt][r] = 0.f;

  int mw[2], mhh[2];
  #pragma unroll
  for (int mt = 0; mt < 2; ++mt) {
    int m = wm * 32 + mt * 16 + l15;
    mhh[mt] = m >> 5;
    mw[mt] = m & 31;
  }
  const size_t tokbase = ((size_t)b << 15) + ((size_t)d << 10) + ((size_t)h0 << 5);

  // stage 4-row halo (h0-1 .. h0+2) of plane (d+dz-1) -> 32KB
  auto stage = [&](int dz) {
    const int zr = (d + dz + 31) & 31;
    #pragma unroll
    for (int p = 0; p < 8; ++p) {
      const int g = p * 256 + tid;        // 2048 chunks of 16B
      const int tok = g >> 4, gi = g & 15;
      const int r = tok >> 5, w = tok & 31;
      const int yr = (h0 + r + 31) & 31;
      const size_t srcbyte = ((((size_t)b << 15) + ((size_t)zr << 10) + ((size_t)yr << 5) + w) << 8)
                             + (size_t)((gi ^ (w & 7)) << 4);
      gload_lds16((const char*)inT + srcbyte, (char*)Als + (size_t)g * 16);
    }
  };

  auto compute = [&](int dz) {
    #pragma unroll
    for (int dy = 0; dy < 3; ++dy) {
      const int tap = dz * 3 + dy;
      #pragma unroll
      for (int dx = 0; dx < 3; ++dx) {
        int abase[2], asw[2];
        #pragma unroll
        for (int mt = 0; mt < 2; ++mt) {
          const int wsft = (mw[mt] + dx + 31) & 31;
          const int stok = (mhh[mt] + dy) * 32 + wsft;
          abase[mt] = stok * 256;
          asw[mt] = (wsft & 7) << 4;
        }
        #pragma unroll
        for (int ks = 0; ks < 4; ++ks) {
          const int k2 = (ks * 32 + l4 * 8) * 2;
          const int bbase = (((tap * 3 + dx) * 4 + ks) * 4 + l4) * 1024;
          short8 afr[2], bfr[4];
          #pragma unroll
          for (int nt = 0; nt < 4; ++nt) {
            const int co = wn * 64 + nt * 16 + l15;
            bfr[nt] = *(const short8*)(Bp + bbase + co * 8);
          }
          #pragma unroll
          for (int mt = 0; mt < 2; ++mt)
            afr[mt] = *(const short8*)((const char*)Als + abase[mt] + (k2 ^ asw[mt]));
          __builtin_amdgcn_s_setprio(1);
          #pragma unroll
          for (int mt = 0; mt < 2; ++mt)
            #pragma unroll
            for (int nt = 0; nt < 4; ++nt)
              acc[mt][nt] = __builtin_amdgcn_mfma_f32_16x16x32_bf16(afr[mt], bfr[nt],
                                                                    acc[mt][nt], 0, 0, 0);
          __builtin_amdgcn_s_setprio(0);
        }
      }
    }
  };

  for (int dz = 0; dz < 3; ++dz) {
    stage(dz);
    __syncthreads();   // stage complete (drains vmcnt)
    compute(dz);
    if (dz < 2) __syncthreads();  // all reads done before next stage overwrites
  }

  // epilogue: bias + bf16 store + fused fp32 stats partials
  #pragma unroll
  for (int nt = 0; nt < 4; ++nt) {
    const int co = wn * 64 + nt * 16 + l15;
    const float bias = b1[co];
    float s = 0.f, q = 0.f;
    #pragma unroll
    for (int mt = 0; mt < 2; ++mt) {
      #pragma unroll
      for (int r = 0; r < 4; ++r) {
        const int m = wm * 32 + mt * 16 + l4 * 4 + r;
        const float v = acc[mt][nt][r] + bias;
        out[(tokbase + m) * 128 + co] = f2bf(v);
        s += v; q += v * v;
      }
    }
    s += __shfl_xor(s, 16); s += __shfl_xor(s, 32);
    q += __shfl_xor(q, 16); q += __shfl_xor(q, 32);
    if (l4 == 0) { sumb[co][wm] = s; sqb[co][wm] = q; }
  }
  __syncthreads();
  if (tid < 128) {
    ps[blk * 128 + tid] = sumb[tid][0] + sumb[tid][1];
    pss[blk * 128 + tid] = sqb[tid][0] + sqb[tid][1];
  }
}

// ---------------------------------------------------------------------------
// K2: stats finalize, parallel
// ---------------------------------------------------------------------------
__global__ __launch_bounds__(64) void stats_final_kernel(
    const float* __restrict__ ps, const float* __restrict__ pss,
    float* __restrict__ mu, float* __restrict__ rs, int nb) {
  const int pair = blockIdx.x;  // b*128 + c
  const int b = pair >> 7, c = pair & 127;
  const int lane = threadIdx.x;
  float s = 0.f, ss = 0.f;
  for (int j = lane; j < nb; j += 64) {
    const int idx = ((b * nb + j) << 7) + c;
    s += ps[idx];
    ss += pss[idx];
  }
  #pragma unroll
  for (int o = 32; o > 0; o >>= 1) {
    s += __shfl_xor(s, o);
    ss += __shfl_xor(ss, o);
  }
  if (lane == 0) {
    float m = s * (1.0f / 32768.0f);
    float v = ss * (1.0f / 32768.0f) - m * m;
    mu[pair] = m;
    rs[pair] = rsqrtf(v + 1e-5f);
  }
}

// ---------------------------------------------------------------------------
// K3: 1x1 GEMM via bf16 MFMA, register-only (r7 proven).
// ---------------------------------------------------------------------------
template <int PRE, int AB16, int POST, int STATS>
__global__ __launch_bounds__(256) void gemm_mfma_kernel(
    const void* __restrict__ Avoid, const unsigned short* __restrict__ Wp,
    const float* __restrict__ bias, void* __restrict__ Yvoid, int O,
    const float* __restrict__ mu, const float* __restrict__ rs,
    const unsigned short* __restrict__ xtb, float* __restrict__ ps,
    float* __restrict__ pss) {
  __shared__ float sumb[128][2];
  __shared__ float sqb[128][2];
  const int tid = threadIdx.x;
  const int lane = tid & 63, wid = tid >> 6;
  const int wm = wid >> 1, wn = wid & 1;
  const int l15 = lane & 15, l4 = lane >> 4;
  const int og = blockIdx.x * 128;
  const int t0 = blockIdx.y * 128;
  const int bidx = t0 >> 15;
  const float* Af = (const float*)Avoid;
  const unsigned short* Ab = (const unsigned short*)Avoid;
  float* Yf = (float*)Yvoid;
  unsigned short* Yb = (unsigned short*)Yvoid;

  f32x4 acc[4][4];
  #pragma unroll
  for (int mt = 0; mt < 4; ++mt)
    #pragma unroll
    for (int nt = 0; nt < 4; ++nt)
      #pragma unroll
      for (int r = 0; r < 4; ++r) acc[mt][nt][r] = 0.f;

  #pragma unroll
  for (int ks = 0; ks < 4; ++ks) {
    const int kb = ks * 32 + l4 * 8;
    short8 a[4], bfr[4];
    float4 m0, m1, r0, r1;
    if constexpr (PRE == 1) {
      m0 = *(const float4*)(mu + bidx * 128 + kb);
      m1 = *(const float4*)(mu + bidx * 128 + kb + 4);
      r0 = *(const float4*)(rs + bidx * 128 + kb);
      r1 = *(const float4*)(rs + bidx * 128 + kb + 4);
    }
    #pragma unroll
    for (int mt = 0; mt < 4; ++mt) {
      const int tok = t0 + wm * 64 + mt * 16 + l15;
      float v[16];
      bool have = false;
      if constexpr (AB16 == 1) {
        if constexpr (PRE == 1) {
          bf16x16_load(Ab + (size_t)tok * 128 + kb, v);
          have = true;
        } else {
          a[mt] = *(const short8*)(Ab + (size_t)tok * 128 + kb);
        }
      } else {
        const float* ap = Af + (size_t)tok * 128 + kb;
        float4 v0 = *(const float4*)ap;
        float4 v1 = *(const float4*)(ap + 4);
        v[0] = v0.x; v[1] = v0.y; v[2] = v0.z; v[3] = v0.w;
        v[4] = v1.x; v[5] = v1.y; v[6] = v1.z; v[7] = v1.w;
        have = true;
      }
      if (have) {
        if constexpr (PRE == 1) {
          const float mm[8] = {m0.x, m0.y, m0.z, m0.w, m1.x, m1.y, m1.z, m1.w};
          const float rr[8] = {r0.x, r0.y, r0.z, r0.w, r1.x, r1.y, r1.z, r1.w};
          #pragma unroll
          for (int j = 0; j < 8; ++j) v[j] = gelu_f((v[j] - mm[j]) * rr[j]);
        }
        short8 t;
        #pragma unroll
        for (int j = 0; j < 8; ++j) t[j] = (short)f2bf(v[j]);
        a[mt] = t;
      }
    }
    #pragma unroll
    for (int nt = 0; nt < 4; ++nt) {
      const int o = og + wn * 64 + nt * 16 + l15;
      bfr[nt] = *(const short8*)(Wp + (size_t)o * 128 + kb);
    }
    #pragma unroll
    for (int mt = 0; mt < 4; ++mt)
      #pragma unroll
      for (int nt = 0; nt < 4; ++nt)
        acc[mt][nt] = __builtin_amdgcn_mfma_f32_16x16x32_bf16(a[mt], bfr[nt], acc[mt][nt], 0, 0, 0);
  }

  #pragma unroll
  for (int nt = 0; nt < 4; ++nt) {
    const int o = og + wn * 64 + nt * 16 + l15;
    const float bb = bias[o];
    float s = 0.f, q = 0.f;
    #pragma unroll
    for (int mt = 0; mt < 4; ++mt) {
      #pragma unroll
      for (int r = 0; r < 4; ++r) {
        const int t = t0 + wm * 64 + mt * 16 + l4 * 4 + r;
        const float v = acc[mt][nt][r] + bb;
        if constexpr (POST == 0) {
          Yf[(size_t)t * O + o] = v;
        } else if constexpr (POST == 1) {
          Yb[(size_t)t * 128 + o] = f2bf(sigmoid_f(v) * bf2f(xtb[(size_t)t * 128 + o]));
        } else if constexpr (POST == 2) {
          Yb[(size_t)t * O + o] = f2bf(v);
        } else {
          const int which = o >> 7, hsub = (o & 127) >> 4, ch = o & 15;
          Yb[((size_t)hsub * NTOK + t) * 48 + which * 16 + ch] = f2bf(v);
        }
        if constexpr (STATS) { s += v; q += v * v; }
      }
    }
    if constexpr (STATS) {
      s += __shfl_xor(s, 16); s += __shfl_xor(s, 32);
      q += __shfl_xor(q, 16); q += __shfl_xor(q, 32);
      if (l4 == 0) { sumb[o - og][wm] = s; sqb[o - og][wm] = q; }
    }
  }
  if constexpr (STATS) {
    __syncthreads();
    if (tid < 128) {
      ps[blockIdx.y * 128 + tid] = sumb[tid][0] + sumb[tid][1];
      pss[blockIdx.y * 128 + tid] = sqb[tid][0] + sqb[tid][1];
    }
  }
}

// ---------------------------------------------------------------------------
// K6: final projection over A0+A1+A2 (bf16), swapped orientation -> NCDHW
// ---------------------------------------------------------------------------
__global__ __launch_bounds__(256) void proj_mfma_kernel(
    const unsigned short* __restrict__ A0b, const unsigned short* __restrict__ A1b,
    const unsigned short* __restrict__ A2b, const unsigned short* __restrict__ Wp,
    const float* __restrict__ bias, float* __restrict__ out) {
  const int tid = threadIdx.x;
  const int lane = tid & 63, wid = tid >> 6;
  const int wm = wid >> 1, wn = wid & 1;
  const int l15 = lane & 15, l4 = lane >> 4;
  const int t0 = blockIdx.x * 128;

  f32x4 acc[4][4];
  #pragma unroll
  for (int mt = 0; mt < 4; ++mt)
    #pragma unroll
    for (int nt = 0; nt < 4; ++nt)
      #pragma unroll
      for (int r = 0; r < 4; ++r) acc[mt][nt][r] = 0.f;

  #pragma unroll
  for (int ks = 0; ks < 4; ++ks) {
    const int kb = ks * 32 + l4 * 8;
    short8 a[4], bfr[4];
    #pragma unroll
    for (int mt = 0; mt < 4; ++mt) {
      const int o = wm * 64 + mt * 16 + l15;
      a[mt] = *(const short8*)(Wp + (size_t)o * 128 + kb);
    }
    #pragma unroll
    for (int nt = 0; nt < 4; ++nt) {
      const int tok = t0 + wn * 64 + nt * 16 + l15;
      const size_t off = (size_t)tok * 128 + kb;
      short8 s0 = *(const short8*)(A0b + off);
      short8 s1 = *(const short8*)(A1b + off);
      short8 s2 = *(const short8*)(A2b + off);
      short8 r;
      #pragma unroll
      for (int i = 0; i < 8; ++i) {
        float f = bf2f((unsigned short)s0[i]) + bf2f((unsigned short)s1[i]) +
                  bf2f((unsigned short)s2[i]);
        r[i] = (short)f2bf(f);
      }
      bfr[nt] = r;
    }
    #pragma unroll
    for (int mt = 0; mt < 4; ++mt)
      #pragma unroll
      for (int nt = 0; nt < 4; ++nt)
        acc[mt][nt] = __builtin_amdgcn_mfma_f32_16x16x32_bf16(a[mt], bfr[nt], acc[mt][nt], 0, 0, 0);
  }

  #pragma unroll
  for (int nt = 0; nt < 4; ++nt) {
    const int tok = t0 + wn * 64 + nt * 16 + l15;
    const int dhw = tok & 32767, bB = tok >> 15;
    #pragma unroll
    for (int mt = 0; mt < 4; ++mt) {
      #pragma unroll
      for (int r = 0; r < 4; ++r) {
        const int o = wm * 64 + mt * 16 + l4 * 4 + r;
        out[((size_t)(bB * 128 + o) << 15) + dhw] = acc[mt][nt][r] + bias[o];
      }
    }
  }
}

// ---------------------------------------------------------------------------
// K7: axial attention via MFMA (r8 proven). One wave per (seq, head, axial).
// ---------------------------------------------------------------------------
__global__ __launch_bounds__(64) void attn_mfma_kernel(
    const unsigned short* __restrict__ qkvh, const float* __restrict__ Rbuf,
    const float* __restrict__ pbw, unsigned short* __restrict__ a0,
    unsigned short* __restrict__ a1, unsigned short* __restrict__ a2) {
  __shared__ unsigned short Vt[16 * 40];  // [d][tok], row pad 40 shorts
  __shared__ float Ot[32 * 20];           // [tok][d], row pad 20 floats
  const int axial = blockIdx.z;
  const int head = blockIdx.y;
  const int seq = blockIdx.x;
  unsigned short* dstbuf = (axial == 0) ? a0 : ((axial == 1) ? a1 : a2);
  const int lane = threadIdx.x;
  const int tok = lane & 31, hi = lane >> 5;
  const int b = seq >> 10, rem = seq & 1023;
  const int u = rem >> 5, v = rem & 31;
  int base, stride, comp;
  if (axial == 0)      { base = (b << 15) + (u << 5) + v;         stride = 1024; comp = 2; }
  else if (axial == 1) { base = (b << 15) + (u << 10) + v;        stride = 32;   comp = 1; }
  else                 { base = (b << 15) + (u << 10) + (v << 5); stride = 1;    comp = 0; }
  const float* Rp = Rbuf + (axial * 8 + head) * 18;
  const float rq00 = fabsf(Rp[0]);
  const size_t t_tok = (size_t)base + (size_t)tok * stride;
  const unsigned short* row = qkvh + (size_t)head * ((size_t)NTOK * 48) + t_tok * 48;
  short8 aq = *(const short8*)(row + hi * 8);
  short8 ak = *(const short8*)(row + 16 + hi * 8);
  short8 av = *(const short8*)(row + 32 + hi * 8);
  if (hi) {  // ch15 carries the R00^2 correction
    aq[7] = (short)f2bf(bf2f((unsigned short)aq[7]) * rq00);
    ak[7] = (short)f2bf(bf2f((unsigned short)ak[7]) * rq00);
  }
  #pragma unroll
  for (int e = 0; e < 8; ++e) Vt[(hi * 8 + e) * 40 + tok] = (unsigned short)av[e];
  __syncthreads();
  f32x16 sacc;
  #pragma unroll
  for (int r = 0; r < 16; ++r) sacc[r] = 0.f;
  sacc = __builtin_amdgcn_mfma_f32_32x32x16_bf16(ak, aq, sacc, 0, 0, 0);
  const float wb = pbw[comp];
  float p[16];
  float mmax = -1e30f;
  #pragma unroll
  for (int r = 0; r < 16; ++r) {
    const int kk = (r & 3) + 4 * hi + 8 * (r >> 2);
    const float lin = -1.0f + (2.0f / 31.0f) * (float)kk;
    p[r] = sacc[r] * 0.25f - lin * wb;
    mmax = fmaxf(mmax, p[r]);
  }
  mmax = fmaxf(mmax, __shfl_xor(mmax, 32));
  float sum = 0.f;
  #pragma unroll
  for (int r = 0; r < 16; ++r) { p[r] = expf(p[r] - mmax); sum += p[r]; }
  sum += __shfl_xor(sum, 32);
  const float inv = 1.0f / sum;
  #pragma unroll
  for (int r = 0; r < 16; ++r) p[r] *= inv;
  unsigned pk[8], sw[8];
  #pragma unroll
  for (int j = 0; j < 8; ++j) {
    unsigned r_;
    asm("v_cvt_pk_bf16_f32 %0, %1, %2" : "=v"(r_) : "v"(p[2 * j]), "v"(p[2 * j + 1]));
    pk[j] = r_;
  }
  #pragma unroll
  for (int j = 0; j < 8; ++j) sw[j] = (unsigned)__shfl_xor((int)pk[j], 32);
  uint4 Fu, Gu;
  Fu.x = hi ? sw[2] : pk[0];
  Fu.y = hi ? sw[3] : pk[1];
  Fu.z = hi ? pk[2] : sw[0];
  Fu.w = hi ? pk[3] : sw[1];
  Gu.x = hi ? sw[6] : pk[4];
  Gu.y = hi ? sw[7] : pk[5];
  Gu.z = hi ? pk[6] : sw[4];
  Gu.w = hi ? pk[7] : sw[5];
  short8 Pf = *(short8*)&Fu;
  short8 Pg = *(short8*)&Gu;
  const unsigned short* vrow = Vt + (tok & 15) * 40;
  short8 Bv0 = *(const short8*)(vrow + hi * 8);
  short8 Bv1 = *(const short8*)(vrow + 16 + hi * 8);
  f32x16 oacc;
  #pragma unroll
  for (int r = 0; r < 16; ++r) oacc[r] = 0.f;
  oacc = __builtin_amdgcn_mfma_f32_32x32x16_bf16(Pf, Bv0, oacc, 0, 0, 0);
  oacc = __builtin_amdgcn_mfma_f32_32x32x16_bf16(Pg, Bv1, oacc, 0, 0, 0);
  if (tok < 16) {
    #pragma unroll
    for (int r = 0; r < 16; ++r) {
      const int q = (r & 3) + 4 * hi + 8 * (r >> 2);
      Ot[q * 20 + tok] = oacc[r];
    }
  }
  __syncthreads();
  if (lane < 32) {
    float o16[16], y16[16], Rv[9];
    #pragma unroll
    for (int j = 0; j < 16; ++j) o16[j] = Ot[lane * 20 + j];
    #pragma unroll
    for (int i = 0; i < 9; ++i) Rv[i] = Rp[9 + i];
    rot16(Rv, o16, y16);
    unsigned outw[8];
    #pragma unroll
    for (int j = 0; j < 8; ++j)
      outw[j] = ((unsigned)f2bf(y16[2 * j + 1]) << 16) | (unsigned)f2bf(y16[2 * j]);
    const size_t t2 = (size_t)base + (size_t)lane * stride;
    unsigned short* dst = dstbuf + t2 * 128 + head * 16;
    uint4 o0 = {outw[0], outw[1], outw[2], outw[3]};
    uint4 o1 = {outw[4], outw[5], outw[6], outw[7]};
    *(uint4*)dst = o0;
    *(uint4*)(dst + 8) = o1;
  }
}

// ---------------------------------------------------------------------------
extern "C" void kernel_launch(void* const* d_in, const int* in_sizes, int n_in,
                              void* d_out, int out_size, void* d_ws, size_t ws_size,
                              hipStream_t stream) {
  const float* x       = (const float*)d_in[0];
  const float* pos_emb = (const float*)d_in[1];
  const float* qkv_w   = (const float*)d_in[2];
  const float* qkv_b   = (const float*)d_in[3];
  const float* lp_w1   = (const float*)d_in[4];
  const float* lp_b1   = (const float*)d_in[5];
  const float* lp_w2   = (const float*)d_in[6];
  const float* lp_b2   = (const float*)d_in[7];
  const float* mod_w1  = (const float*)d_in[8];
  const float* mod_b1  = (const float*)d_in[9];
  const float* mod_w2  = (const float*)d_in[10];
  const float* mod_b2  = (const float*)d_in[11];
  // d_in[12] pa_w, d_in[13] pa_b: cancel in softmax (constant along key axis)
  const float* proj_w  = (const float*)d_in[14];
  const float* proj_b  = (const float*)d_in[15];
  const float* pbw     = (const float*)d_in[16];
  // d_in[17] pos_bias_b: cancels in softmax
  const float* Ad      = (const float*)d_in[18];
  const float* Ah      = (const float*)d_in[19];
  const float* Aw      = (const float*)d_in[20];
  const float* Rd      = (const float*)d_in[21];
  const float* Rh      = (const float*)d_in[22];
  const float* Rw      = (const float*)d_in[23];
  // d_in[24..26] t_d/t_h/t_w: cancel in rel (pairwise difference)

  float* ws = (float*)d_ws;
  unsigned short* lfb    = (unsigned short*)(ws + WS_R0);   // lf bf16
  unsigned short* A0b    = (unsigned short*)(ws + WS_A0);
  unsigned short* A1b    = (unsigned short*)(ws + WS_A1);
  unsigned short* A2b    = (unsigned short*)(ws + WS_A2);
  unsigned short* mpreb  = (unsigned short*)(ws + WS_MPREB);
  unsigned short* xtokb  = (unsigned short*)(ws + WS_XTOKB);
  unsigned short* inT    = (unsigned short*)(ws + WS_INT);
  unsigned short* qkvh   = (unsigned short*)(ws + WS_QKVH);
  unsigned short* convP  = (unsigned short*)(ws + WS_CONVP);
  unsigned short* qkvP   = (unsigned short*)(ws + WS_QKVP);
  unsigned short* WcP    = (unsigned short*)(ws + WS_WCP);
  unsigned short* modw2P = (unsigned short*)(ws + WS_MODW2P);
  unsigned short* projP  = (unsigned short*)(ws + WS_PROJP);
  float* bc     = ws + WS_BC;
  float* Rbuf   = ws + WS_RBUF;
  float* ps     = ws + WS_PS;
  float* pss    = ws + WS_PSS;
  float* mu1    = ws + WS_MU1;
  float* rs1    = ws + WS_RS1;
  float* mu2    = ws + WS_MU2;
  float* rs2    = ws + WS_RS2;
  unsigned short* xmodb = inT;  // x_mod bf16 reuses INT region (inT dead after conv)

  prep_w_kernel<<<256, 256, 0, stream>>>(lp_w1, qkv_w, mod_w1, lp_w2, lp_b2, mod_b1,
                                         mod_w2, proj_w, Ad, Ah, Aw, Rd, Rh, Rw,
                                         convP, qkvP, WcP, modw2P, projP, bc, Rbuf);
  transpose_kernel<<<2048, 256, 0, stream>>>(x, pos_emb, xtokb, inT);
  // lf (bf16) = circular conv3x3x3(pos_emb), fused fp32 stats partials
  conv_mfma_kernel<<<1024, 256, 0, stream>>>(inT, convP, lp_b1, lfb, ps, pss);
  stats_final_kernel<<<256, 64, 0, stream>>>(ps, pss, mu1, rs1, 512);
  // m_pre (bf16) = gelu(inorm(lf)) @ Wc^T + bc, fused stats partials
  gemm_mfma_kernel<1, 1, 2, 1><<<dim3(1, 512), 256, 0, stream>>>(
      lfb, WcP, bc, mpreb, 128, mu1, rs1, nullptr, ps, pss);
  stats_final_kernel<<<256, 64, 0, stream>>>(ps, pss, mu2, rs2, 256);
  // x_mod (bf16) = x * sigmoid(gelu(inorm(m_pre)) @ mod_w2^T + mod_b2)
  gemm_mfma_kernel<1, 1, 1, 0><<<dim3(1, 512), 256, 0, stream>>>(
      mpreb, modw2P, mod_b2, xmodb, 128, mu2, rs2, xtokb, nullptr, nullptr);
  // qkv (bf16, head-major) = x_mod @ qkv_w^T + qkv_b
  gemm_mfma_kernel<0, 1, 3, 0><<<dim3(3, 512), 256, 0, stream>>>(
      xmodb, qkvP, qkv_b, qkvh, 384, nullptr, nullptr, nullptr, nullptr, nullptr);
  attn_mfma_kernel<<<dim3(2048, 8, 3), 64, 0, stream>>>(qkvh, Rbuf, pbw, A0b, A1b, A2b);
  proj_mfma_kernel<<<512, 256, 0, stream>>>(A0b, A1b, A2b, projP, proj_b, (float*)d_out);
}

// Round 11
// 279.453 us; speedup vs baseline: 1.0978x; 1.0723x over previous
//
#include <hip/hip_runtime.h>
#include <cstdint>
#include <cstddef>

// ---------------------------------------------------------------------------
// Problem constants: B=2, C=128, D=H=W=32, nh=8, hd=16, L=32
// Tokens: t = b*32768 + d*1024 + h*32 + w   (65536 tokens, 128 channels)
// ---------------------------------------------------------------------------

#define NTOK 65536
#define SPAT 32768

// ws offsets (floats). Same proven map as r7-r10 (136.4 MB).
#define WS_R0     0ull          // region: lf bf16 (8388608 ush) -> A0/A1
#define WS_A0     0ull          // 4194304 (8388608 ush)
#define WS_A1     4194304ull    // 4194304
#define WS_MPREB  8388608ull    // 4194304 (8388608 ush)
#define WS_A2     8388608ull    // 4194304 (overlays dead MPREB)
#define WS_XTOKB  12582912ull   // 4194304 (8388608 ush)
#define WS_INT    16777216ull   // 4194304 (8388608 ush): pos_emb bf16 -> x_mod bf16
#define WS_QKVH   20971520ull   // 12582912 (25165824 ush) [h][t][48]
#define WS_CONVP  33554432ull   // 221184 (442368 ush) [tap][dx][ks][l4][co][8]
#define WS_QKVP   33775616ull   // 24576  (49152 ush)
#define WS_WCP    33800192ull   // 8192
#define WS_MODW2P 33808384ull   // 8192
#define WS_PROJP  33816576ull   // 8192
#define WS_BC     33824768ull   // 128
#define WS_RBUF   33824896ull   // 432
#define WS_PS     33825328ull   // 131072 (1024 blocks x 128)
#define WS_PSS    33956400ull   // 131072
#define WS_MU1    34087472ull   // 256
#define WS_RS1    34087728ull   // 256
#define WS_MU2    34087984ull   // 256
#define WS_RS2    34088240ull   // 256
// total 34088496 floats = 136.4 MB

typedef __attribute__((ext_vector_type(8))) short short8;
typedef __attribute__((ext_vector_type(4))) float f32x4;
typedef __attribute__((ext_vector_type(16))) float f32x16;

__device__ __forceinline__ float gelu_f(float x) {
  return 0.5f * x * (1.0f + erff(x * 0.70710678118654752f));
}
__device__ __forceinline__ float sigmoid_f(float x) {
  return 1.0f / (1.0f + expf(-x));
}
__device__ __forceinline__ unsigned short f2bf(float x) {  // RNE f32->bf16
  unsigned int u = __float_as_uint(x);
  unsigned int r = u + 0x7fffu + ((u >> 16) & 1u);
  return (unsigned short)(r >> 16);
}
__device__ __forceinline__ float bf2f(unsigned short u) {
  return __uint_as_float(((unsigned int)u) << 16);
}
// 16 consecutive bf16 -> 16 fp32
__device__ __forceinline__ void bf16x16_load(const unsigned short* p, float* f) {
  const uint4 a = *(const uint4*)p;
  const uint4 b = *(const uint4*)(p + 8);
  const unsigned int w[8] = {a.x, a.y, a.z, a.w, b.x, b.y, b.z, b.w};
  #pragma unroll
  for (int i = 0; i < 8; ++i) {
    f[2 * i] = __uint_as_float(w[i] << 16);
    f[2 * i + 1] = __uint_as_float(w[i] & 0xffff0000u);
  }
}
// async global->LDS, 16B per lane (dest must be wave-uniform base + lane*16)
__device__ __forceinline__ void gload_lds16(const void* g, void* l) {
  __builtin_amdgcn_global_load_lds(
      (const __attribute__((address_space(1))) unsigned int*)g,
      (__attribute__((address_space(3))) unsigned int*)l, 16, 0, 0);
}
__device__ __forceinline__ float dot3(const float* a, const float* b) {
  return a[0] * b[0] + a[1] * b[1] + a[2] * b[2];
}
__device__ __forceinline__ void cross3(const float* a, const float* b, float* c) {
  c[0] = a[1] * b[2] - a[2] * b[1];
  c[1] = a[2] * b[0] - a[0] * b[2];
  c[2] = a[0] * b[1] - a[1] * b[0];
}

// exact port of _r6_to_matrix for one head (6 floats in, 9 out row-major)
__device__ void r6_to_matrix(const float* r6, float* R) {
  float v1[3] = {r6[0], r6[1], r6[2]};
  float n1 = sqrtf(dot3(v1, v1));
  float inv1 = 1.0f / (n1 + 1e-7f);
  v1[0] *= inv1; v1[1] *= inv1; v1[2] *= inv1;
  float v2[3] = {r6[3], r6[4], r6[5]};
  float d = dot3(v2, v1);
  v2[0] -= d * v1[0]; v2[1] -= d * v1[1]; v2[2] -= d * v1[2];
  float n2 = sqrtf(dot3(v2, v2));
  float inv2 = 1.0f / (n2 + 1e-7f);
  v2[0] *= inv2; v2[1] *= inv2; v2[2] *= inv2;
  float v3[3]; cross3(v1, v2, v3);
  float cx[3]; cross3(v2, v3, cx);
  float det = dot3(v1, cx);
  if (det < 0.0f) { v3[0] = -v3[0]; v3[1] = -v3[1]; v3[2] = -v3[2]; }
  R[0] = v1[0]; R[1] = v1[1]; R[2] = v1[2];
  R[3] = v2[0]; R[4] = v2[1]; R[5] = v2[2];
  R[6] = v3[0]; R[7] = v3[1]; R[8] = v3[2];
}

// exact port of _ensure_matrix for one head (9 in row-major, 9 out)
__device__ void ensure_matrix(const float* Rin, float* Ro) {
  float a[3] = {Rin[0] + 1e-6f, Rin[1] + 1e-6f, Rin[2] + 1e-6f};
  float na = fmaxf(sqrtf(dot3(a, a)), 1e-12f);
  float v1[3] = {a[0] / na, a[1] / na, a[2] / na};
  float b0[3] = {Rin[3], Rin[4], Rin[5]};
  float d = dot3(b0, v1);
  float bb[3] = {b0[0] - d * v1[0] + 1e-6f, b0[1] - d * v1[1] + 1e-6f, b0[2] - d * v1[2] + 1e-6f};
  float nb = fmaxf(sqrtf(dot3(bb, bb)), 1e-12f);
  float v2[3] = {bb[0] / nb, bb[1] / nb, bb[2] / nb};
  float v3[3]; cross3(v1, v2, v3);
  float cx[3]; cross3(v2, v3, cx);
  float det = dot3(v1, cx);
  if (det < 0.0f) { v3[0] = -v3[0]; v3[1] = -v3[1]; v3[2] = -v3[2]; }
  float Rn[9] = {v1[0], v1[1], v1[2], v2[0], v2[1], v2[2], v3[0], v3[1], v3[2]};
  float T1[9], T2[9];
  for (int i = 0; i < 3; ++i)
    for (int j = 0; j < 3; ++j) {
      float s = 0.f;
      for (int k = 0; k < 3; ++k) s += Rn[k * 3 + i] * Rn[k * 3 + j];
      T1[i * 3 + j] = s;
    }
  for (int i = 0; i < 3; ++i)
    for (int j = 0; j < 3; ++j) {
      float s = 0.f;
      for (int k = 0; k < 3; ++k) s += T1[i * 3 + k] * Rn[j * 3 + k];
      T2[i * 3 + j] = s;
    }
  for (int i = 0; i < 9; ++i) Ro[i] = 0.5f * (Rn[i] + T2[i]);
}

// y = R_eff x for hd=16 (5 full 3x3 groups + scalar R00 on ch15)
__device__ __forceinline__ void rot16(const float* R, const float* x, float* y) {
  #pragma unroll
  for (int g = 0; g < 5; ++g) {
    float a = x[3 * g], b = x[3 * g + 1], c = x[3 * g + 2];
    y[3 * g + 0] = R[0] * a + R[1] * b + R[2] * c;
    y[3 * g + 1] = R[3] * a + R[4] * b + R[5] * c;
    y[3 * g + 2] = R[6] * a + R[7] * b + R[8] * c;
  }
  y[15] = R[0] * x[15];
}

// ---------------------------------------------------------------------------
// K0: weight packs (+ rotation matrices in block 0)
// ---------------------------------------------------------------------------
__global__ __launch_bounds__(256) void prep_w_kernel(
    const float* __restrict__ lp_w1, const float* __restrict__ qkv_w,
    const float* __restrict__ mod_w1, const float* __restrict__ lp_w2,
    const float* __restrict__ lp_b2, const float* __restrict__ mod_b1,
    const float* __restrict__ mod_w2, const float* __restrict__ proj_w,
    const float* __restrict__ Ad, const float* __restrict__ Ah,
    const float* __restrict__ Aw, const float* __restrict__ Rd,
    const float* __restrict__ Rh, const float* __restrict__ Rw,
    unsigned short* __restrict__ convP, unsigned short* __restrict__ qkvP,
    unsigned short* __restrict__ WcP, unsigned short* __restrict__ modw2P,
    unsigned short* __restrict__ projP, float* __restrict__ bc,
    float* __restrict__ Rbuf) {
  int gid = blockIdx.x * 256 + threadIdx.x;  // 65536 threads
  for (int f = gid; f < 442368; f += 65536) {
    int e = f & 7;
    int co = (f >> 3) & 127;
    int rest = f >> 10;
    int l4 = rest & 3;
    int ks = (rest >> 2) & 3;
    int dxt = rest >> 4;
    int dx = dxt % 3;
    int tap = dxt / 3;
    int dz = tap / 3, dy = tap % 3;
    int ci = ks * 32 + l4 * 8 + e;
    convP[f] = f2bf(lp_w1[(co * 128 + ci) * 27 + dz * 9 + dy * 3 + dx]);
  }
  if (gid < 49152) qkvP[gid] = f2bf(qkv_w[gid]);
  if (gid < 16384) {
    modw2P[gid] = f2bf(mod_w2[gid]);
    projP[gid] = f2bf(proj_w[gid]);
    int o = gid >> 7, i = gid & 127;
    float s = 0.f;
    for (int c = 0; c < 128; ++c) s += mod_w1[o * 128 + c] * lp_w2[c * 128 + i];
    WcP[gid] = f2bf(s);
  }
  if (gid < 128) {
    float s = 0.f;
    for (int c = 0; c < 128; ++c) s += mod_w1[gid * 128 + c] * lp_b2[c];
    bc[gid] = s + mod_b1[gid];
  }
  if (blockIdx.x == 0 && threadIdx.x >= 224 && threadIdx.x < 248) {
    int tid = threadIdx.x - 224;
    int ax = tid >> 3, h = tid & 7;
    const float* A = (ax == 0) ? Ad : ((ax == 1) ? Ah : Aw);
    const float* R = (ax == 0) ? Rd : ((ax == 1) ? Rh : Rw);
    float Rq[9], Rv[9];
    r6_to_matrix(A + h * 6, Rq);
    ensure_matrix(R + h * 9, Rv);
    float* dst = Rbuf + (ax * 8 + h) * 18;
    for (int i = 0; i < 9; ++i) { dst[i] = Rq[i]; dst[9 + i] = Rv[i]; }
  }
}

// ---------------------------------------------------------------------------
// K0c: merged transposes. Per (b,d,h) plane: x -> xtokb bf16, pos_emb -> inT bf16
// ---------------------------------------------------------------------------
__global__ __launch_bounds__(256) void transpose_kernel(const float* __restrict__ x,
                                                        const float* __restrict__ pe,
                                                        unsigned short* __restrict__ xtokb,
                                                        unsigned short* __restrict__ inT) {
  __shared__ float lds[32][132];
  int blk = blockIdx.x;  // b*1024 + d*32 + h
  int b = blk >> 10;
  int dh = blk & 1023;
  int tid = threadIdx.x;
  size_t planebase = ((size_t)b << 22) + ((size_t)dh << 5);
  size_t tb = ((size_t)blk) << 5;
  #pragma unroll
  for (int r = 0; r < 16; ++r) {
    int idx = r * 256 + tid;
    int ci = idx >> 5, w = idx & 31;
    lds[w][ci] = x[planebase + ((size_t)ci << 15) + w];
  }
  __syncthreads();
  #pragma unroll
  for (int r = 0; r < 16; ++r) {
    int idx = r * 256 + tid;
    int w = idx >> 7, ci = idx & 127;
    xtokb[(tb + w) * 128 + ci] = f2bf(lds[w][ci]);
  }
  __syncthreads();
  #pragma unroll
  for (int r = 0; r < 16; ++r) {
    int idx = r * 256 + tid;
    int ci = idx >> 5, w = idx & 31;
    lds[w][ci] = pe[planebase + ((size_t)ci << 15) + w];
  }
  __syncthreads();
  #pragma unroll
  for (int r = 0; r < 16; ++r) {
    int idx = r * 256 + tid;
    int w = idx >> 7, ci = idx & 127;
    inT[(tb + w) * 128 + ci] = f2bf(lds[w][ci]);
  }
}

// ---------------------------------------------------------------------------
// K1: 3x3x3 circular conv via bf16 MFMA, v7.
// 1024 blocks, 64 tokens (2 h-rows) x 128 co; 4 waves N-split x4:
// each wave = 64 tok x 32 co (acc 4x2). Per iteration: 2 B-frags for 8 MFMAs
// -> B L2 traffic halved vs v6 (4 B/MFMA/lane). Same residency envelope as
// v6: 32KB LDS halo, ~64-80 VGPR, launch_bounds(256,4) -> 4 blocks/CU.
// lf written bf16; fused fp32 stats in epilogue.
// ---------------------------------------------------------------------------
__global__ __launch_bounds__(256, 4) void conv_mfma_kernel(
    const unsigned short* __restrict__ inT, const unsigned short* __restrict__ Bp,
    const float* __restrict__ b1, unsigned short* __restrict__ out,
    float* __restrict__ ps, float* __restrict__ pss) {
  __shared__ unsigned short Als[16384];  // 32KB: 4 rows x 32 w x 128 ci, swizzled
  __shared__ float sumb[128];
  __shared__ float sqb[128];
  const int blk = blockIdx.x;             // 1024 blocks
  const int b = blk >> 9, d = (blk >> 4) & 31, hg = blk & 15;
  const int h0 = hg << 1;                 // 2 output h-rows
  const int tid = threadIdx.x;
  const int lane = tid & 63;
  const int wid = tid >> 6;               // N-split: wave owns co [wid*32, wid*32+32)
  const int l15 = lane & 15, l4 = lane >> 4;

  f32x4 acc[4][2];
  #pragma unroll
  for (int mt = 0; mt < 4; ++mt)
    #pragma unroll
    for (int nt = 0; nt < 2; ++nt)
      #pragma unroll
      for (int r = 0; r < 4; ++r) acc[mt][nt][r] = 0.f;

  int mw[4], mhh[4];
  #pragma unroll
  for (int mt = 0; mt < 4; ++mt) {
    int m = mt * 16 + l15;                // tokens 0..63
    mhh[mt] = m >> 5;
    mw[mt] = m & 31;
  }
  const size_t tokbase = ((size_t)b << 15) + ((size_t)d << 10) + ((size_t)h0 << 5);

  // stage 4-row halo (h0-1 .. h0+2) of plane (d+dz-1) -> 32KB
  auto stage = [&](int dz) {
    const int zr = (d + dz + 31) & 31;
    #pragma unroll
    for (int p = 0; p < 8; ++p) {
      const int g = p * 256 + tid;        // 2048 chunks of 16B
      const int tok = g >> 4, gi = g & 15;
      const int r = tok >> 5, w = tok & 31;
      const int yr = (h0 + r + 31) & 31;
      const size_t srcbyte = ((((size_t)b << 15) + ((size_t)zr << 10) + ((size_t)yr << 5) + w) << 8)
                             + (size_t)((gi ^ (w & 7)) << 4);
      gload_lds16((const char*)inT + srcbyte, (char*)Als + (size_t)g * 16);
    }
  };

  auto compute = [&](int dz) {
    #pragma unroll
    for (int dy = 0; dy < 3; ++dy) {
      const int tap = dz * 3 + dy;
      #pragma unroll
      for (int dx = 0; dx < 3; ++dx) {
        int abase[4], asw[4];
        #pragma unroll
        for (int mt = 0; mt < 4; ++mt) {
          const int wsft = (mw[mt] + dx + 31) & 31;
          const int stok = (mhh[mt] + dy) * 32 + wsft;
          abase[mt] = stok * 256;
          asw[mt] = (wsft & 7) << 4;
        }
        #pragma unroll
        for (int ks = 0; ks < 4; ++ks) {
          const int k2 = (ks * 32 + l4 * 8) * 2;
          const int bbase = (((tap * 3 + dx) * 4 + ks) * 4 + l4) * 1024;
          short8 afr[4], bfr[2];
          #pragma unroll
          for (int nt = 0; nt < 2; ++nt) {
            const int co = wid * 32 + nt * 16 + l15;
            bfr[nt] = *(const short8*)(Bp + bbase + co * 8);
          }
          #pragma unroll
          for (int mt = 0; mt < 4; ++mt)
            afr[mt] = *(const short8*)((const char*)Als + abase[mt] + (k2 ^ asw[mt]));
          __builtin_amdgcn_s_setprio(1);
          #pragma unroll
          for (int mt = 0; mt < 4; ++mt)
            #pragma unroll
            for (int nt = 0; nt < 2; ++nt)
              acc[mt][nt] = __builtin_amdgcn_mfma_f32_16x16x32_bf16(afr[mt], bfr[nt],
                                                                    acc[mt][nt], 0, 0, 0);
          __builtin_amdgcn_s_setprio(0);
        }
      }
    }
  };

  for (int dz = 0; dz < 3; ++dz) {
    stage(dz);
    __syncthreads();   // stage complete (drains vmcnt)
    compute(dz);
    if (dz < 2) __syncthreads();  // all reads done before next stage overwrites
  }

  // epilogue: bias + bf16 store + fused fp32 stats partials
  // each co owned by exactly one (wid, nt, l15)
  #pragma unroll
  for (int nt = 0; nt < 2; ++nt) {
    const int co = wid * 32 + nt * 16 + l15;
    const float bias = b1[co];
    float s = 0.f, q = 0.f;
    #pragma unroll
    for (int mt = 0; mt < 4; ++mt) {
      #pragma unroll
      for (int r = 0; r < 4; ++r) {
        const int m = mt * 16 + l4 * 4 + r;
        const float v = acc[mt][nt][r] + bias;
        out[(tokbase + m) * 128 + co] = f2bf(v);
        s += v; q += v * v;
      }
    }
    s += __shfl_xor(s, 16); s += __shfl_xor(s, 32);
    q += __shfl_xor(q, 16); q += __shfl_xor(q, 32);
    if (l4 == 0) { sumb[co] = s; sqb[co] = q; }
  }
  __syncthreads();
  if (tid < 128) {
    ps[blk * 128 + tid] = sumb[tid];
    pss[blk * 128 + tid] = sqb[tid];
  }
}

// ---------------------------------------------------------------------------
// K2: stats finalize, parallel
// ---------------------------------------------------------------------------
__global__ __launch_bounds__(64) void stats_final_kernel(
    const float* __restrict__ ps, const float* __restrict__ pss,
    float* __restrict__ mu, float* __restrict__ rs, int nb) {
  const int pair = blockIdx.x;  // b*128 + c
  const int b = pair >> 7, c = pair & 127;
  const int lane = threadIdx.x;
  float s = 0.f, ss = 0.f;
  for (int j = lane; j < nb; j += 64) {
    const int idx = ((b * nb + j) << 7) + c;
    s += ps[idx];
    ss += pss[idx];
  }
  #pragma unroll
  for (int o = 32; o > 0; o >>= 1) {
    s += __shfl_xor(s, o);
    ss += __shfl_xor(ss, o);
  }
  if (lane == 0) {
    float m = s * (1.0f / 32768.0f);
    float v = ss * (1.0f / 32768.0f) - m * m;
    mu[pair] = m;
    rs[pair] = rsqrtf(v + 1e-5f);
  }
}

// ---------------------------------------------------------------------------
// K3: 1x1 GEMM via bf16 MFMA, register-only (r7 proven).
// ---------------------------------------------------------------------------
template <int PRE, int AB16, int POST, int STATS>
__global__ __launch_bounds__(256) void gemm_mfma_kernel(
    const void* __restrict__ Avoid, const unsigned short* __restrict__ Wp,
    const float* __restrict__ bias, void* __restrict__ Yvoid, int O,
    const float* __restrict__ mu, const float* __restrict__ rs,
    const unsigned short* __restrict__ xtb, float* __restrict__ ps,
    float* __restrict__ pss) {
  __shared__ float sumb[128][2];
  __shared__ float sqb[128][2];
  const int tid = threadIdx.x;
  const int lane = tid & 63, wid = tid >> 6;
  const int wm = wid >> 1, wn = wid & 1;
  const int l15 = lane & 15, l4 = lane >> 4;
  const int og = blockIdx.x * 128;
  const int t0 = blockIdx.y * 128;
  const int bidx = t0 >> 15;
  const float* Af = (const float*)Avoid;
  const unsigned short* Ab = (const unsigned short*)Avoid;
  float* Yf = (float*)Yvoid;
  unsigned short* Yb = (unsigned short*)Yvoid;

  f32x4 acc[4][4];
  #pragma unroll
  for (int mt = 0; mt < 4; ++mt)
    #pragma unroll
    for (int nt = 0; nt < 4; ++nt)
      #pragma unroll
      for (int r = 0; r < 4; ++r) acc[mt][nt][r] = 0.f;

  #pragma unroll
  for (int ks = 0; ks < 4; ++ks) {
    const int kb = ks * 32 + l4 * 8;
    short8 a[4], bfr[4];
    float4 m0, m1, r0, r1;
    if constexpr (PRE == 1) {
      m0 = *(const float4*)(mu + bidx * 128 + kb);
      m1 = *(const float4*)(mu + bidx * 128 + kb + 4);
      r0 = *(const float4*)(rs + bidx * 128 + kb);
      r1 = *(const float4*)(rs + bidx * 128 + kb + 4);
    }
    #pragma unroll
    for (int mt = 0; mt < 4; ++mt) {
      const int tok = t0 + wm * 64 + mt * 16 + l15;
      float v[16];
      bool have = false;
      if constexpr (AB16 == 1) {
        if constexpr (PRE == 1) {
          bf16x16_load(Ab + (size_t)tok * 128 + kb, v);
          have = true;
        } else {
          a[mt] = *(const short8*)(Ab + (size_t)tok * 128 + kb);
        }
      } else {
        const float* ap = Af + (size_t)tok * 128 + kb;
        float4 v0 = *(const float4*)ap;
        float4 v1 = *(const float4*)(ap + 4);
        v[0] = v0.x; v[1] = v0.y; v[2] = v0.z; v[3] = v0.w;
        v[4] = v1.x; v[5] = v1.y; v[6] = v1.z; v[7] = v1.w;
        have = true;
      }
      if (have) {
        if constexpr (PRE == 1) {
          const float mm[8] = {m0.x, m0.y, m0.z, m0.w, m1.x, m1.y, m1.z, m1.w};
          const float rr[8] = {r0.x, r0.y, r0.z, r0.w, r1.x, r1.y, r1.z, r1.w};
          #pragma unroll
          for (int j = 0; j < 8; ++j) v[j] = gelu_f((v[j] - mm[j]) * rr[j]);
        }
        short8 t;
        #pragma unroll
        for (int j = 0; j < 8; ++j) t[j] = (short)f2bf(v[j]);
        a[mt] = t;
      }
    }
    #pragma unroll
    for (int nt = 0; nt < 4; ++nt) {
      const int o = og + wn * 64 + nt * 16 + l15;
      bfr[nt] = *(const short8*)(Wp + (size_t)o * 128 + kb);
    }
    #pragma unroll
    for (int mt = 0; mt < 4; ++mt)
      #pragma unroll
      for (int nt = 0; nt < 4; ++nt)
        acc[mt][nt] = __builtin_amdgcn_mfma_f32_16x16x32_bf16(a[mt], bfr[nt], acc[mt][nt], 0, 0, 0);
  }

  #pragma unroll
  for (int nt = 0; nt < 4; ++nt) {
    const int o = og + wn * 64 + nt * 16 + l15;
    const float bb = bias[o];
    float s = 0.f, q = 0.f;
    #pragma unroll
    for (int mt = 0; mt < 4; ++mt) {
      #pragma unroll
      for (int r = 0; r < 4; ++r) {
        const int t = t0 + wm * 64 + mt * 16 + l4 * 4 + r;
        const float v = acc[mt][nt][r] + bb;
        if constexpr (POST == 0) {
          Yf[(size_t)t * O + o] = v;
        } else if constexpr (POST == 1) {
          Yb[(size_t)t * 128 + o] = f2bf(sigmoid_f(v) * bf2f(xtb[(size_t)t * 128 + o]));
        } else if constexpr (POST == 2) {
          Yb[(size_t)t * O + o] = f2bf(v);
        } else {
          const int which = o >> 7, hsub = (o & 127) >> 4, ch = o & 15;
          Yb[((size_t)hsub * NTOK + t) * 48 + which * 16 + ch] = f2bf(v);
        }
        if constexpr (STATS) { s += v; q += v * v; }
      }
    }
    if constexpr (STATS) {
      s += __shfl_xor(s, 16); s += __shfl_xor(s, 32);
      q += __shfl_xor(q, 16); q += __shfl_xor(q, 32);
      if (l4 == 0) { sumb[o - og][wm] = s; sqb[o - og][wm] = q; }
    }
  }
  if constexpr (STATS) {
    __syncthreads();
    if (tid < 128) {
      ps[blockIdx.y * 128 + tid] = sumb[tid][0] + sumb[tid][1];
      pss[blockIdx.y * 128 + tid] = sqb[tid][0] + sqb[tid][1];
    }
  }
}

// ---------------------------------------------------------------------------
// K6: final projection over A0+A1+A2 (bf16), swapped orientation -> NCDHW
// ---------------------------------------------------------------------------
__global__ __launch_bounds__(256) void proj_mfma_kernel(
    const unsigned short* __restrict__ A0b, const unsigned short* __restrict__ A1b,
    const unsigned short* __restrict__ A2b, const unsigned short* __restrict__ Wp,
    const float* __restrict__ bias, float* __restrict__ out) {
  const int tid = threadIdx.x;
  const int lane = tid & 63, wid = tid >> 6;
  const int wm = wid >> 1, wn = wid & 1;
  const int l15 = lane & 15, l4 = lane >> 4;
  const int t0 = blockIdx.x * 128;

  f32x4 acc[4][4];
  #pragma unroll
  for (int mt = 0; mt < 4; ++mt)
    #pragma unroll
    for (int nt = 0; nt < 4; ++nt)
      #pragma unroll
      for (int r = 0; r < 4; ++r) acc[mt][nt][r] = 0.f;

  #pragma unroll
  for (int ks = 0; ks < 4; ++ks) {
    const int kb = ks * 32 + l4 * 8;
    short8 a[4], bfr[4];
    #pragma unroll
    for (int mt = 0; mt < 4; ++mt) {
      const int o = wm * 64 + mt * 16 + l15;
      a[mt] = *(const short8*)(Wp + (size_t)o * 128 + kb);
    }
    #pragma unroll
    for (int nt = 0; nt < 4; ++nt) {
      const int tok = t0 + wn * 64 + nt * 16 + l15;
      const size_t off = (size_t)tok * 128 + kb;
      short8 s0 = *(const short8*)(A0b + off);
      short8 s1 = *(const short8*)(A1b + off);
      short8 s2 = *(const short8*)(A2b + off);
      short8 r;
      #pragma unroll
      for (int i = 0; i < 8; ++i) {
        float f = bf2f((unsigned short)s0[i]) + bf2f((unsigned short)s1[i]) +
                  bf2f((unsigned short)s2[i]);
        r[i] = (short)f2bf(f);
      }
      bfr[nt] = r;
    }
    #pragma unroll
    for (int mt = 0; mt < 4; ++mt)
      #pragma unroll
      for (int nt = 0; nt < 4; ++nt)
        acc[mt][nt] = __builtin_amdgcn_mfma_f32_16x16x32_bf16(a[mt], bfr[nt], acc[mt][nt], 0, 0, 0);
  }

  #pragma unroll
  for (int nt = 0; nt < 4; ++nt) {
    const int tok = t0 + wn * 64 + nt * 16 + l15;
    const int dhw = tok & 32767, bB = tok >> 15;
    #pragma unroll
    for (int mt = 0; mt < 4; ++mt) {
      #pragma unroll
      for (int r = 0; r < 4; ++r) {
        const int o = wm * 64 + mt * 16 + l4 * 4 + r;
        out[((size_t)(bB * 128 + o) << 15) + dhw] = acc[mt][nt][r] + bias[o];
      }
    }
  }
}

// ---------------------------------------------------------------------------
// K7: axial attention via MFMA (r8 proven). One wave per (seq, head, axial).
// ---------------------------------------------------------------------------
__global__ __launch_bounds__(64) void attn_mfma_kernel(
    const unsigned short* __restrict__ qkvh, const float* __restrict__ Rbuf,
    const float* __restrict__ pbw, unsigned short* __restrict__ a0,
    unsigned short* __restrict__ a1, unsigned short* __restrict__ a2) {
  __shared__ unsigned short Vt[16 * 40];  // [d][tok], row pad 40 shorts
  __shared__ float Ot[32 * 20];           // [tok][d], row pad 20 floats
  const int axial = blockIdx.z;
  const int head = blockIdx.y;
  const int seq = blockIdx.x;
  unsigned short* dstbuf = (axial == 0) ? a0 : ((axial == 1) ? a1 : a2);
  const int lane = threadIdx.x;
  const int tok = lane & 31, hi = lane >> 5;
  const int b = seq >> 10, rem = seq & 1023;
  const int u = rem >> 5, v = rem & 31;
  int base, stride, comp;
  if (axial == 0)      { base = (b << 15) + (u << 5) + v;         stride = 1024; comp = 2; }
  else if (axial == 1) { base = (b << 15) + (u << 10) + v;        stride = 32;   comp = 1; }
  else                 { base = (b << 15) + (u << 10) + (v << 5); stride = 1;    comp = 0; }
  const float* Rp = Rbuf + (axial * 8 + head) * 18;
  const float rq00 = fabsf(Rp[0]);
  const size_t t_tok = (size_t)base + (size_t)tok * stride;
  const unsigned short* row = qkvh + (size_t)head * ((size_t)NTOK * 48) + t_tok * 48;
  short8 aq = *(const short8*)(row + hi * 8);
  short8 ak = *(const short8*)(row + 16 + hi * 8);
  short8 av = *(const short8*)(row + 32 + hi * 8);
  if (hi) {  // ch15 carries the R00^2 correction
    aq[7] = (short)f2bf(bf2f((unsigned short)aq[7]) * rq00);
    ak[7] = (short)f2bf(bf2f((unsigned short)ak[7]) * rq00);
  }
  #pragma unroll
  for (int e = 0; e < 8; ++e) Vt[(hi * 8 + e) * 40 + tok] = (unsigned short)av[e];
  __syncthreads();
  f32x16 sacc;
  #pragma unroll
  for (int r = 0; r < 16; ++r) sacc[r] = 0.f;
  sacc = __builtin_amdgcn_mfma_f32_32x32x16_bf16(ak, aq, sacc, 0, 0, 0);
  const float wb = pbw[comp];
  float p[16];
  float mmax = -1e30f;
  #pragma unroll
  for (int r = 0; r < 16; ++r) {
    const int kk = (r & 3) + 4 * hi + 8 * (r >> 2);
    const float lin = -1.0f + (2.0f / 31.0f) * (float)kk;
    p[r] = sacc[r] * 0.25f - lin * wb;
    mmax = fmaxf(mmax, p[r]);
  }
  mmax = fmaxf(mmax, __shfl_xor(mmax, 32));
  float sum = 0.f;
  #pragma unroll
  for (int r = 0; r < 16; ++r) { p[r] = expf(p[r] - mmax); sum += p[r]; }
  sum += __shfl_xor(sum, 32);
  const float inv = 1.0f / sum;
  #pragma unroll
  for (int r = 0; r < 16; ++r) p[r] *= inv;
  unsigned pk[8], sw[8];
  #pragma unroll
  for (int j = 0; j < 8; ++j) {
    unsigned r_;
    asm("v_cvt_pk_bf16_f32 %0, %1, %2" : "=v"(r_) : "v"(p[2 * j]), "v"(p[2 * j + 1]));
    pk[j] = r_;
  }
  #pragma unroll
  for (int j = 0; j < 8; ++j) sw[j] = (unsigned)__shfl_xor((int)pk[j], 32);
  uint4 Fu, Gu;
  Fu.x = hi ? sw[2] : pk[0];
  Fu.y = hi ? sw[3] : pk[1];
  Fu.z = hi ? pk[2] : sw[0];
  Fu.w = hi ? pk[3] : sw[1];
  Gu.x = hi ? sw[6] : pk[4];
  Gu.y = hi ? sw[7] : pk[5];
  Gu.z = hi ? pk[6] : sw[4];
  Gu.w = hi ? pk[7] : sw[5];
  short8 Pf = *(short8*)&Fu;
  short8 Pg = *(short8*)&Gu;
  const unsigned short* vrow = Vt + (tok & 15) * 40;
  short8 Bv0 = *(const short8*)(vrow + hi * 8);
  short8 Bv1 = *(const short8*)(vrow + 16 + hi * 8);
  f32x16 oacc;
  #pragma unroll
  for (int r = 0; r < 16; ++r) oacc[r] = 0.f;
  oacc = __builtin_amdgcn_mfma_f32_32x32x16_bf16(Pf, Bv0, oacc, 0, 0, 0);
  oacc = __builtin_amdgcn_mfma_f32_32x32x16_bf16(Pg, Bv1, oacc, 0, 0, 0);
  if (tok < 16) {
    #pragma unroll
    for (int r = 0; r < 16; ++r) {
      const int q = (r & 3) + 4 * hi + 8 * (r >> 2);
      Ot[q * 20 + tok] = oacc[r];
    }
  }
  __syncthreads();
  if (lane < 32) {
    float o16[16], y16[16], Rv[9];
    #pragma unroll
    for (int j = 0; j < 16; ++j) o16[j] = Ot[lane * 20 + j];
    #pragma unroll
    for (int i = 0; i < 9; ++i) Rv[i] = Rp[9 + i];
    rot16(Rv, o16, y16);
    unsigned outw[8];
    #pragma unroll
    for (int j = 0; j < 8; ++j)
      outw[j] = ((unsigned)f2bf(y16[2 * j + 1]) << 16) | (unsigned)f2bf(y16[2 * j]);
    const size_t t2 = (size_t)base + (size_t)lane * stride;
    unsigned short* dst = dstbuf + t2 * 128 + head * 16;
    uint4 o0 = {outw[0], outw[1], outw[2], outw[3]};
    uint4 o1 = {outw[4], outw[5], outw[6], outw[7]};
    *(uint4*)dst = o0;
    *(uint4*)(dst + 8) = o1;
  }
}

// ---------------------------------------------------------------------------
extern "C" void kernel_launch(void* const* d_in, const int* in_sizes, int n_in,
                              void* d_out, int out_size, void* d_ws, size_t ws_size,
                              hipStream_t stream) {
  const float* x       = (const float*)d_in[0];
  const float* pos_emb = (const float*)d_in[1];
  const float* qkv_w   = (const float*)d_in[2];
  const float* qkv_b   = (const float*)d_in[3];
  const float* lp_w1   = (const float*)d_in[4];
  const float* lp_b1   = (const float*)d_in[5];
  const float* lp_w2   = (const float*)d_in[6];
  const float* lp_b2   = (const float*)d_in[7];
  const float* mod_w1  = (const float*)d_in[8];
  const float* mod_b1  = (const float*)d_in[9];
  const float* mod_w2  = (const float*)d_in[10];
  const float* mod_b2  = (const float*)d_in[11];
  // d_in[12] pa_w, d_in[13] pa_b: cancel in softmax (constant along key axis)
  const float* proj_w  = (const float*)d_in[14];
  const float* proj_b  = (const float*)d_in[15];
  const float* pbw     = (const float*)d_in[16];
  // d_in[17] pos_bias_b: cancels in softmax
  const float* Ad      = (const float*)d_in[18];
  const float* Ah      = (const float*)d_in[19];
  const float* Aw      = (const float*)d_in[20];
  const float* Rd      = (const float*)d_in[21];
  const float* Rh      = (const float*)d_in[22];
  const float* Rw      = (const float*)d_in[23];
  // d_in[24..26] t_d/t_h/t_w: cancel in rel (pairwise difference)

  float* ws = (float*)d_ws;
  unsigned short* lfb    = (unsigned short*)(ws + WS_R0);   // lf bf16
  unsigned short* A0b    = (unsigned short*)(ws + WS_A0);
  unsigned short* A1b    = (unsigned short*)(ws + WS_A1);
  unsigned short* A2b    = (unsigned short*)(ws + WS_A2);
  unsigned short* mpreb  = (unsigned short*)(ws + WS_MPREB);
  unsigned short* xtokb  = (unsigned short*)(ws + WS_XTOKB);
  unsigned short* inT    = (unsigned short*)(ws + WS_INT);
  unsigned short* qkvh   = (unsigned short*)(ws + WS_QKVH);
  unsigned short* convP  = (unsigned short*)(ws + WS_CONVP);
  unsigned short* qkvP   = (unsigned short*)(ws + WS_QKVP);
  unsigned short* WcP    = (unsigned short*)(ws + WS_WCP);
  unsigned short* modw2P = (unsigned short*)(ws + WS_MODW2P);
  unsigned short* projP  = (unsigned short*)(ws + WS_PROJP);
  float* bc     = ws + WS_BC;
  float* Rbuf   = ws + WS_RBUF;
  float* ps     = ws + WS_PS;
  float* pss    = ws + WS_PSS;
  float* mu1    = ws + WS_MU1;
  float* rs1    = ws + WS_RS1;
  float* mu2    = ws + WS_MU2;
  float* rs2    = ws + WS_RS2;
  unsigned short* xmodb = inT;  // x_mod bf16 reuses INT region (inT dead after conv)

  prep_w_kernel<<<256, 256, 0, stream>>>(lp_w1, qkv_w, mod_w1, lp_w2, lp_b2, mod_b1,
                                         mod_w2, proj_w, Ad, Ah, Aw, Rd, Rh, Rw,
                                         convP, qkvP, WcP, modw2P, projP, bc, Rbuf);
  transpose_kernel<<<2048, 256, 0, stream>>>(x, pos_emb, xtokb, inT);
  // lf (bf16) = circular conv3x3x3(pos_emb), fused fp32 stats partials
  conv_mfma_kernel<<<1024, 256, 0, stream>>>(inT, convP, lp_b1, lfb, ps, pss);
  stats_final_kernel<<<256, 64, 0, stream>>>(ps, pss, mu1, rs1, 512);
  // m_pre (bf16) = gelu(inorm(lf)) @ Wc^T + bc, fused stats partials
  gemm_mfma_kernel<1, 1, 2, 1><<<dim3(1, 512), 256, 0, stream>>>(
      lfb, WcP, bc, mpreb, 128, mu1, rs1, nullptr, ps, pss);
  stats_final_kernel<<<256, 64, 0, stream>>>(ps, pss, mu2, rs2, 256);
  // x_mod (bf16) = x * sigmoid(gelu(inorm(m_pre)) @ mod_w2^T + mod_b2)
  gemm_mfma_kernel<1, 1, 1, 0><<<dim3(1, 512), 256, 0, stream>>>(
      mpreb, modw2P, mod_b2, xmodb, 128, mu2, rs2, xtokb, nullptr, nullptr);
  // qkv (bf16, head-major) = x_mod @ qkv_w^T + qkv_b
  gemm_mfma_kernel<0, 1, 3, 0><<<dim3(3, 512), 256, 0, stream>>>(
      xmodb, qkvP, qkv_b, qkvh, 384, nullptr, nullptr, nullptr, nullptr, nullptr);
  attn_mfma_kernel<<<dim3(2048, 8, 3), 64, 0, stream>>>(qkvh, Rbuf, pbw, A0b, A1b, A2b);
  proj_mfma_kernel<<<512, 256, 0, stream>>>(A0b, A1b, A2b, projP, proj_b, (float*)d_out);
}

// Round 12
// 274.145 us; speedup vs baseline: 1.1191x; 1.0194x over previous
//
#include <hip/hip_runtime.h>
#include <cstdint>
#include <cstddef>

// ---------------------------------------------------------------------------
// Problem constants: B=2, C=128, D=H=W=32, nh=8, hd=16, L=32
// Tokens: t = b*32768 + d*1024 + h*32 + w   (65536 tokens, 128 channels)
// ---------------------------------------------------------------------------

#define NTOK 65536
#define SPAT 32768

// ws offsets (floats). Same proven map as r7-r11 (136.4 MB).
#define WS_R0     0ull          // region: lf bf16 (8388608 ush) -> A0/A1
#define WS_A0     0ull          // 4194304 (8388608 ush)
#define WS_A1     4194304ull    // 4194304
#define WS_MPREB  8388608ull    // 4194304 (8388608 ush)
#define WS_A2     8388608ull    // 4194304 (overlays dead MPREB)
#define WS_XTOKB  12582912ull   // 4194304 (8388608 ush)
#define WS_INT    16777216ull   // 4194304 (8388608 ush): pos_emb bf16 -> x_mod bf16
#define WS_QKVH   20971520ull   // 12582912 (25165824 ush) [t][h*48+sec*16+ch]
#define WS_CONVP  33554432ull   // 221184 (442368 ush) [tap][dx][ks][l4][co][8]
#define WS_QKVP   33775616ull   // 24576  (49152 ush)
#define WS_WCP    33800192ull   // 8192
#define WS_MODW2P 33808384ull   // 8192
#define WS_PROJP  33816576ull   // 8192
#define WS_BC     33824768ull   // 128
#define WS_RBUF   33824896ull   // 432
#define WS_PS     33825328ull   // 131072 (1024 blocks x 128)
#define WS_PSS    33956400ull   // 131072
#define WS_MU1    34087472ull   // 256
#define WS_RS1    34087728ull   // 256
#define WS_MU2    34087984ull   // 256
#define WS_RS2    34088240ull   // 256
// total 34088496 floats = 136.4 MB

typedef __attribute__((ext_vector_type(8))) short short8;
typedef __attribute__((ext_vector_type(4))) float f32x4;
typedef __attribute__((ext_vector_type(16))) float f32x16;

__device__ __forceinline__ float gelu_f(float x) {
  return 0.5f * x * (1.0f + erff(x * 0.70710678118654752f));
}
__device__ __forceinline__ float sigmoid_f(float x) {
  return 1.0f / (1.0f + expf(-x));
}
__device__ __forceinline__ unsigned short f2bf(float x) {  // RNE f32->bf16
  unsigned int u = __float_as_uint(x);
  unsigned int r = u + 0x7fffu + ((u >> 16) & 1u);
  return (unsigned short)(r >> 16);
}
__device__ __forceinline__ float bf2f(unsigned short u) {
  return __uint_as_float(((unsigned int)u) << 16);
}
// 16 consecutive bf16 -> 16 fp32
__device__ __forceinline__ void bf16x16_load(const unsigned short* p, float* f) {
  const uint4 a = *(const uint4*)p;
  const uint4 b = *(const uint4*)(p + 8);
  const unsigned int w[8] = {a.x, a.y, a.z, a.w, b.x, b.y, b.z, b.w};
  #pragma unroll
  for (int i = 0; i < 8; ++i) {
    f[2 * i] = __uint_as_float(w[i] << 16);
    f[2 * i + 1] = __uint_as_float(w[i] & 0xffff0000u);
  }
}
// async global->LDS, 16B per lane (dest must be wave-uniform base + lane*16)
__device__ __forceinline__ void gload_lds16(const void* g, void* l) {
  __builtin_amdgcn_global_load_lds(
      (const __attribute__((address_space(1))) unsigned int*)g,
      (__attribute__((address_space(3))) unsigned int*)l, 16, 0, 0);
}
__device__ __forceinline__ float dot3(const float* a, const float* b) {
  return a[0] * b[0] + a[1] * b[1] + a[2] * b[2];
}
__device__ __forceinline__ void cross3(const float* a, const float* b, float* c) {
  c[0] = a[1] * b[2] - a[2] * b[1];
  c[1] = a[2] * b[0] - a[0] * b[2];
  c[2] = a[0] * b[1] - a[1] * b[0];
}

// exact port of _r6_to_matrix for one head (6 floats in, 9 out row-major)
__device__ void r6_to_matrix(const float* r6, float* R) {
  float v1[3] = {r6[0], r6[1], r6[2]};
  float n1 = sqrtf(dot3(v1, v1));
  float inv1 = 1.0f / (n1 + 1e-7f);
  v1[0] *= inv1; v1[1] *= inv1; v1[2] *= inv1;
  float v2[3] = {r6[3], r6[4], r6[5]};
  float d = dot3(v2, v1);
  v2[0] -= d * v1[0]; v2[1] -= d * v1[1]; v2[2] -= d * v1[2];
  float n2 = sqrtf(dot3(v2, v2));
  float inv2 = 1.0f / (n2 + 1e-7f);
  v2[0] *= inv2; v2[1] *= inv2; v2[2] *= inv2;
  float v3[3]; cross3(v1, v2, v3);
  float cx[3]; cross3(v2, v3, cx);
  float det = dot3(v1, cx);
  if (det < 0.0f) { v3[0] = -v3[0]; v3[1] = -v3[1]; v3[2] = -v3[2]; }
  R[0] = v1[0]; R[1] = v1[1]; R[2] = v1[2];
  R[3] = v2[0]; R[4] = v2[1]; R[5] = v2[2];
  R[6] = v3[0]; R[7] = v3[1]; R[8] = v3[2];
}

// exact port of _ensure_matrix for one head (9 in row-major, 9 out)
__device__ void ensure_matrix(const float* Rin, float* Ro) {
  float a[3] = {Rin[0] + 1e-6f, Rin[1] + 1e-6f, Rin[2] + 1e-6f};
  float na = fmaxf(sqrtf(dot3(a, a)), 1e-12f);
  float v1[3] = {a[0] / na, a[1] / na, a[2] / na};
  float b0[3] = {Rin[3], Rin[4], Rin[5]};
  float d = dot3(b0, v1);
  float bb[3] = {b0[0] - d * v1[0] + 1e-6f, b0[1] - d * v1[1] + 1e-6f, b0[2] - d * v1[2] + 1e-6f};
  float nb = fmaxf(sqrtf(dot3(bb, bb)), 1e-12f);
  float v2[3] = {bb[0] / nb, bb[1] / nb, bb[2] / nb};
  float v3[3]; cross3(v1, v2, v3);
  float cx[3]; cross3(v2, v3, cx);
  float det = dot3(v1, cx);
  if (det < 0.0f) { v3[0] = -v3[0]; v3[1] = -v3[1]; v3[2] = -v3[2]; }
  float Rn[9] = {v1[0], v1[1], v1[2], v2[0], v2[1], v2[2], v3[0], v3[1], v3[2]};
  float T1[9], T2[9];
  for (int i = 0; i < 3; ++i)
    for (int j = 0; j < 3; ++j) {
      float s = 0.f;
      for (int k = 0; k < 3; ++k) s += Rn[k * 3 + i] * Rn[k * 3 + j];
      T1[i * 3 + j] = s;
    }
  for (int i = 0; i < 3; ++i)
    for (int j = 0; j < 3; ++j) {
      float s = 0.f;
      for (int k = 0; k < 3; ++k) s += T1[i * 3 + k] * Rn[j * 3 + k];
      T2[i * 3 + j] = s;
    }
  for (int i = 0; i < 9; ++i) Ro[i] = 0.5f * (Rn[i] + T2[i]);
}

// y = R_eff x for hd=16 (5 full 3x3 groups + scalar R00 on ch15)
__device__ __forceinline__ void rot16(const float* R, const float* x, float* y) {
  #pragma unroll
  for (int g = 0; g < 5; ++g) {
    float a = x[3 * g], b = x[3 * g + 1], c = x[3 * g + 2];
    y[3 * g + 0] = R[0] * a + R[1] * b + R[2] * c;
    y[3 * g + 1] = R[3] * a + R[4] * b + R[5] * c;
    y[3 * g + 2] = R[6] * a + R[7] * b + R[8] * c;
  }
  y[15] = R[0] * x[15];
}

// ---------------------------------------------------------------------------
// K0: weight packs (+ rotation matrices in block 0)
// ---------------------------------------------------------------------------
__global__ __launch_bounds__(256) void prep_w_kernel(
    const float* __restrict__ lp_w1, const float* __restrict__ qkv_w,
    const float* __restrict__ mod_w1, const float* __restrict__ lp_w2,
    const float* __restrict__ lp_b2, const float* __restrict__ mod_b1,
    const float* __restrict__ mod_w2, const float* __restrict__ proj_w,
    const float* __restrict__ Ad, const float* __restrict__ Ah,
    const float* __restrict__ Aw, const float* __restrict__ Rd,
    const float* __restrict__ Rh, const float* __restrict__ Rw,
    unsigned short* __restrict__ convP, unsigned short* __restrict__ qkvP,
    unsigned short* __restrict__ WcP, unsigned short* __restrict__ modw2P,
    unsigned short* __restrict__ projP, float* __restrict__ bc,
    float* __restrict__ Rbuf) {
  int gid = blockIdx.x * 256 + threadIdx.x;  // 65536 threads
  for (int f = gid; f < 442368; f += 65536) {
    int e = f & 7;
    int co = (f >> 3) & 127;
    int rest = f >> 10;
    int l4 = rest & 3;
    int ks = (rest >> 2) & 3;
    int dxt = rest >> 4;
    int dx = dxt % 3;
    int tap = dxt / 3;
    int dz = tap / 3, dy = tap % 3;
    int ci = ks * 32 + l4 * 8 + e;
    convP[f] = f2bf(lp_w1[(co * 128 + ci) * 27 + dz * 9 + dy * 3 + dx]);
  }
  if (gid < 49152) qkvP[gid] = f2bf(qkv_w[gid]);
  if (gid < 16384) {
    modw2P[gid] = f2bf(mod_w2[gid]);
    projP[gid] = f2bf(proj_w[gid]);
    int o = gid >> 7, i = gid & 127;
    float s = 0.f;
    for (int c = 0; c < 128; ++c) s += mod_w1[o * 128 + c] * lp_w2[c * 128 + i];
    WcP[gid] = f2bf(s);
  }
  if (gid < 128) {
    float s = 0.f;
    for (int c = 0; c < 128; ++c) s += mod_w1[gid * 128 + c] * lp_b2[c];
    bc[gid] = s + mod_b1[gid];
  }
  if (blockIdx.x == 0 && threadIdx.x >= 224 && threadIdx.x < 248) {
    int tid = threadIdx.x - 224;
    int ax = tid >> 3, h = tid & 7;
    const float* A = (ax == 0) ? Ad : ((ax == 1) ? Ah : Aw);
    const float* R = (ax == 0) ? Rd : ((ax == 1) ? Rh : Rw);
    float Rq[9], Rv[9];
    r6_to_matrix(A + h * 6, Rq);
    ensure_matrix(R + h * 9, Rv);
    float* dst = Rbuf + (ax * 8 + h) * 18;
    for (int i = 0; i < 9; ++i) { dst[i] = Rq[i]; dst[9 + i] = Rv[i]; }
  }
}

// ---------------------------------------------------------------------------
// K0c: merged transposes. Per (b,d,h) plane: x -> xtokb bf16, pos_emb -> inT bf16
// ---------------------------------------------------------------------------
__global__ __launch_bounds__(256) void transpose_kernel(const float* __restrict__ x,
                                                        const float* __restrict__ pe,
                                                        unsigned short* __restrict__ xtokb,
                                                        unsigned short* __restrict__ inT) {
  __shared__ float lds[32][132];
  int blk = blockIdx.x;  // b*1024 + d*32 + h
  int b = blk >> 10;
  int dh = blk & 1023;
  int tid = threadIdx.x;
  size_t planebase = ((size_t)b << 22) + ((size_t)dh << 5);
  size_t tb = ((size_t)blk) << 5;
  #pragma unroll
  for (int r = 0; r < 16; ++r) {
    int idx = r * 256 + tid;
    int ci = idx >> 5, w = idx & 31;
    lds[w][ci] = x[planebase + ((size_t)ci << 15) + w];
  }
  __syncthreads();
  #pragma unroll
  for (int r = 0; r < 16; ++r) {
    int idx = r * 256 + tid;
    int w = idx >> 7, ci = idx & 127;
    xtokb[(tb + w) * 128 + ci] = f2bf(lds[w][ci]);
  }
  __syncthreads();
  #pragma unroll
  for (int r = 0; r < 16; ++r) {
    int idx = r * 256 + tid;
    int ci = idx >> 5, w = idx & 31;
    lds[w][ci] = pe[planebase + ((size_t)ci << 15) + w];
  }
  __syncthreads();
  #pragma unroll
  for (int r = 0; r < 16; ++r) {
    int idx = r * 256 + tid;
    int w = idx >> 7, ci = idx & 127;
    inT[(tb + w) * 128 + ci] = f2bf(lds[w][ci]);
  }
}

// ---------------------------------------------------------------------------
// K1: 3x3x3 circular conv via bf16 MFMA, v7 (r11 proven, 65 us).
// ---------------------------------------------------------------------------
__global__ __launch_bounds__(256, 4) void conv_mfma_kernel(
    const unsigned short* __restrict__ inT, const unsigned short* __restrict__ Bp,
    const float* __restrict__ b1, unsigned short* __restrict__ out,
    float* __restrict__ ps, float* __restrict__ pss) {
  __shared__ unsigned short Als[16384];  // 32KB: 4 rows x 32 w x 128 ci, swizzled
  __shared__ float sumb[128];
  __shared__ float sqb[128];
  const int blk = blockIdx.x;             // 1024 blocks
  const int b = blk >> 9, d = (blk >> 4) & 31, hg = blk & 15;
  const int h0 = hg << 1;                 // 2 output h-rows
  const int tid = threadIdx.x;
  const int lane = tid & 63;
  const int wid = tid >> 6;               // N-split: wave owns co [wid*32, wid*32+32)
  const int l15 = lane & 15, l4 = lane >> 4;

  f32x4 acc[4][2];
  #pragma unroll
  for (int mt = 0; mt < 4; ++mt)
    #pragma unroll
    for (int nt = 0; nt < 2; ++nt)
      #pragma unroll
      for (int r = 0; r < 4; ++r) acc[mt][nt][r] = 0.f;

  int mw[4], mhh[4];
  #pragma unroll
  for (int mt = 0; mt < 4; ++mt) {
    int m = mt * 16 + l15;                // tokens 0..63
    mhh[mt] = m >> 5;
    mw[mt] = m & 31;
  }
  const size_t tokbase = ((size_t)b << 15) + ((size_t)d << 10) + ((size_t)h0 << 5);

  auto stage = [&](int dz) {
    const int zr = (d + dz + 31) & 31;
    #pragma unroll
    for (int p = 0; p < 8; ++p) {
      const int g = p * 256 + tid;        // 2048 chunks of 16B
      const int tok = g >> 4, gi = g & 15;
      const int r = tok >> 5, w = tok & 31;
      const int yr = (h0 + r + 31) & 31;
      const size_t srcbyte = ((((size_t)b << 15) + ((size_t)zr << 10) + ((size_t)yr << 5) + w) << 8)
                             + (size_t)((gi ^ (w & 7)) << 4);
      gload_lds16((const char*)inT + srcbyte, (char*)Als + (size_t)g * 16);
    }
  };

  auto compute = [&](int dz) {
    #pragma unroll
    for (int dy = 0; dy < 3; ++dy) {
      const int tap = dz * 3 + dy;
      #pragma unroll
      for (int dx = 0; dx < 3; ++dx) {
        int abase[4], asw[4];
        #pragma unroll
        for (int mt = 0; mt < 4; ++mt) {
          const int wsft = (mw[mt] + dx + 31) & 31;
          const int stok = (mhh[mt] + dy) * 32 + wsft;
          abase[mt] = stok * 256;
          asw[mt] = (wsft & 7) << 4;
        }
        #pragma unroll
        for (int ks = 0; ks < 4; ++ks) {
          const int k2 = (ks * 32 + l4 * 8) * 2;
          const int bbase = (((tap * 3 + dx) * 4 + ks) * 4 + l4) * 1024;
          short8 afr[4], bfr[2];
          #pragma unroll
          for (int nt = 0; nt < 2; ++nt) {
            const int co = wid * 32 + nt * 16 + l15;
            bfr[nt] = *(const short8*)(Bp + bbase + co * 8);
          }
          #pragma unroll
          for (int mt = 0; mt < 4; ++mt)
            afr[mt] = *(const short8*)((const char*)Als + abase[mt] + (k2 ^ asw[mt]));
          __builtin_amdgcn_s_setprio(1);
          #pragma unroll
          for (int mt = 0; mt < 4; ++mt)
            #pragma unroll
            for (int nt = 0; nt < 2; ++nt)
              acc[mt][nt] = __builtin_amdgcn_mfma_f32_16x16x32_bf16(afr[mt], bfr[nt],
                                                                    acc[mt][nt], 0, 0, 0);
          __builtin_amdgcn_s_setprio(0);
        }
      }
    }
  };

  for (int dz = 0; dz < 3; ++dz) {
    stage(dz);
    __syncthreads();
    compute(dz);
    if (dz < 2) __syncthreads();
  }

  #pragma unroll
  for (int nt = 0; nt < 2; ++nt) {
    const int co = wid * 32 + nt * 16 + l15;
    const float bias = b1[co];
    float s = 0.f, q = 0.f;
    #pragma unroll
    for (int mt = 0; mt < 4; ++mt) {
      #pragma unroll
      for (int r = 0; r < 4; ++r) {
        const int m = mt * 16 + l4 * 4 + r;
        const float v = acc[mt][nt][r] + bias;
        out[(tokbase + m) * 128 + co] = f2bf(v);
        s += v; q += v * v;
      }
    }
    s += __shfl_xor(s, 16); s += __shfl_xor(s, 32);
    q += __shfl_xor(q, 16); q += __shfl_xor(q, 32);
    if (l4 == 0) { sumb[co] = s; sqb[co] = q; }
  }
  __syncthreads();
  if (tid < 128) {
    ps[blk * 128 + tid] = sumb[tid];
    pss[blk * 128 + tid] = sqb[tid];
  }
}

// ---------------------------------------------------------------------------
// K2: stats finalize, parallel
// ---------------------------------------------------------------------------
__global__ __launch_bounds__(64) void stats_final_kernel(
    const float* __restrict__ ps, const float* __restrict__ pss,
    float* __restrict__ mu, float* __restrict__ rs, int nb) {
  const int pair = blockIdx.x;  // b*128 + c
  const int b = pair >> 7, c = pair & 127;
  const int lane = threadIdx.x;
  float s = 0.f, ss = 0.f;
  for (int j = lane; j < nb; j += 64) {
    const int idx = ((b * nb + j) << 7) + c;
    s += ps[idx];
    ss += pss[idx];
  }
  #pragma unroll
  for (int o = 32; o > 0; o >>= 1) {
    s += __shfl_xor(s, o);
    ss += __shfl_xor(ss, o);
  }
  if (lane == 0) {
    float m = s * (1.0f / 32768.0f);
    float v = ss * (1.0f / 32768.0f) - m * m;
    mu[pair] = m;
    rs[pair] = rsqrtf(v + 1e-5f);
  }
}

// ---------------------------------------------------------------------------
// K3: 1x1 GEMM via bf16 MFMA, register-only (r7 proven).
// POST 3 now stores token-major interleaved qkv: [t][h*48 + sec*16 + ch]
// ---------------------------------------------------------------------------
template <int PRE, int AB16, int POST, int STATS>
__global__ __launch_bounds__(256) void gemm_mfma_kernel(
    const void* __restrict__ Avoid, const unsigned short* __restrict__ Wp,
    const float* __restrict__ bias, void* __restrict__ Yvoid, int O,
    const float* __restrict__ mu, const float* __restrict__ rs,
    const unsigned short* __restrict__ xtb, float* __restrict__ ps,
    float* __restrict__ pss) {
  __shared__ float sumb[128][2];
  __shared__ float sqb[128][2];
  const int tid = threadIdx.x;
  const int lane = tid & 63, wid = tid >> 6;
  const int wm = wid >> 1, wn = wid & 1;
  const int l15 = lane & 15, l4 = lane >> 4;
  const int og = blockIdx.x * 128;
  const int t0 = blockIdx.y * 128;
  const int bidx = t0 >> 15;
  const float* Af = (const float*)Avoid;
  const unsigned short* Ab = (const unsigned short*)Avoid;
  float* Yf = (float*)Yvoid;
  unsigned short* Yb = (unsigned short*)Yvoid;

  f32x4 acc[4][4];
  #pragma unroll
  for (int mt = 0; mt < 4; ++mt)
    #pragma unroll
    for (int nt = 0; nt < 4; ++nt)
      #pragma unroll
      for (int r = 0; r < 4; ++r) acc[mt][nt][r] = 0.f;

  #pragma unroll
  for (int ks = 0; ks < 4; ++ks) {
    const int kb = ks * 32 + l4 * 8;
    short8 a[4], bfr[4];
    float4 m0, m1, r0, r1;
    if constexpr (PRE == 1) {
      m0 = *(const float4*)(mu + bidx * 128 + kb);
      m1 = *(const float4*)(mu + bidx * 128 + kb + 4);
      r0 = *(const float4*)(rs + bidx * 128 + kb);
      r1 = *(const float4*)(rs + bidx * 128 + kb + 4);
    }
    #pragma unroll
    for (int mt = 0; mt < 4; ++mt) {
      const int tok = t0 + wm * 64 + mt * 16 + l15;
      float v[16];
      bool have = false;
      if constexpr (AB16 == 1) {
        if constexpr (PRE == 1) {
          bf16x16_load(Ab + (size_t)tok * 128 + kb, v);
          have = true;
        } else {
          a[mt] = *(const short8*)(Ab + (size_t)tok * 128 + kb);
        }
      } else {
        const float* ap = Af + (size_t)tok * 128 + kb;
        float4 v0 = *(const float4*)ap;
        float4 v1 = *(const float4*)(ap + 4);
        v[0] = v0.x; v[1] = v0.y; v[2] = v0.z; v[3] = v0.w;
        v[4] = v1.x; v[5] = v1.y; v[6] = v1.z; v[7] = v1.w;
        have = true;
      }
      if (have) {
        if constexpr (PRE == 1) {
          const float mm[8] = {m0.x, m0.y, m0.z, m0.w, m1.x, m1.y, m1.z, m1.w};
          const float rr[8] = {r0.x, r0.y, r0.z, r0.w, r1.x, r1.y, r1.z, r1.w};
          #pragma unroll
          for (int j = 0; j < 8; ++j) v[j] = gelu_f((v[j] - mm[j]) * rr[j]);
        }
        short8 t;
        #pragma unroll
        for (int j = 0; j < 8; ++j) t[j] = (short)f2bf(v[j]);
        a[mt] = t;
      }
    }
    #pragma unroll
    for (int nt = 0; nt < 4; ++nt) {
      const int o = og + wn * 64 + nt * 16 + l15;
      bfr[nt] = *(const short8*)(Wp + (size_t)o * 128 + kb);
    }
    #pragma unroll
    for (int mt = 0; mt < 4; ++mt)
      #pragma unroll
      for (int nt = 0; nt < 4; ++nt)
        acc[mt][nt] = __builtin_amdgcn_mfma_f32_16x16x32_bf16(a[mt], bfr[nt], acc[mt][nt], 0, 0, 0);
  }

  #pragma unroll
  for (int nt = 0; nt < 4; ++nt) {
    const int o = og + wn * 64 + nt * 16 + l15;
    const float bb = bias[o];
    float s = 0.f, q = 0.f;
    #pragma unroll
    for (int mt = 0; mt < 4; ++mt) {
      #pragma unroll
      for (int r = 0; r < 4; ++r) {
        const int t = t0 + wm * 64 + mt * 16 + l4 * 4 + r;
        const float v = acc[mt][nt][r] + bb;
        if constexpr (POST == 0) {
          Yf[(size_t)t * O + o] = v;
        } else if constexpr (POST == 1) {
          Yb[(size_t)t * 128 + o] = f2bf(sigmoid_f(v) * bf2f(xtb[(size_t)t * 128 + o]));
        } else if constexpr (POST == 2) {
          Yb[(size_t)t * O + o] = f2bf(v);
        } else {
          // token-major interleaved qkv: [t][h*48 + sec*16 + ch]
          const int sec = o >> 7, hsub = (o & 127) >> 4, ch = o & 15;
          Yb[(size_t)t * 384 + hsub * 48 + sec * 16 + ch] = f2bf(v);
        }
        if constexpr (STATS) { s += v; q += v * v; }
      }
    }
    if constexpr (STATS) {
      s += __shfl_xor(s, 16); s += __shfl_xor(s, 32);
      q += __shfl_xor(q, 16); q += __shfl_xor(q, 32);
      if (l4 == 0) { sumb[o - og][wm] = s; sqb[o - og][wm] = q; }
    }
  }
  if constexpr (STATS) {
    __syncthreads();
    if (tid < 128) {
      ps[blockIdx.y * 128 + tid] = sumb[tid][0] + sumb[tid][1];
      pss[blockIdx.y * 128 + tid] = sqb[tid][0] + sqb[tid][1];
    }
  }
}

// ---------------------------------------------------------------------------
// K6: final projection over A0+A1+A2 (bf16), swapped orientation -> NCDHW
// ---------------------------------------------------------------------------
__global__ __launch_bounds__(256) void proj_mfma_kernel(
    const unsigned short* __restrict__ A0b, const unsigned short* __restrict__ A1b,
    const unsigned short* __restrict__ A2b, const unsigned short* __restrict__ Wp,
    const float* __restrict__ bias, float* __restrict__ out) {
  const int tid = threadIdx.x;
  const int lane = tid & 63, wid = tid >> 6;
  const int wm = wid >> 1, wn = wid & 1;
  const int l15 = lane & 15, l4 = lane >> 4;
  const int t0 = blockIdx.x * 128;

  f32x4 acc[4][4];
  #pragma unroll
  for (int mt = 0; mt < 4; ++mt)
    #pragma unroll
    for (int nt = 0; nt < 4; ++nt)
      #pragma unroll
      for (int r = 0; r < 4; ++r) acc[mt][nt][r] = 0.f;

  #pragma unroll
  for (int ks = 0; ks < 4; ++ks) {
    const int kb = ks * 32 + l4 * 8;
    short8 a[4], bfr[4];
    #pragma unroll
    for (int mt = 0; mt < 4; ++mt) {
      const int o = wm * 64 + mt * 16 + l15;
      a[mt] = *(const short8*)(Wp + (size_t)o * 128 + kb);
    }
    #pragma unroll
    for (int nt = 0; nt < 4; ++nt) {
      const int tok = t0 + wn * 64 + nt * 16 + l15;
      const size_t off = (size_t)tok * 128 + kb;
      short8 s0 = *(const short8*)(A0b + off);
      short8 s1 = *(const short8*)(A1b + off);
      short8 s2 = *(const short8*)(A2b + off);
      short8 r;
      #pragma unroll
      for (int i = 0; i < 8; ++i) {
        float f = bf2f((unsigned short)s0[i]) + bf2f((unsigned short)s1[i]) +
                  bf2f((unsigned short)s2[i]);
        r[i] = (short)f2bf(f);
      }
      bfr[nt] = r;
    }
    #pragma unroll
    for (int mt = 0; mt < 4; ++mt)
      #pragma unroll
      for (int nt = 0; nt < 4; ++nt)
        acc[mt][nt] = __builtin_amdgcn_mfma_f32_16x16x32_bf16(a[mt], bfr[nt], acc[mt][nt], 0, 0, 0);
  }

  #pragma unroll
  for (int nt = 0; nt < 4; ++nt) {
    const int tok = t0 + wn * 64 + nt * 16 + l15;
    const int dhw = tok & 32767, bB = tok >> 15;
    #pragma unroll
    for (int mt = 0; mt < 4; ++mt) {
      #pragma unroll
      for (int r = 0; r < 4; ++r) {
        const int o = wm * 64 + mt * 16 + l4 * 4 + r;
        out[((size_t)(bB * 128 + o) << 15) + dhw] = acc[mt][nt][r] + bias[o];
      }
    }
  }
}

// ---------------------------------------------------------------------------
// K7: axial attention via MFMA, v3. One 512-thread block per (seq, axial):
// stage 32 token-rows of interleaved qkv (768B each, coalesced) into LDS,
// then 8 waves each run one head's pipeline (r8-proven math).
// ---------------------------------------------------------------------------
__global__ __launch_bounds__(512) void attn_mfma_kernel(
    const unsigned short* __restrict__ qkvt, const float* __restrict__ Rbuf,
    const float* __restrict__ pbw, unsigned short* __restrict__ a0,
    unsigned short* __restrict__ a1, unsigned short* __restrict__ a2) {
  __shared__ unsigned short rows[32 * 392];  // pitch 392 ush = 784B (16B aligned)
  __shared__ unsigned short Vt[8][16 * 40];  // per-head [d][tok]
  __shared__ float Ot[8][32 * 20];           // per-head [tok][d]
  const int axial = blockIdx.y;
  const int seq = blockIdx.x;
  unsigned short* dstbuf = (axial == 0) ? a0 : ((axial == 1) ? a1 : a2);
  const int tid = threadIdx.x;
  const int lane = tid & 63, head = tid >> 6;
  const int tok = lane & 31, hi = lane >> 5;
  const int b = seq >> 10, rem = seq & 1023;
  const int u = rem >> 5, v = rem & 31;
  int base, stride, comp;
  if (axial == 0)      { base = (b << 15) + (u << 5) + v;         stride = 1024; comp = 2; }
  else if (axial == 1) { base = (b << 15) + (u << 10) + v;        stride = 32;   comp = 1; }
  else                 { base = (b << 15) + (u << 10) + (v << 5); stride = 1;    comp = 0; }

  // stage: 32 rows x 384 ush (768B contiguous each), 1536 chunks of 16B
  #pragma unroll
  for (int p = 0; p < 3; ++p) {
    const int c = p * 512 + tid;
    const int r = c / 48, cw = c - r * 48;
    const size_t src = ((size_t)base + (size_t)r * stride) * 384 + (size_t)cw * 8;
    *(uint4*)((char*)rows + r * 784 + cw * 16) = *(const uint4*)(qkvt + src);
  }
  __syncthreads();

  const float* Rp = Rbuf + (axial * 8 + head) * 18;
  const float rq00 = fabsf(Rp[0]);
  const unsigned short* myrow = rows + tok * 392 + head * 48;
  short8 aq = *(const short8*)(myrow + hi * 8);
  short8 ak = *(const short8*)(myrow + 16 + hi * 8);
  short8 av = *(const short8*)(myrow + 32 + hi * 8);
  if (hi) {  // ch15 carries the R00^2 correction
    aq[7] = (short)f2bf(bf2f((unsigned short)aq[7]) * rq00);
    ak[7] = (short)f2bf(bf2f((unsigned short)ak[7]) * rq00);
  }
  // stage V^T per head (wave-private; no barrier needed)
  #pragma unroll
  for (int e = 0; e < 8; ++e) Vt[head][(hi * 8 + e) * 40 + tok] = (unsigned short)av[e];

  f32x16 sacc;
  #pragma unroll
  for (int r = 0; r < 16; ++r) sacc[r] = 0.f;
  sacc = __builtin_amdgcn_mfma_f32_32x32x16_bf16(ak, aq, sacc, 0, 0, 0);
  const float wb = pbw[comp];
  float p[16];
  float mmax = -1e30f;
  #pragma unroll
  for (int r = 0; r < 16; ++r) {
    const int kk = (r & 3) + 4 * hi + 8 * (r >> 2);
    const float lin = -1.0f + (2.0f / 31.0f) * (float)kk;
    p[r] = sacc[r] * 0.25f - lin * wb;
    mmax = fmaxf(mmax, p[r]);
  }
  mmax = fmaxf(mmax, __shfl_xor(mmax, 32));
  float sum = 0.f;
  #pragma unroll
  for (int r = 0; r < 16; ++r) { p[r] = expf(p[r] - mmax); sum += p[r]; }
  sum += __shfl_xor(sum, 32);
  const float inv = 1.0f / sum;
  #pragma unroll
  for (int r = 0; r < 16; ++r) p[r] *= inv;
  unsigned pk[8], sw[8];
  #pragma unroll
  for (int j = 0; j < 8; ++j) {
    unsigned r_;
    asm("v_cvt_pk_bf16_f32 %0, %1, %2" : "=v"(r_) : "v"(p[2 * j]), "v"(p[2 * j + 1]));
    pk[j] = r_;
  }
  #pragma unroll
  for (int j = 0; j < 8; ++j) sw[j] = (unsigned)__shfl_xor((int)pk[j], 32);
  uint4 Fu, Gu;
  Fu.x = hi ? sw[2] : pk[0];
  Fu.y = hi ? sw[3] : pk[1];
  Fu.z = hi ? pk[2] : sw[0];
  Fu.w = hi ? pk[3] : sw[1];
  Gu.x = hi ? sw[6] : pk[4];
  Gu.y = hi ? sw[7] : pk[5];
  Gu.z = hi ? pk[6] : sw[4];
  Gu.w = hi ? pk[7] : sw[5];
  short8 Pf = *(short8*)&Fu;
  short8 Pg = *(short8*)&Gu;
  const unsigned short* vrow = Vt[head] + (tok & 15) * 40;
  short8 Bv0 = *(const short8*)(vrow + hi * 8);
  short8 Bv1 = *(const short8*)(vrow + 16 + hi * 8);
  f32x16 oacc;
  #pragma unroll
  for (int r = 0; r < 16; ++r) oacc[r] = 0.f;
  oacc = __builtin_amdgcn_mfma_f32_32x32x16_bf16(Pf, Bv0, oacc, 0, 0, 0);
  oacc = __builtin_amdgcn_mfma_f32_32x32x16_bf16(Pg, Bv1, oacc, 0, 0, 0);
  if (tok < 16) {
    #pragma unroll
    for (int r = 0; r < 16; ++r) {
      const int q = (r & 3) + 4 * hi + 8 * (r >> 2);
      Ot[head][q * 20 + tok] = oacc[r];
    }
  }
  // Ot is wave-private: same-wave LDS ordering suffices (no barrier)
  if (lane < 32) {
    float o16[16], y16[16], Rv[9];
    #pragma unroll
    for (int j = 0; j < 16; ++j) o16[j] = Ot[head][lane * 20 + j];
    #pragma unroll
    for (int i = 0; i < 9; ++i) Rv[i] = Rp[9 + i];
    rot16(Rv, o16, y16);
    unsigned outw[8];
    #pragma unroll
    for (int j = 0; j < 8; ++j)
      outw[j] = ((unsigned)f2bf(y16[2 * j + 1]) << 16) | (unsigned)f2bf(y16[2 * j]);
    const size_t t2 = (size_t)base + (size_t)lane * stride;
    unsigned short* dst = dstbuf + t2 * 128 + head * 16;
    uint4 o0 = {outw[0], outw[1], outw[2], outw[3]};
    uint4 o1 = {outw[4], outw[5], outw[6], outw[7]};
    *(uint4*)dst = o0;
    *(uint4*)(dst + 8) = o1;
  }
}

// ---------------------------------------------------------------------------
extern "C" void kernel_launch(void* const* d_in, const int* in_sizes, int n_in,
                              void* d_out, int out_size, void* d_ws, size_t ws_size,
                              hipStream_t stream) {
  const float* x       = (const float*)d_in[0];
  const float* pos_emb = (const float*)d_in[1];
  const float* qkv_w   = (const float*)d_in[2];
  const float* qkv_b   = (const float*)d_in[3];
  const float* lp_w1   = (const float*)d_in[4];
  const float* lp_b1   = (const float*)d_in[5];
  const float* lp_w2   = (const float*)d_in[6];
  const float* lp_b2   = (const float*)d_in[7];
  const float* mod_w1  = (const float*)d_in[8];
  const float* mod_b1  = (const float*)d_in[9];
  const float* mod_w2  = (const float*)d_in[10];
  const float* mod_b2  = (const float*)d_in[11];
  // d_in[12] pa_w, d_in[13] pa_b: cancel in softmax (constant along key axis)
  const float* proj_w  = (const float*)d_in[14];
  const float* proj_b  = (const float*)d_in[15];
  const float* pbw     = (const float*)d_in[16];
  // d_in[17] pos_bias_b: cancels in softmax
  const float* Ad      = (const float*)d_in[18];
  const float* Ah      = (const float*)d_in[19];
  const float* Aw      = (const float*)d_in[20];
  const float* Rd      = (const float*)d_in[21];
  const float* Rh      = (const float*)d_in[22];
  const float* Rw      = (const float*)d_in[23];
  // d_in[24..26] t_d/t_h/t_w: cancel in rel (pairwise difference)

  float* ws = (float*)d_ws;
  unsigned short* lfb    = (unsigned short*)(ws + WS_R0);   // lf bf16
  unsigned short* A0b    = (unsigned short*)(ws + WS_A0);
  unsigned short* A1b    = (unsigned short*)(ws + WS_A1);
  unsigned short* A2b    = (unsigned short*)(ws + WS_A2);
  unsigned short* mpreb  = (unsigned short*)(ws + WS_MPREB);
  unsigned short* xtokb  = (unsigned short*)(ws + WS_XTOKB);
  unsigned short* inT    = (unsigned short*)(ws + WS_INT);
  unsigned short* qkvt   = (unsigned short*)(ws + WS_QKVH);
  unsigned short* convP  = (unsigned short*)(ws + WS_CONVP);
  unsigned short* qkvP   = (unsigned short*)(ws + WS_QKVP);
  unsigned short* WcP    = (unsigned short*)(ws + WS_WCP);
  unsigned short* modw2P = (unsigned short*)(ws + WS_MODW2P);
  unsigned short* projP  = (unsigned short*)(ws + WS_PROJP);
  float* bc     = ws + WS_BC;
  float* Rbuf   = ws + WS_RBUF;
  float* ps     = ws + WS_PS;
  float* pss    = ws + WS_PSS;
  float* mu1    = ws + WS_MU1;
  float* rs1    = ws + WS_RS1;
  float* mu2    = ws + WS_MU2;
  float* rs2    = ws + WS_RS2;
  unsigned short* xmodb = inT;  // x_mod bf16 reuses INT region (inT dead after conv)

  prep_w_kernel<<<256, 256, 0, stream>>>(lp_w1, qkv_w, mod_w1, lp_w2, lp_b2, mod_b1,
                                         mod_w2, proj_w, Ad, Ah, Aw, Rd, Rh, Rw,
                                         convP, qkvP, WcP, modw2P, projP, bc, Rbuf);
  transpose_kernel<<<2048, 256, 0, stream>>>(x, pos_emb, xtokb, inT);
  // lf (bf16) = circular conv3x3x3(pos_emb), fused fp32 stats partials
  conv_mfma_kernel<<<1024, 256, 0, stream>>>(inT, convP, lp_b1, lfb, ps, pss);
  stats_final_kernel<<<256, 64, 0, stream>>>(ps, pss, mu1, rs1, 512);
  // m_pre (bf16) = gelu(inorm(lf)) @ Wc^T + bc, fused stats partials
  gemm_mfma_kernel<1, 1, 2, 1><<<dim3(1, 512), 256, 0, stream>>>(
      lfb, WcP, bc, mpreb, 128, mu1, rs1, nullptr, ps, pss);
  stats_final_kernel<<<256, 64, 0, stream>>>(ps, pss, mu2, rs2, 256);
  // x_mod (bf16) = x * sigmoid(gelu(inorm(m_pre)) @ mod_w2^T + mod_b2)
  gemm_mfma_kernel<1, 1, 1, 0><<<dim3(1, 512), 256, 0, stream>>>(
      mpreb, modw2P, mod_b2, xmodb, 128, mu2, rs2, xtokb, nullptr, nullptr);
  // qkv (bf16, token-major interleaved) = x_mod @ qkv_w^T + qkv_b
  gemm_mfma_kernel<0, 1, 3, 0><<<dim3(3, 512), 256, 0, stream>>>(
      xmodb, qkvP, qkv_b, qkvt, 384, nullptr, nullptr, nullptr, nullptr, nullptr);
  // attention: one 512-thread block per (seq, axial), 8 heads in-block
  attn_mfma_kernel<<<dim3(2048, 3), 512, 0, stream>>>(qkvt, Rbuf, pbw, A0b, A1b, A2b);
  proj_mfma_kernel<<<512, 256, 0, stream>>>(A0b, A1b, A2b, projP, proj_b, (float*)d_out);
}

// Round 13
// 250.962 us; speedup vs baseline: 1.2224x; 1.0924x over previous
//
#include <hip/hip_runtime.h>
#include <cstdint>
#include <cstddef>

// ---------------------------------------------------------------------------
// Problem constants: B=2, C=128, D=H=W=32, nh=8, hd=16, L=32
// Tokens: t = b*32768 + d*1024 + h*32 + w   (65536 tokens, 128 channels)
// ---------------------------------------------------------------------------

#define NTOK 65536
#define SPAT 32768

// ws offsets (floats). Same proven map as r7-r12 (136.4 MB).
#define WS_R0     0ull          // region: lf bf16 (8388608 ush) -> A0/A1
#define WS_A0     0ull          // 4194304 (8388608 ush)
#define WS_A1     4194304ull    // 4194304
#define WS_MPREB  8388608ull    // 4194304 (8388608 ush)
#define WS_A2     8388608ull    // 4194304 (overlays dead MPREB)
#define WS_XTOKB  12582912ull   // 4194304 (8388608 ush)
#define WS_INT    16777216ull   // 4194304 (8388608 ush): pos_emb bf16
#define WS_QKVH   20971520ull   // 12582912 (25165824 ush) [t][h*48+sec*16+ch]
#define WS_CONVP  33554432ull   // 221184 (442368 ush) [tap][dx][ks][l4][co][8]
#define WS_QKVP   33775616ull   // 24576  (49152 ush)
#define WS_WCP    33800192ull   // 8192
#define WS_MODW2P 33808384ull   // 8192
#define WS_PROJP  33816576ull   // 8192
#define WS_BC     33824768ull   // 128
#define WS_RBUF   33824896ull   // 432
#define WS_PS     33825328ull   // 131072 (1024 blocks x 128)
#define WS_PSS    33956400ull   // 131072
#define WS_MU1    34087472ull   // 256
#define WS_RS1    34087728ull   // 256
#define WS_MU2    34087984ull   // 256
#define WS_RS2    34088240ull   // 256
// total 34088496 floats = 136.4 MB

typedef __attribute__((ext_vector_type(8))) short short8;
typedef __attribute__((ext_vector_type(4))) float f32x4;
typedef __attribute__((ext_vector_type(16))) float f32x16;

__device__ __forceinline__ float gelu_f(float x) {
  return 0.5f * x * (1.0f + erff(x * 0.70710678118654752f));
}
__device__ __forceinline__ float sigmoid_f(float x) {
  return 1.0f / (1.0f + expf(-x));
}
__device__ __forceinline__ unsigned short f2bf(float x) {  // RNE f32->bf16
  unsigned int u = __float_as_uint(x);
  unsigned int r = u + 0x7fffu + ((u >> 16) & 1u);
  return (unsigned short)(r >> 16);
}
__device__ __forceinline__ float bf2f(unsigned short u) {
  return __uint_as_float(((unsigned int)u) << 16);
}
// 16 consecutive bf16 -> 16 fp32
__device__ __forceinline__ void bf16x16_load(const unsigned short* p, float* f) {
  const uint4 a = *(const uint4*)p;
  const uint4 b = *(const uint4*)(p + 8);
  const unsigned int w[8] = {a.x, a.y, a.z, a.w, b.x, b.y, b.z, b.w};
  #pragma unroll
  for (int i = 0; i < 8; ++i) {
    f[2 * i] = __uint_as_float(w[i] << 16);
    f[2 * i + 1] = __uint_as_float(w[i] & 0xffff0000u);
  }
}
// async global->LDS, 16B per lane (dest must be wave-uniform base + lane*16)
__device__ __forceinline__ void gload_lds16(const void* g, void* l) {
  __builtin_amdgcn_global_load_lds(
      (const __attribute__((address_space(1))) unsigned int*)g,
      (__attribute__((address_space(3))) unsigned int*)l, 16, 0, 0);
}
__device__ __forceinline__ float dot3(const float* a, const float* b) {
  return a[0] * b[0] + a[1] * b[1] + a[2] * b[2];
}
__device__ __forceinline__ void cross3(const float* a, const float* b, float* c) {
  c[0] = a[1] * b[2] - a[2] * b[1];
  c[1] = a[2] * b[0] - a[0] * b[2];
  c[2] = a[0] * b[1] - a[1] * b[0];
}

// exact port of _r6_to_matrix for one head (6 floats in, 9 out row-major)
__device__ void r6_to_matrix(const float* r6, float* R) {
  float v1[3] = {r6[0], r6[1], r6[2]};
  float n1 = sqrtf(dot3(v1, v1));
  float inv1 = 1.0f / (n1 + 1e-7f);
  v1[0] *= inv1; v1[1] *= inv1; v1[2] *= inv1;
  float v2[3] = {r6[3], r6[4], r6[5]};
  float d = dot3(v2, v1);
  v2[0] -= d * v1[0]; v2[1] -= d * v1[1]; v2[2] -= d * v1[2];
  float n2 = sqrtf(dot3(v2, v2));
  float inv2 = 1.0f / (n2 + 1e-7f);
  v2[0] *= inv2; v2[1] *= inv2; v2[2] *= inv2;
  float v3[3]; cross3(v1, v2, v3);
  float cx[3]; cross3(v2, v3, cx);
  float det = dot3(v1, cx);
  if (det < 0.0f) { v3[0] = -v3[0]; v3[1] = -v3[1]; v3[2] = -v3[2]; }
  R[0] = v1[0]; R[1] = v1[1]; R[2] = v1[2];
  R[3] = v2[0]; R[4] = v2[1]; R[5] = v2[2];
  R[6] = v3[0]; R[7] = v3[1]; R[8] = v3[2];
}

// exact port of _ensure_matrix for one head (9 in row-major, 9 out)
__device__ void ensure_matrix(const float* Rin, float* Ro) {
  float a[3] = {Rin[0] + 1e-6f, Rin[1] + 1e-6f, Rin[2] + 1e-6f};
  float na = fmaxf(sqrtf(dot3(a, a)), 1e-12f);
  float v1[3] = {a[0] / na, a[1] / na, a[2] / na};
  float b0[3] = {Rin[3], Rin[4], Rin[5]};
  float d = dot3(b0, v1);
  float bb[3] = {b0[0] - d * v1[0] + 1e-6f, b0[1] - d * v1[1] + 1e-6f, b0[2] - d * v1[2] + 1e-6f};
  float nb = fmaxf(sqrtf(dot3(bb, bb)), 1e-12f);
  float v2[3] = {bb[0] / nb, bb[1] / nb, bb[2] / nb};
  float v3[3]; cross3(v1, v2, v3);
  float cx[3]; cross3(v2, v3, cx);
  float det = dot3(v1, cx);
  if (det < 0.0f) { v3[0] = -v3[0]; v3[1] = -v3[1]; v3[2] = -v3[2]; }
  float Rn[9] = {v1[0], v1[1], v1[2], v2[0], v2[1], v2[2], v3[0], v3[1], v3[2]};
  float T1[9], T2[9];
  for (int i = 0; i < 3; ++i)
    for (int j = 0; j < 3; ++j) {
      float s = 0.f;
      for (int k = 0; k < 3; ++k) s += Rn[k * 3 + i] * Rn[k * 3 + j];
      T1[i * 3 + j] = s;
    }
  for (int i = 0; i < 3; ++i)
    for (int j = 0; j < 3; ++j) {
      float s = 0.f;
      for (int k = 0; k < 3; ++k) s += T1[i * 3 + k] * Rn[j * 3 + k];
      T2[i * 3 + j] = s;
    }
  for (int i = 0; i < 9; ++i) Ro[i] = 0.5f * (Rn[i] + T2[i]);
}

// y = R_eff x for hd=16 (5 full 3x3 groups + scalar R00 on ch15)
__device__ __forceinline__ void rot16(const float* R, const float* x, float* y) {
  #pragma unroll
  for (int g = 0; g < 5; ++g) {
    float a = x[3 * g], b = x[3 * g + 1], c = x[3 * g + 2];
    y[3 * g + 0] = R[0] * a + R[1] * b + R[2] * c;
    y[3 * g + 1] = R[3] * a + R[4] * b + R[5] * c;
    y[3 * g + 2] = R[6] * a + R[7] * b + R[8] * c;
  }
  y[15] = R[0] * x[15];
}

// ---------------------------------------------------------------------------
// K0: merged prep (blocks 0..255) + transposes (blocks 256..2303)
// ---------------------------------------------------------------------------
__global__ __launch_bounds__(256) void prep_transpose_kernel(
    const float* __restrict__ lp_w1, const float* __restrict__ qkv_w,
    const float* __restrict__ mod_w1, const float* __restrict__ lp_w2,
    const float* __restrict__ lp_b2, const float* __restrict__ mod_b1,
    const float* __restrict__ mod_w2, const float* __restrict__ proj_w,
    const float* __restrict__ Ad, const float* __restrict__ Ah,
    const float* __restrict__ Aw, const float* __restrict__ Rd,
    const float* __restrict__ Rh, const float* __restrict__ Rw,
    const float* __restrict__ x, const float* __restrict__ pe,
    unsigned short* __restrict__ convP, unsigned short* __restrict__ qkvP,
    unsigned short* __restrict__ WcP, unsigned short* __restrict__ modw2P,
    unsigned short* __restrict__ projP, float* __restrict__ bc,
    float* __restrict__ Rbuf, unsigned short* __restrict__ xtokb,
    unsigned short* __restrict__ inT) {
  __shared__ float lds[32][132];
  if (blockIdx.x < 256) {
    int gid = blockIdx.x * 256 + threadIdx.x;  // 65536 threads
    for (int f = gid; f < 442368; f += 65536) {
      int e = f & 7;
      int co = (f >> 3) & 127;
      int rest = f >> 10;
      int l4 = rest & 3;
      int ks = (rest >> 2) & 3;
      int dxt = rest >> 4;
      int dx = dxt % 3;
      int tap = dxt / 3;
      int dz = tap / 3, dy = tap % 3;
      int ci = ks * 32 + l4 * 8 + e;
      convP[f] = f2bf(lp_w1[(co * 128 + ci) * 27 + dz * 9 + dy * 3 + dx]);
    }
    if (gid < 49152) qkvP[gid] = f2bf(qkv_w[gid]);
    if (gid < 16384) {
      modw2P[gid] = f2bf(mod_w2[gid]);
      projP[gid] = f2bf(proj_w[gid]);
      int o = gid >> 7, i = gid & 127;
      float s = 0.f;
      for (int c = 0; c < 128; ++c) s += mod_w1[o * 128 + c] * lp_w2[c * 128 + i];
      WcP[gid] = f2bf(s);
    }
    if (gid < 128) {
      float s = 0.f;
      for (int c = 0; c < 128; ++c) s += mod_w1[gid * 128 + c] * lp_b2[c];
      bc[gid] = s + mod_b1[gid];
    }
    if (blockIdx.x == 0 && threadIdx.x >= 224 && threadIdx.x < 248) {
      int tid = threadIdx.x - 224;
      int ax = tid >> 3, h = tid & 7;
      const float* A = (ax == 0) ? Ad : ((ax == 1) ? Ah : Aw);
      const float* R = (ax == 0) ? Rd : ((ax == 1) ? Rh : Rw);
      float Rq[9], Rv[9];
      r6_to_matrix(A + h * 6, Rq);
      ensure_matrix(R + h * 9, Rv);
      float* dst = Rbuf + (ax * 8 + h) * 18;
      for (int i = 0; i < 9; ++i) { dst[i] = Rq[i]; dst[9 + i] = Rv[i]; }
    }
    return;
  }
  // transpose path
  int blk = blockIdx.x - 256;  // b*1024 + d*32 + h
  int b = blk >> 10;
  int dh = blk & 1023;
  int tid = threadIdx.x;
  size_t planebase = ((size_t)b << 22) + ((size_t)dh << 5);
  size_t tb = ((size_t)blk) << 5;
  #pragma unroll
  for (int r = 0; r < 16; ++r) {
    int idx = r * 256 + tid;
    int ci = idx >> 5, w = idx & 31;
    lds[w][ci] = x[planebase + ((size_t)ci << 15) + w];
  }
  __syncthreads();
  #pragma unroll
  for (int r = 0; r < 16; ++r) {
    int idx = r * 256 + tid;
    int w = idx >> 7, ci = idx & 127;
    xtokb[(tb + w) * 128 + ci] = f2bf(lds[w][ci]);
  }
  __syncthreads();
  #pragma unroll
  for (int r = 0; r < 16; ++r) {
    int idx = r * 256 + tid;
    int ci = idx >> 5, w = idx & 31;
    lds[w][ci] = pe[planebase + ((size_t)ci << 15) + w];
  }
  __syncthreads();
  #pragma unroll
  for (int r = 0; r < 16; ++r) {
    int idx = r * 256 + tid;
    int w = idx >> 7, ci = idx & 127;
    inT[(tb + w) * 128 + ci] = f2bf(lds[w][ci]);
  }
}

// ---------------------------------------------------------------------------
// K1: 3x3x3 circular conv via bf16 MFMA, v7 (r11/r12 proven) + XCD swizzle.
// ---------------------------------------------------------------------------
__global__ __launch_bounds__(256, 4) void conv_mfma_kernel(
    const unsigned short* __restrict__ inT, const unsigned short* __restrict__ Bp,
    const float* __restrict__ b1, unsigned short* __restrict__ out,
    float* __restrict__ ps, float* __restrict__ pss) {
  __shared__ unsigned short Als[16384];  // 32KB: 4 rows x 32 w x 128 ci, swizzled
  __shared__ float sumb[128];
  __shared__ float sqb[128];
  // XCD-chunked bijective swizzle (1024 % 8 == 0): each XCD gets 128
  // consecutive logical blocks = 8 adjacent d-planes -> halo L2 reuse.
  const int orig = blockIdx.x;
  const int blk = ((orig & 7) << 7) + (orig >> 3);
  const int b = blk >> 9, d = (blk >> 4) & 31, hg = blk & 15;
  const int h0 = hg << 1;                 // 2 output h-rows
  const int tid = threadIdx.x;
  const int lane = tid & 63;
  const int wid = tid >> 6;               // N-split: wave owns co [wid*32, wid*32+32)
  const int l15 = lane & 15, l4 = lane >> 4;

  f32x4 acc[4][2];
  #pragma unroll
  for (int mt = 0; mt < 4; ++mt)
    #pragma unroll
    for (int nt = 0; nt < 2; ++nt)
      #pragma unroll
      for (int r = 0; r < 4; ++r) acc[mt][nt][r] = 0.f;

  int mw[4], mhh[4];
  #pragma unroll
  for (int mt = 0; mt < 4; ++mt) {
    int m = mt * 16 + l15;                // tokens 0..63
    mhh[mt] = m >> 5;
    mw[mt] = m & 31;
  }
  const size_t tokbase = ((size_t)b << 15) + ((size_t)d << 10) + ((size_t)h0 << 5);

  auto stage = [&](int dz) {
    const int zr = (d + dz + 31) & 31;
    #pragma unroll
    for (int p = 0; p < 8; ++p) {
      const int g = p * 256 + tid;        // 2048 chunks of 16B
      const int tok = g >> 4, gi = g & 15;
      const int r = tok >> 5, w = tok & 31;
      const int yr = (h0 + r + 31) & 31;
      const size_t srcbyte = ((((size_t)b << 15) + ((size_t)zr << 10) + ((size_t)yr << 5) + w) << 8)
                             + (size_t)((gi ^ (w & 7)) << 4);
      gload_lds16((const char*)inT + srcbyte, (char*)Als + (size_t)g * 16);
    }
  };

  auto compute = [&](int dz) {
    #pragma unroll
    for (int dy = 0; dy < 3; ++dy) {
      const int tap = dz * 3 + dy;
      #pragma unroll
      for (int dx = 0; dx < 3; ++dx) {
        int abase[4], asw[4];
        #pragma unroll
        for (int mt = 0; mt < 4; ++mt) {
          const int wsft = (mw[mt] + dx + 31) & 31;
          const int stok = (mhh[mt] + dy) * 32 + wsft;
          abase[mt] = stok * 256;
          asw[mt] = (wsft & 7) << 4;
        }
        #pragma unroll
        for (int ks = 0; ks < 4; ++ks) {
          const int k2 = (ks * 32 + l4 * 8) * 2;
          const int bbase = (((tap * 3 + dx) * 4 + ks) * 4 + l4) * 1024;
          short8 afr[4], bfr[2];
          #pragma unroll
          for (int nt = 0; nt < 2; ++nt) {
            const int co = wid * 32 + nt * 16 + l15;
            bfr[nt] = *(const short8*)(Bp + bbase + co * 8);
          }
          #pragma unroll
          for (int mt = 0; mt < 4; ++mt)
            afr[mt] = *(const short8*)((const char*)Als + abase[mt] + (k2 ^ asw[mt]));
          __builtin_amdgcn_s_setprio(1);
          #pragma unroll
          for (int mt = 0; mt < 4; ++mt)
            #pragma unroll
            for (int nt = 0; nt < 2; ++nt)
              acc[mt][nt] = __builtin_amdgcn_mfma_f32_16x16x32_bf16(afr[mt], bfr[nt],
                                                                    acc[mt][nt], 0, 0, 0);
          __builtin_amdgcn_s_setprio(0);
        }
      }
    }
  };

  for (int dz = 0; dz < 3; ++dz) {
    stage(dz);
    __syncthreads();
    compute(dz);
    if (dz < 2) __syncthreads();
  }

  #pragma unroll
  for (int nt = 0; nt < 2; ++nt) {
    const int co = wid * 32 + nt * 16 + l15;
    const float bias = b1[co];
    float s = 0.f, q = 0.f;
    #pragma unroll
    for (int mt = 0; mt < 4; ++mt) {
      #pragma unroll
      for (int r = 0; r < 4; ++r) {
        const int m = mt * 16 + l4 * 4 + r;
        const float v = acc[mt][nt][r] + bias;
        out[(tokbase + m) * 128 + co] = f2bf(v);
        s += v; q += v * v;
      }
    }
    s += __shfl_xor(s, 16); s += __shfl_xor(s, 32);
    q += __shfl_xor(q, 16); q += __shfl_xor(q, 32);
    if (l4 == 0) { sumb[co] = s; sqb[co] = q; }
  }
  __syncthreads();
  if (tid < 128) {
    ps[blk * 128 + tid] = sumb[tid];
    pss[blk * 128 + tid] = sqb[tid];
  }
}

// ---------------------------------------------------------------------------
// K2: stats finalize, parallel
// ---------------------------------------------------------------------------
__global__ __launch_bounds__(64) void stats_final_kernel(
    const float* __restrict__ ps, const float* __restrict__ pss,
    float* __restrict__ mu, float* __restrict__ rs, int nb) {
  const int pair = blockIdx.x;  // b*128 + c
  const int b = pair >> 7, c = pair & 127;
  const int lane = threadIdx.x;
  float s = 0.f, ss = 0.f;
  for (int j = lane; j < nb; j += 64) {
    const int idx = ((b * nb + j) << 7) + c;
    s += ps[idx];
    ss += pss[idx];
  }
  #pragma unroll
  for (int o = 32; o > 0; o >>= 1) {
    s += __shfl_xor(s, o);
    ss += __shfl_xor(ss, o);
  }
  if (lane == 0) {
    float m = s * (1.0f / 32768.0f);
    float v = ss * (1.0f / 32768.0f) - m * m;
    mu[pair] = m;
    rs[pair] = rsqrtf(v + 1e-5f);
  }
}

// ---------------------------------------------------------------------------
// K3: 1x1 GEMM via bf16 MFMA, register-only (r7 proven). Used for Wc only.
// PRE: 0 none | 1 gelu(inorm)   AB16: A dtype   POST: 2 bf16 [t][O]
// ---------------------------------------------------------------------------
template <int PRE, int AB16, int POST, int STATS>
__global__ __launch_bounds__(256) void gemm_mfma_kernel(
    const void* __restrict__ Avoid, const unsigned short* __restrict__ Wp,
    const float* __restrict__ bias, void* __restrict__ Yvoid, int O,
    const float* __restrict__ mu, const float* __restrict__ rs,
    const unsigned short* __restrict__ xtb, float* __restrict__ ps,
    float* __restrict__ pss) {
  __shared__ float sumb[128][2];
  __shared__ float sqb[128][2];
  const int tid = threadIdx.x;
  const int lane = tid & 63, wid = tid >> 6;
  const int wm = wid >> 1, wn = wid & 1;
  const int l15 = lane & 15, l4 = lane >> 4;
  const int og = blockIdx.x * 128;
  const int t0 = blockIdx.y * 128;
  const int bidx = t0 >> 15;
  const float* Af = (const float*)Avoid;
  const unsigned short* Ab = (const unsigned short*)Avoid;
  float* Yf = (float*)Yvoid;
  unsigned short* Yb = (unsigned short*)Yvoid;

  f32x4 acc[4][4];
  #pragma unroll
  for (int mt = 0; mt < 4; ++mt)
    #pragma unroll
    for (int nt = 0; nt < 4; ++nt)
      #pragma unroll
      for (int r = 0; r < 4; ++r) acc[mt][nt][r] = 0.f;

  #pragma unroll
  for (int ks = 0; ks < 4; ++ks) {
    const int kb = ks * 32 + l4 * 8;
    short8 a[4], bfr[4];
    float4 m0, m1, r0, r1;
    if constexpr (PRE == 1) {
      m0 = *(const float4*)(mu + bidx * 128 + kb);
      m1 = *(const float4*)(mu + bidx * 128 + kb + 4);
      r0 = *(const float4*)(rs + bidx * 128 + kb);
      r1 = *(const float4*)(rs + bidx * 128 + kb + 4);
    }
    #pragma unroll
    for (int mt = 0; mt < 4; ++mt) {
      const int tok = t0 + wm * 64 + mt * 16 + l15;
      float v[16];
      bool have = false;
      if constexpr (AB16 == 1) {
        if constexpr (PRE == 1) {
          bf16x16_load(Ab + (size_t)tok * 128 + kb, v);
          have = true;
        } else {
          a[mt] = *(const short8*)(Ab + (size_t)tok * 128 + kb);
        }
      } else {
        const float* ap = Af + (size_t)tok * 128 + kb;
        float4 v0 = *(const float4*)ap;
        float4 v1 = *(const float4*)(ap + 4);
        v[0] = v0.x; v[1] = v0.y; v[2] = v0.z; v[3] = v0.w;
        v[4] = v1.x; v[5] = v1.y; v[6] = v1.z; v[7] = v1.w;
        have = true;
      }
      if (have) {
        if constexpr (PRE == 1) {
          const float mm[8] = {m0.x, m0.y, m0.z, m0.w, m1.x, m1.y, m1.z, m1.w};
          const float rr[8] = {r0.x, r0.y, r0.z, r0.w, r1.x, r1.y, r1.z, r1.w};
          #pragma unroll
          for (int j = 0; j < 8; ++j) v[j] = gelu_f((v[j] - mm[j]) * rr[j]);
        }
        short8 t;
        #pragma unroll
        for (int j = 0; j < 8; ++j) t[j] = (short)f2bf(v[j]);
        a[mt] = t;
      }
    }
    #pragma unroll
    for (int nt = 0; nt < 4; ++nt) {
      const int o = og + wn * 64 + nt * 16 + l15;
      bfr[nt] = *(const short8*)(Wp + (size_t)o * 128 + kb);
    }
    #pragma unroll
    for (int mt = 0; mt < 4; ++mt)
      #pragma unroll
      for (int nt = 0; nt < 4; ++nt)
        acc[mt][nt] = __builtin_amdgcn_mfma_f32_16x16x32_bf16(a[mt], bfr[nt], acc[mt][nt], 0, 0, 0);
  }

  #pragma unroll
  for (int nt = 0; nt < 4; ++nt) {
    const int o = og + wn * 64 + nt * 16 + l15;
    const float bb = bias[o];
    float s = 0.f, q = 0.f;
    #pragma unroll
    for (int mt = 0; mt < 4; ++mt) {
      #pragma unroll
      for (int r = 0; r < 4; ++r) {
        const int t = t0 + wm * 64 + mt * 16 + l4 * 4 + r;
        const float v = acc[mt][nt][r] + bb;
        if constexpr (POST == 0) {
          Yf[(size_t)t * O + o] = v;
        } else if constexpr (POST == 2) {
          Yb[(size_t)t * O + o] = f2bf(v);
        }
        if constexpr (STATS) { s += v; q += v * v; }
      }
    }
    if constexpr (STATS) {
      s += __shfl_xor(s, 16); s += __shfl_xor(s, 32);
      q += __shfl_xor(q, 16); q += __shfl_xor(q, 32);
      if (l4 == 0) { sumb[o - og][wm] = s; sqb[o - og][wm] = q; }
    }
  }
  if constexpr (STATS) {
    __syncthreads();
    if (tid < 128) {
      ps[blockIdx.y * 128 + tid] = sumb[tid][0] + sumb[tid][1];
      pss[blockIdx.y * 128 + tid] = sqb[tid][0] + sqb[tid][1];
    }
  }
}

// ---------------------------------------------------------------------------
// K4: fused gate + qkv GEMM. Block = 128 tokens; 4 waves 2x2.
// Phase A: x_mod = x * sigmoid(gelu(inorm(mpre)) @ modw2^T + b2) -> swizzled
//          32KB LDS tile (bf16 [tl][k], byte col ^ ((tl&7)<<4)).
// Phase B: qkv[t][h*48+sec*16+ch] = x_mod @ qkv_w^T + qkv_b (3 chunks of 128 o)
// ---------------------------------------------------------------------------
__global__ __launch_bounds__(256) void gateqkv_mfma_kernel(
    const unsigned short* __restrict__ mpreb, const unsigned short* __restrict__ modw2P,
    const float* __restrict__ mod_b2, const unsigned short* __restrict__ xtb,
    const unsigned short* __restrict__ qkvP, const float* __restrict__ qkv_b,
    unsigned short* __restrict__ qkvt, const float* __restrict__ mu,
    const float* __restrict__ rs) {
  __shared__ char xm[32768];  // 128 x 256B rows, XOR-swizzled cols
  const int tid = threadIdx.x;
  const int lane = tid & 63, wid = tid >> 6;
  const int wm = wid >> 1, wn = wid & 1;
  const int l15 = lane & 15, l4 = lane >> 4;
  const int t0 = blockIdx.x * 128;
  const int bidx = t0 >> 15;

  f32x4 acc[4][4];
  #pragma unroll
  for (int mt = 0; mt < 4; ++mt)
    #pragma unroll
    for (int nt = 0; nt < 4; ++nt)
      #pragma unroll
      for (int r = 0; r < 4; ++r) acc[mt][nt][r] = 0.f;

  // Phase A: gate GEMM (A = gelu(inorm(mpre)) bf16, B = modw2P)
  #pragma unroll
  for (int ks = 0; ks < 4; ++ks) {
    const int kb = ks * 32 + l4 * 8;
    short8 a[4], bfr[4];
    const float4 m0 = *(const float4*)(mu + bidx * 128 + kb);
    const float4 m1 = *(const float4*)(mu + bidx * 128 + kb + 4);
    const float4 r0 = *(const float4*)(rs + bidx * 128 + kb);
    const float4 r1 = *(const float4*)(rs + bidx * 128 + kb + 4);
    const float mm[8] = {m0.x, m0.y, m0.z, m0.w, m1.x, m1.y, m1.z, m1.w};
    const float rr[8] = {r0.x, r0.y, r0.z, r0.w, r1.x, r1.y, r1.z, r1.w};
    #pragma unroll
    for (int mt = 0; mt < 4; ++mt) {
      const int tok = t0 + wm * 64 + mt * 16 + l15;
      float v[16];
      bf16x16_load(mpreb + (size_t)tok * 128 + kb, v);
      short8 t;
      #pragma unroll
      for (int j = 0; j < 8; ++j) t[j] = (short)f2bf(gelu_f((v[j] - mm[j]) * rr[j]));
      a[mt] = t;
    }
    #pragma unroll
    for (int nt = 0; nt < 4; ++nt) {
      const int o = wn * 64 + nt * 16 + l15;
      bfr[nt] = *(const short8*)(modw2P + (size_t)o * 128 + kb);
    }
    #pragma unroll
    for (int mt = 0; mt < 4; ++mt)
      #pragma unroll
      for (int nt = 0; nt < 4; ++nt)
        acc[mt][nt] = __builtin_amdgcn_mfma_f32_16x16x32_bf16(a[mt], bfr[nt], acc[mt][nt], 0, 0, 0);
  }
  // epilogue A: x_mod -> swizzled LDS
  #pragma unroll
  for (int nt = 0; nt < 4; ++nt) {
    const int o = wn * 64 + nt * 16 + l15;
    const float bb = mod_b2[o];
    #pragma unroll
    for (int mt = 0; mt < 4; ++mt) {
      #pragma unroll
      for (int r = 0; r < 4; ++r) {
        const int tl = wm * 64 + mt * 16 + l4 * 4 + r;
        const int t = t0 + tl;
        const float v = sigmoid_f(acc[mt][nt][r] + bb) * bf2f(xtb[(size_t)t * 128 + o]);
        *(unsigned short*)(xm + tl * 256 + ((o * 2) ^ ((tl & 7) << 4))) = f2bf(v);
      }
    }
  }
  __syncthreads();

  // Phase B: qkv GEMM, 3 output chunks of 128
  for (int c = 0; c < 3; ++c) {
    #pragma unroll
    for (int mt = 0; mt < 4; ++mt)
      #pragma unroll
      for (int nt = 0; nt < 4; ++nt)
        #pragma unroll
        for (int r = 0; r < 4; ++r) acc[mt][nt][r] = 0.f;
    #pragma unroll
    for (int ks = 0; ks < 4; ++ks) {
      const int kb = ks * 32 + l4 * 8;
      short8 a[4], bfr[4];
      #pragma unroll
      for (int mt = 0; mt < 4; ++mt) {
        const int tl = wm * 64 + mt * 16 + l15;
        a[mt] = *(const short8*)(xm + tl * 256 + ((kb * 2) ^ ((tl & 7) << 4)));
      }
      #pragma unroll
      for (int nt = 0; nt < 4; ++nt) {
        const int o = c * 128 + wn * 64 + nt * 16 + l15;
        bfr[nt] = *(const short8*)(qkvP + (size_t)o * 128 + kb);
      }
      #pragma unroll
      for (int mt = 0; mt < 4; ++mt)
        #pragma unroll
        for (int nt = 0; nt < 4; ++nt)
          acc[mt][nt] = __builtin_amdgcn_mfma_f32_16x16x32_bf16(a[mt], bfr[nt], acc[mt][nt], 0, 0, 0);
    }
    #pragma unroll
    for (int nt = 0; nt < 4; ++nt) {
      const int o = c * 128 + wn * 64 + nt * 16 + l15;
      const float bb = qkv_b[o];
      const int hsub = (o & 127) >> 4, ch = o & 15;
      #pragma unroll
      for (int mt = 0; mt < 4; ++mt) {
        #pragma unroll
        for (int r = 0; r < 4; ++r) {
          const int t = t0 + wm * 64 + mt * 16 + l4 * 4 + r;
          qkvt[(size_t)t * 384 + hsub * 48 + c * 16 + ch] = f2bf(acc[mt][nt][r] + bb);
        }
      }
    }
  }
}

// ---------------------------------------------------------------------------
// K6: final projection over A0+A1+A2 (bf16), swapped orientation -> NCDHW
// ---------------------------------------------------------------------------
__global__ __launch_bounds__(256) void proj_mfma_kernel(
    const unsigned short* __restrict__ A0b, const unsigned short* __restrict__ A1b,
    const unsigned short* __restrict__ A2b, const unsigned short* __restrict__ Wp,
    const float* __restrict__ bias, float* __restrict__ out) {
  const int tid = threadIdx.x;
  const int lane = tid & 63, wid = tid >> 6;
  const int wm = wid >> 1, wn = wid & 1;
  const int l15 = lane & 15, l4 = lane >> 4;
  const int t0 = blockIdx.x * 128;

  f32x4 acc[4][4];
  #pragma unroll
  for (int mt = 0; mt < 4; ++mt)
    #pragma unroll
    for (int nt = 0; nt < 4; ++nt)
      #pragma unroll
      for (int r = 0; r < 4; ++r) acc[mt][nt][r] = 0.f;

  #pragma unroll
  for (int ks = 0; ks < 4; ++ks) {
    const int kb = ks * 32 + l4 * 8;
    short8 a[4], bfr[4];
    #pragma unroll
    for (int mt = 0; mt < 4; ++mt) {
      const int o = wm * 64 + mt * 16 + l15;
      a[mt] = *(const short8*)(Wp + (size_t)o * 128 + kb);
    }
    #pragma unroll
    for (int nt = 0; nt < 4; ++nt) {
      const int tok = t0 + wn * 64 + nt * 16 + l15;
      const size_t off = (size_t)tok * 128 + kb;
      short8 s0 = *(const short8*)(A0b + off);
      short8 s1 = *(const short8*)(A1b + off);
      short8 s2 = *(const short8*)(A2b + off);
      short8 r;
      #pragma unroll
      for (int i = 0; i < 8; ++i) {
        float f = bf2f((unsigned short)s0[i]) + bf2f((unsigned short)s1[i]) +
                  bf2f((unsigned short)s2[i]);
        r[i] = (short)f2bf(f);
      }
      bfr[nt] = r;
    }
    #pragma unroll
    for (int mt = 0; mt < 4; ++mt)
      #pragma unroll
      for (int nt = 0; nt < 4; ++nt)
        acc[mt][nt] = __builtin_amdgcn_mfma_f32_16x16x32_bf16(a[mt], bfr[nt], acc[mt][nt], 0, 0, 0);
  }

  #pragma unroll
  for (int nt = 0; nt < 4; ++nt) {
    const int tok = t0 + wn * 64 + nt * 16 + l15;
    const int dhw = tok & 32767, bB = tok >> 15;
    #pragma unroll
    for (int mt = 0; mt < 4; ++mt) {
      #pragma unroll
      for (int r = 0; r < 4; ++r) {
        const int o = wm * 64 + mt * 16 + l4 * 4 + r;
        out[((size_t)(bB * 128 + o) << 15) + dhw] = acc[mt][nt][r] + bias[o];
      }
    }
  }
}

// ---------------------------------------------------------------------------
// K7: axial attention via MFMA, v3 (r12 proven). One 512-thread block per
// (seq, axial); 8 waves = 8 heads; coalesced interleaved-qkv staging.
// ---------------------------------------------------------------------------
__global__ __launch_bounds__(512) void attn_mfma_kernel(
    const unsigned short* __restrict__ qkvt, const float* __restrict__ Rbuf,
    const float* __restrict__ pbw, unsigned short* __restrict__ a0,
    unsigned short* __restrict__ a1, unsigned short* __restrict__ a2) {
  __shared__ unsigned short rows[32 * 392];  // pitch 392 ush = 784B (16B aligned)
  __shared__ unsigned short Vt[8][16 * 40];  // per-head [d][tok]
  __shared__ float Ot[8][32 * 20];           // per-head [tok][d]
  const int axial = blockIdx.y;
  const int seq = blockIdx.x;
  unsigned short* dstbuf = (axial == 0) ? a0 : ((axial == 1) ? a1 : a2);
  const int tid = threadIdx.x;
  const int lane = tid & 63, head = tid >> 6;
  const int tok = lane & 31, hi = lane >> 5;
  const int b = seq >> 10, rem = seq & 1023;
  const int u = rem >> 5, v = rem & 31;
  int base, stride, comp;
  if (axial == 0)      { base = (b << 15) + (u << 5) + v;         stride = 1024; comp = 2; }
  else if (axial == 1) { base = (b << 15) + (u << 10) + v;        stride = 32;   comp = 1; }
  else                 { base = (b << 15) + (u << 10) + (v << 5); stride = 1;    comp = 0; }

  #pragma unroll
  for (int p = 0; p < 3; ++p) {
    const int c = p * 512 + tid;
    const int r = c / 48, cw = c - r * 48;
    const size_t src = ((size_t)base + (size_t)r * stride) * 384 + (size_t)cw * 8;
    *(uint4*)((char*)rows + r * 784 + cw * 16) = *(const uint4*)(qkvt + src);
  }
  __syncthreads();

  const float* Rp = Rbuf + (axial * 8 + head) * 18;
  const float rq00 = fabsf(Rp[0]);
  const unsigned short* myrow = rows + tok * 392 + head * 48;
  short8 aq = *(const short8*)(myrow + hi * 8);
  short8 ak = *(const short8*)(myrow + 16 + hi * 8);
  short8 av = *(const short8*)(myrow + 32 + hi * 8);
  if (hi) {
    aq[7] = (short)f2bf(bf2f((unsigned short)aq[7]) * rq00);
    ak[7] = (short)f2bf(bf2f((unsigned short)ak[7]) * rq00);
  }
  #pragma unroll
  for (int e = 0; e < 8; ++e) Vt[head][(hi * 8 + e) * 40 + tok] = (unsigned short)av[e];

  f32x16 sacc;
  #pragma unroll
  for (int r = 0; r < 16; ++r) sacc[r] = 0.f;
  sacc = __builtin_amdgcn_mfma_f32_32x32x16_bf16(ak, aq, sacc, 0, 0, 0);
  const float wb = pbw[comp];
  float p[16];
  float mmax = -1e30f;
  #pragma unroll
  for (int r = 0; r < 16; ++r) {
    const int kk = (r & 3) + 4 * hi + 8 * (r >> 2);
    const float lin = -1.0f + (2.0f / 31.0f) * (float)kk;
    p[r] = sacc[r] * 0.25f - lin * wb;
    mmax = fmaxf(mmax, p[r]);
  }
  mmax = fmaxf(mmax, __shfl_xor(mmax, 32));
  float sum = 0.f;
  #pragma unroll
  for (int r = 0; r < 16; ++r) { p[r] = expf(p[r] - mmax); sum += p[r]; }
  sum += __shfl_xor(sum, 32);
  const float inv = 1.0f / sum;
  #pragma unroll
  for (int r = 0; r < 16; ++r) p[r] *= inv;
  unsigned pk[8], sw[8];
  #pragma unroll
  for (int j = 0; j < 8; ++j) {
    unsigned r_;
    asm("v_cvt_pk_bf16_f32 %0, %1, %2" : "=v"(r_) : "v"(p[2 * j]), "v"(p[2 * j + 1]));
    pk[j] = r_;
  }
  #pragma unroll
  for (int j = 0; j < 8; ++j) sw[j] = (unsigned)__shfl_xor((int)pk[j], 32);
  uint4 Fu, Gu;
  Fu.x = hi ? sw[2] : pk[0];
  Fu.y = hi ? sw[3] : pk[1];
  Fu.z = hi ? pk[2] : sw[0];
  Fu.w = hi ? pk[3] : sw[1];
  Gu.x = hi ? sw[6] : pk[4];
  Gu.y = hi ? sw[7] : pk[5];
  Gu.z = hi ? pk[6] : sw[4];
  Gu.w = hi ? pk[7] : sw[5];
  short8 Pf = *(short8*)&Fu;
  short8 Pg = *(short8*)&Gu;
  const unsigned short* vrow = Vt[head] + (tok & 15) * 40;
  short8 Bv0 = *(const short8*)(vrow + hi * 8);
  short8 Bv1 = *(const short8*)(vrow + 16 + hi * 8);
  f32x16 oacc;
  #pragma unroll
  for (int r = 0; r < 16; ++r) oacc[r] = 0.f;
  oacc = __builtin_amdgcn_mfma_f32_32x32x16_bf16(Pf, Bv0, oacc, 0, 0, 0);
  oacc = __builtin_amdgcn_mfma_f32_32x32x16_bf16(Pg, Bv1, oacc, 0, 0, 0);
  if (tok < 16) {
    #pragma unroll
    for (int r = 0; r < 16; ++r) {
      const int q = (r & 3) + 4 * hi + 8 * (r >> 2);
      Ot[head][q * 20 + tok] = oacc[r];
    }
  }
  if (lane < 32) {
    float o16[16], y16[16], Rv[9];
    #pragma unroll
    for (int j = 0; j < 16; ++j) o16[j] = Ot[head][lane * 20 + j];
    #pragma unroll
    for (int i = 0; i < 9; ++i) Rv[i] = Rp[9 + i];
    rot16(Rv, o16, y16);
    unsigned outw[8];
    #pragma unroll
    for (int j = 0; j < 8; ++j)
      outw[j] = ((unsigned)f2bf(y16[2 * j + 1]) << 16) | (unsigned)f2bf(y16[2 * j]);
    const size_t t2 = (size_t)base + (size_t)lane * stride;
    unsigned short* dst = dstbuf + t2 * 128 + head * 16;
    uint4 o0 = {outw[0], outw[1], outw[2], outw[3]};
    uint4 o1 = {outw[4], outw[5], outw[6], outw[7]};
    *(uint4*)dst = o0;
    *(uint4*)(dst + 8) = o1;
  }
}

// ---------------------------------------------------------------------------
extern "C" void kernel_launch(void* const* d_in, const int* in_sizes, int n_in,
                              void* d_out, int out_size, void* d_ws, size_t ws_size,
                              hipStream_t stream) {
  const float* x       = (const float*)d_in[0];
  const float* pos_emb = (const float*)d_in[1];
  const float* qkv_w   = (const float*)d_in[2];
  const float* qkv_b   = (const float*)d_in[3];
  const float* lp_w1   = (const float*)d_in[4];
  const float* lp_b1   = (const float*)d_in[5];
  const float* lp_w2   = (const float*)d_in[6];
  const float* lp_b2   = (const float*)d_in[7];
  const float* mod_w1  = (const float*)d_in[8];
  const float* mod_b1  = (const float*)d_in[9];
  const float* mod_w2  = (const float*)d_in[10];
  const float* mod_b2  = (const float*)d_in[11];
  // d_in[12] pa_w, d_in[13] pa_b: cancel in softmax (constant along key axis)
  const float* proj_w  = (const float*)d_in[14];
  const float* proj_b  = (const float*)d_in[15];
  const float* pbw     = (const float*)d_in[16];
  // d_in[17] pos_bias_b: cancels in softmax
  const float* Ad      = (const float*)d_in[18];
  const float* Ah      = (const float*)d_in[19];
  const float* Aw      = (const float*)d_in[20];
  const float* Rd      = (const float*)d_in[21];
  const float* Rh      = (const float*)d_in[22];
  const float* Rw      = (const float*)d_in[23];
  // d_in[24..26] t_d/t_h/t_w: cancel in rel (pairwise difference)

  float* ws = (float*)d_ws;
  unsigned short* lfb    = (unsigned short*)(ws + WS_R0);   // lf bf16
  unsigned short* A0b    = (unsigned short*)(ws + WS_A0);
  unsigned short* A1b    = (unsigned short*)(ws + WS_A1);
  unsigned short* A2b    = (unsigned short*)(ws + WS_A2);
  unsigned short* mpreb  = (unsigned short*)(ws + WS_MPREB);
  unsigned short* xtokb  = (unsigned short*)(ws + WS_XTOKB);
  unsigned short* inT    = (unsigned short*)(ws + WS_INT);
  unsigned short* qkvt   = (unsigned short*)(ws + WS_QKVH);
  unsigned short* convP  = (unsigned short*)(ws + WS_CONVP);
  unsigned short* qkvP   = (unsigned short*)(ws + WS_QKVP);
  unsigned short* WcP    = (unsigned short*)(ws + WS_WCP);
  unsigned short* modw2P = (unsigned short*)(ws + WS_MODW2P);
  unsigned short* projP  = (unsigned short*)(ws + WS_PROJP);
  float* bc     = ws + WS_BC;
  float* Rbuf   = ws + WS_RBUF;
  float* ps     = ws + WS_PS;
  float* pss    = ws + WS_PSS;
  float* mu1    = ws + WS_MU1;
  float* rs1    = ws + WS_RS1;
  float* mu2    = ws + WS_MU2;
  float* rs2    = ws + WS_RS2;

  // merged prep + transposes
  prep_transpose_kernel<<<2304, 256, 0, stream>>>(
      lp_w1, qkv_w, mod_w1, lp_w2, lp_b2, mod_b1, mod_w2, proj_w,
      Ad, Ah, Aw, Rd, Rh, Rw, x, pos_emb,
      convP, qkvP, WcP, modw2P, projP, bc, Rbuf, xtokb, inT);
  // lf (bf16) = circular conv3x3x3(pos_emb), fused fp32 stats partials
  conv_mfma_kernel<<<1024, 256, 0, stream>>>(inT, convP, lp_b1, lfb, ps, pss);
  stats_final_kernel<<<256, 64, 0, stream>>>(ps, pss, mu1, rs1, 512);
  // m_pre (bf16) = gelu(inorm(lf)) @ Wc^T + bc, fused stats partials
  gemm_mfma_kernel<1, 1, 2, 1><<<dim3(1, 512), 256, 0, stream>>>(
      lfb, WcP, bc, mpreb, 128, mu1, rs1, nullptr, ps, pss);
  stats_final_kernel<<<256, 64, 0, stream>>>(ps, pss, mu2, rs2, 256);
  // fused: x_mod (LDS) = x * sigmoid(gelu(inorm(m_pre)) @ modw2^T + b2);
  //        qkv (bf16, interleaved) = x_mod @ qkv_w^T + qkv_b
  gateqkv_mfma_kernel<<<512, 256, 0, stream>>>(
      mpreb, modw2P, mod_b2, xtokb, qkvP, qkv_b, qkvt, mu2, rs2);
  // attention: one 512-thread block per (seq, axial), 8 heads in-block
  attn_mfma_kernel<<<dim3(2048, 3), 512, 0, stream>>>(qkvt, Rbuf, pbw, A0b, A1b, A2b);
  proj_mfma_kernel<<<512, 256, 0, stream>>>(A0b, A1b, A2b, projP, proj_b, (float*)d_out);
}

// Round 14
// 227.997 us; speedup vs baseline: 1.3456x; 1.1007x over previous
//
#include <hip/hip_runtime.h>
#include <cstdint>
#include <cstddef>

// ---------------------------------------------------------------------------
// Problem constants: B=2, C=128, D=H=W=32, nh=8, hd=16, L=32
// Tokens: t = b*32768 + d*1024 + h*32 + w   (65536 tokens, 128 channels)
// ---------------------------------------------------------------------------

#define NTOK 65536
#define SPAT 32768

// ws offsets (floats). Same proven map as r7-r13 (136.4 MB).
#define WS_R0     0ull          // region: lf bf16 (8388608 ush) -> A0/A1
#define WS_A0     0ull          // 4194304 (8388608 ush)
#define WS_A1     4194304ull    // 4194304
#define WS_MPREB  8388608ull    // 4194304 (8388608 ush)
#define WS_A2     8388608ull    // 4194304 (overlays dead MPREB)
#define WS_XTOKB  12582912ull   // 4194304 (8388608 ush)
#define WS_INT    16777216ull   // 4194304 (8388608 ush): pos_emb bf16
#define WS_QKVH   20971520ull   // 12582912 (25165824 ush) [t][h*48+sec*16+ch]
#define WS_CONVP  33554432ull   // 221184 (442368 ush) [tap][dx][ks][l4][co][8]
#define WS_QKVP   33775616ull   // 24576  (49152 ush)
#define WS_WCP    33800192ull   // 8192
#define WS_MODW2P 33808384ull   // 8192
#define WS_PROJP  33816576ull   // 8192
#define WS_BC     33824768ull   // 128
#define WS_RBUF   33824896ull   // 432
#define WS_PS     33825328ull   // 131072 (1024 blocks x 128)
#define WS_PSS    33956400ull   // 131072
#define WS_MU1    34087472ull   // 256
#define WS_RS1    34087728ull   // 256
#define WS_MU2    34087984ull   // 256
#define WS_RS2    34088240ull   // 256
// total 34088496 floats = 136.4 MB

typedef __attribute__((ext_vector_type(8))) short short8;
typedef __attribute__((ext_vector_type(4))) float f32x4;
typedef __attribute__((ext_vector_type(16))) float f32x16;

// tanh-form gelu: branch-free, ~13 VALU ops (vs ~25 divergent for erff).
// |err| <= ~1e-3 absolute on inorm-scale inputs -- below bf16 rounding here.
__device__ __forceinline__ float gelu_f(float x) {
  float u = 0.79788456080286536f * (x + 0.044715f * x * x * x);
  u = fminf(u, 40.0f);                     // overflow guard (tanh->1)
  float e = __expf(2.0f * u);
  float t = (e - 1.0f) / (e + 1.0f);
  return 0.5f * x * (1.0f + t);
}
__device__ __forceinline__ float sigmoid_f(float x) {
  return 1.0f / (1.0f + __expf(-x));
}
__device__ __forceinline__ unsigned short f2bf(float x) {  // RNE f32->bf16
  unsigned int u = __float_as_uint(x);
  unsigned int r = u + 0x7fffu + ((u >> 16) & 1u);
  return (unsigned short)(r >> 16);
}
__device__ __forceinline__ float bf2f(unsigned short u) {
  return __uint_as_float(((unsigned int)u) << 16);
}
// 16 consecutive bf16 -> 16 fp32
__device__ __forceinline__ void bf16x16_load(const unsigned short* p, float* f) {
  const uint4 a = *(const uint4*)p;
  const uint4 b = *(const uint4*)(p + 8);
  const unsigned int w[8] = {a.x, a.y, a.z, a.w, b.x, b.y, b.z, b.w};
  #pragma unroll
  for (int i = 0; i < 8; ++i) {
    f[2 * i] = __uint_as_float(w[i] << 16);
    f[2 * i + 1] = __uint_as_float(w[i] & 0xffff0000u);
  }
}
// 8 consecutive bf16 -> 8 fp32
__device__ __forceinline__ void bf16x8_load(const unsigned short* p, float* f) {
  const uint4 a = *(const uint4*)p;
  const unsigned int w[4] = {a.x, a.y, a.z, a.w};
  #pragma unroll
  for (int i = 0; i < 4; ++i) {
    f[2 * i] = __uint_as_float(w[i] << 16);
    f[2 * i + 1] = __uint_as_float(w[i] & 0xffff0000u);
  }
}
// async global->LDS, 16B per lane (dest must be wave-uniform base + lane*16)
__device__ __forceinline__ void gload_lds16(const void* g, void* l) {
  __builtin_amdgcn_global_load_lds(
      (const __attribute__((address_space(1))) unsigned int*)g,
      (__attribute__((address_space(3))) unsigned int*)l, 16, 0, 0);
}
__device__ __forceinline__ float dot3(const float* a, const float* b) {
  return a[0] * b[0] + a[1] * b[1] + a[2] * b[2];
}
__device__ __forceinline__ void cross3(const float* a, const float* b, float* c) {
  c[0] = a[1] * b[2] - a[2] * b[1];
  c[1] = a[2] * b[0] - a[0] * b[2];
  c[2] = a[0] * b[1] - a[1] * b[0];
}

// exact port of _r6_to_matrix for one head (6 floats in, 9 out row-major)
__device__ void r6_to_matrix(const float* r6, float* R) {
  float v1[3] = {r6[0], r6[1], r6[2]};
  float n1 = sqrtf(dot3(v1, v1));
  float inv1 = 1.0f / (n1 + 1e-7f);
  v1[0] *= inv1; v1[1] *= inv1; v1[2] *= inv1;
  float v2[3] = {r6[3], r6[4], r6[5]};
  float d = dot3(v2, v1);
  v2[0] -= d * v1[0]; v2[1] -= d * v1[1]; v2[2] -= d * v1[2];
  float n2 = sqrtf(dot3(v2, v2));
  float inv2 = 1.0f / (n2 + 1e-7f);
  v2[0] *= inv2; v2[1] *= inv2; v2[2] *= inv2;
  float v3[3]; cross3(v1, v2, v3);
  float cx[3]; cross3(v2, v3, cx);
  float det = dot3(v1, cx);
  if (det < 0.0f) { v3[0] = -v3[0]; v3[1] = -v3[1]; v3[2] = -v3[2]; }
  R[0] = v1[0]; R[1] = v1[1]; R[2] = v1[2];
  R[3] = v2[0]; R[4] = v2[1]; R[5] = v2[2];
  R[6] = v3[0]; R[7] = v3[1]; R[8] = v3[2];
}

// exact port of _ensure_matrix for one head (9 in row-major, 9 out)
__device__ void ensure_matrix(const float* Rin, float* Ro) {
  float a[3] = {Rin[0] + 1e-6f, Rin[1] + 1e-6f, Rin[2] + 1e-6f};
  float na = fmaxf(sqrtf(dot3(a, a)), 1e-12f);
  float v1[3] = {a[0] / na, a[1] / na, a[2] / na};
  float b0[3] = {Rin[3], Rin[4], Rin[5]};
  float d = dot3(b0, v1);
  float bb[3] = {b0[0] - d * v1[0] + 1e-6f, b0[1] - d * v1[1] + 1e-6f, b0[2] - d * v1[2] + 1e-6f};
  float nb = fmaxf(sqrtf(dot3(bb, bb)), 1e-12f);
  float v2[3] = {bb[0] / nb, bb[1] / nb, bb[2] / nb};
  float v3[3]; cross3(v1, v2, v3);
  float cx[3]; cross3(v2, v3, cx);
  float det = dot3(v1, cx);
  if (det < 0.0f) { v3[0] = -v3[0]; v3[1] = -v3[1]; v3[2] = -v3[2]; }
  float Rn[9] = {v1[0], v1[1], v1[2], v2[0], v2[1], v2[2], v3[0], v3[1], v3[2]};
  float T1[9], T2[9];
  for (int i = 0; i < 3; ++i)
    for (int j = 0; j < 3; ++j) {
      float s = 0.f;
      for (int k = 0; k < 3; ++k) s += Rn[k * 3 + i] * Rn[k * 3 + j];
      T1[i * 3 + j] = s;
    }
  for (int i = 0; i < 3; ++i)
    for (int j = 0; j < 3; ++j) {
      float s = 0.f;
      for (int k = 0; k < 3; ++k) s += T1[i * 3 + k] * Rn[j * 3 + k];
      T2[i * 3 + j] = s;
    }
  for (int i = 0; i < 9; ++i) Ro[i] = 0.5f * (Rn[i] + T2[i]);
}

// y = R_eff x for hd=16 (5 full 3x3 groups + scalar R00 on ch15)
__device__ __forceinline__ void rot16(const float* R, const float* x, float* y) {
  #pragma unroll
  for (int g = 0; g < 5; ++g) {
    float a = x[3 * g], b = x[3 * g + 1], c = x[3 * g + 2];
    y[3 * g + 0] = R[0] * a + R[1] * b + R[2] * c;
    y[3 * g + 1] = R[3] * a + R[4] * b + R[5] * c;
    y[3 * g + 2] = R[6] * a + R[7] * b + R[8] * c;
  }
  y[15] = R[0] * x[15];
}

// ---------------------------------------------------------------------------
// K0: merged prep (blocks 0..255) + transposes (blocks 256..2303)
// ---------------------------------------------------------------------------
__global__ __launch_bounds__(256) void prep_transpose_kernel(
    const float* __restrict__ lp_w1, const float* __restrict__ qkv_w,
    const float* __restrict__ mod_w1, const float* __restrict__ lp_w2,
    const float* __restrict__ lp_b2, const float* __restrict__ mod_b1,
    const float* __restrict__ mod_w2, const float* __restrict__ proj_w,
    const float* __restrict__ Ad, const float* __restrict__ Ah,
    const float* __restrict__ Aw, const float* __restrict__ Rd,
    const float* __restrict__ Rh, const float* __restrict__ Rw,
    const float* __restrict__ x, const float* __restrict__ pe,
    unsigned short* __restrict__ convP, unsigned short* __restrict__ qkvP,
    unsigned short* __restrict__ WcP, unsigned short* __restrict__ modw2P,
    unsigned short* __restrict__ projP, float* __restrict__ bc,
    float* __restrict__ Rbuf, unsigned short* __restrict__ xtokb,
    unsigned short* __restrict__ inT) {
  __shared__ float lds[32][132];
  if (blockIdx.x < 256) {
    int gid = blockIdx.x * 256 + threadIdx.x;  // 65536 threads
    for (int f = gid; f < 442368; f += 65536) {
      int e = f & 7;
      int co = (f >> 3) & 127;
      int rest = f >> 10;
      int l4 = rest & 3;
      int ks = (rest >> 2) & 3;
      int dxt = rest >> 4;
      int dx = dxt % 3;
      int tap = dxt / 3;
      int dz = tap / 3, dy = tap % 3;
      int ci = ks * 32 + l4 * 8 + e;
      convP[f] = f2bf(lp_w1[(co * 128 + ci) * 27 + dz * 9 + dy * 3 + dx]);
    }
    if (gid < 49152) qkvP[gid] = f2bf(qkv_w[gid]);
    if (gid < 16384) {
      modw2P[gid] = f2bf(mod_w2[gid]);
      projP[gid] = f2bf(proj_w[gid]);
      int o = gid >> 7, i = gid & 127;
      float s = 0.f;
      for (int c = 0; c < 128; ++c) s += mod_w1[o * 128 + c] * lp_w2[c * 128 + i];
      WcP[gid] = f2bf(s);
    }
    if (gid < 128) {
      float s = 0.f;
      for (int c = 0; c < 128; ++c) s += mod_w1[gid * 128 + c] * lp_b2[c];
      bc[gid] = s + mod_b1[gid];
    }
    if (blockIdx.x == 0 && threadIdx.x >= 224 && threadIdx.x < 248) {
      int tid = threadIdx.x - 224;
      int ax = tid >> 3, h = tid & 7;
      const float* A = (ax == 0) ? Ad : ((ax == 1) ? Ah : Aw);
      const float* R = (ax == 0) ? Rd : ((ax == 1) ? Rh : Rw);
      float Rq[9], Rv[9];
      r6_to_matrix(A + h * 6, Rq);
      ensure_matrix(R + h * 9, Rv);
      float* dst = Rbuf + (ax * 8 + h) * 18;
      for (int i = 0; i < 9; ++i) { dst[i] = Rq[i]; dst[9 + i] = Rv[i]; }
    }
    return;
  }
  // transpose path
  int blk = blockIdx.x - 256;  // b*1024 + d*32 + h
  int b = blk >> 10;
  int dh = blk & 1023;
  int tid = threadIdx.x;
  size_t planebase = ((size_t)b << 22) + ((size_t)dh << 5);
  size_t tb = ((size_t)blk) << 5;
  #pragma unroll
  for (int r = 0; r < 16; ++r) {
    int idx = r * 256 + tid;
    int ci = idx >> 5, w = idx & 31;
    lds[w][ci] = x[planebase + ((size_t)ci << 15) + w];
  }
  __syncthreads();
  #pragma unroll
  for (int r = 0; r < 16; ++r) {
    int idx = r * 256 + tid;
    int w = idx >> 7, ci = idx & 127;
    xtokb[(tb + w) * 128 + ci] = f2bf(lds[w][ci]);
  }
  __syncthreads();
  #pragma unroll
  for (int r = 0; r < 16; ++r) {
    int idx = r * 256 + tid;
    int ci = idx >> 5, w = idx & 31;
    lds[w][ci] = pe[planebase + ((size_t)ci << 15) + w];
  }
  __syncthreads();
  #pragma unroll
  for (int r = 0; r < 16; ++r) {
    int idx = r * 256 + tid;
    int w = idx >> 7, ci = idx & 127;
    inT[(tb + w) * 128 + ci] = f2bf(lds[w][ci]);
  }
}

// ---------------------------------------------------------------------------
// K1: 3x3x3 circular conv via bf16 MFMA, v7 + XCD swizzle (r13 proven).
// ---------------------------------------------------------------------------
__global__ __launch_bounds__(256, 4) void conv_mfma_kernel(
    const unsigned short* __restrict__ inT, const unsigned short* __restrict__ Bp,
    const float* __restrict__ b1, unsigned short* __restrict__ out,
    float* __restrict__ ps, float* __restrict__ pss) {
  __shared__ unsigned short Als[16384];  // 32KB: 4 rows x 32 w x 128 ci, swizzled
  __shared__ float sumb[128];
  __shared__ float sqb[128];
  const int orig = blockIdx.x;
  const int blk = ((orig & 7) << 7) + (orig >> 3);  // XCD-chunked bijective swizzle
  const int b = blk >> 9, d = (blk >> 4) & 31, hg = blk & 15;
  const int h0 = hg << 1;                 // 2 output h-rows
  const int tid = threadIdx.x;
  const int lane = tid & 63;
  const int wid = tid >> 6;               // N-split: wave owns co [wid*32, wid*32+32)
  const int l15 = lane & 15, l4 = lane >> 4;

  f32x4 acc[4][2];
  #pragma unroll
  for (int mt = 0; mt < 4; ++mt)
    #pragma unroll
    for (int nt = 0; nt < 2; ++nt)
      #pragma unroll
      for (int r = 0; r < 4; ++r) acc[mt][nt][r] = 0.f;

  int mw[4], mhh[4];
  #pragma unroll
  for (int mt = 0; mt < 4; ++mt) {
    int m = mt * 16 + l15;                // tokens 0..63
    mhh[mt] = m >> 5;
    mw[mt] = m & 31;
  }
  const size_t tokbase = ((size_t)b << 15) + ((size_t)d << 10) + ((size_t)h0 << 5);

  auto stage = [&](int dz) {
    const int zr = (d + dz + 31) & 31;
    #pragma unroll
    for (int p = 0; p < 8; ++p) {
      const int g = p * 256 + tid;        // 2048 chunks of 16B
      const int tok = g >> 4, gi = g & 15;
      const int r = tok >> 5, w = tok & 31;
      const int yr = (h0 + r + 31) & 31;
      const size_t srcbyte = ((((size_t)b << 15) + ((size_t)zr << 10) + ((size_t)yr << 5) + w) << 8)
                             + (size_t)((gi ^ (w & 7)) << 4);
      gload_lds16((const char*)inT + srcbyte, (char*)Als + (size_t)g * 16);
    }
  };

  auto compute = [&](int dz) {
    #pragma unroll
    for (int dy = 0; dy < 3; ++dy) {
      const int tap = dz * 3 + dy;
      #pragma unroll
      for (int dx = 0; dx < 3; ++dx) {
        int abase[4], asw[4];
        #pragma unroll
        for (int mt = 0; mt < 4; ++mt) {
          const int wsft = (mw[mt] + dx + 31) & 31;
          const int stok = (mhh[mt] + dy) * 32 + wsft;
          abase[mt] = stok * 256;
          asw[mt] = (wsft & 7) << 4;
        }
        #pragma unroll
        for (int ks = 0; ks < 4; ++ks) {
          const int k2 = (ks * 32 + l4 * 8) * 2;
          const int bbase = (((tap * 3 + dx) * 4 + ks) * 4 + l4) * 1024;
          short8 afr[4], bfr[2];
          #pragma unroll
          for (int nt = 0; nt < 2; ++nt) {
            const int co = wid * 32 + nt * 16 + l15;
            bfr[nt] = *(const short8*)(Bp + bbase + co * 8);
          }
          #pragma unroll
          for (int mt = 0; mt < 4; ++mt)
            afr[mt] = *(const short8*)((const char*)Als + abase[mt] + (k2 ^ asw[mt]));
          __builtin_amdgcn_s_setprio(1);
          #pragma unroll
          for (int mt = 0; mt < 4; ++mt)
            #pragma unroll
            for (int nt = 0; nt < 2; ++nt)
              acc[mt][nt] = __builtin_amdgcn_mfma_f32_16x16x32_bf16(afr[mt], bfr[nt],
                                                                    acc[mt][nt], 0, 0, 0);
          __builtin_amdgcn_s_setprio(0);
        }
      }
    }
  };

  for (int dz = 0; dz < 3; ++dz) {
    stage(dz);
    __syncthreads();
    compute(dz);
    if (dz < 2) __syncthreads();
  }

  #pragma unroll
  for (int nt = 0; nt < 2; ++nt) {
    const int co = wid * 32 + nt * 16 + l15;
    const float bias = b1[co];
    float s = 0.f, q = 0.f;
    #pragma unroll
    for (int mt = 0; mt < 4; ++mt) {
      #pragma unroll
      for (int r = 0; r < 4; ++r) {
        const int m = mt * 16 + l4 * 4 + r;
        const float v = acc[mt][nt][r] + bias;
        out[(tokbase + m) * 128 + co] = f2bf(v);
        s += v; q += v * v;
      }
    }
    s += __shfl_xor(s, 16); s += __shfl_xor(s, 32);
    q += __shfl_xor(q, 16); q += __shfl_xor(q, 32);
    if (l4 == 0) { sumb[co] = s; sqb[co] = q; }
  }
  __syncthreads();
  if (tid < 128) {
    ps[blk * 128 + tid] = sumb[tid];
    pss[blk * 128 + tid] = sqb[tid];
  }
}

// ---------------------------------------------------------------------------
// K2: stats finalize, parallel
// ---------------------------------------------------------------------------
__global__ __launch_bounds__(64) void stats_final_kernel(
    const float* __restrict__ ps, const float* __restrict__ pss,
    float* __restrict__ mu, float* __restrict__ rs, int nb) {
  const int pair = blockIdx.x;  // b*128 + c
  const int b = pair >> 7, c = pair & 127;
  const int lane = threadIdx.x;
  float s = 0.f, ss = 0.f;
  for (int j = lane; j < nb; j += 64) {
    const int idx = ((b * nb + j) << 7) + c;
    s += ps[idx];
    ss += pss[idx];
  }
  #pragma unroll
  for (int o = 32; o > 0; o >>= 1) {
    s += __shfl_xor(s, o);
    ss += __shfl_xor(ss, o);
  }
  if (lane == 0) {
    float m = s * (1.0f / 32768.0f);
    float v = ss * (1.0f / 32768.0f) - m * m;
    mu[pair] = m;
    rs[pair] = rsqrtf(v + 1e-5f);
  }
}

// ---------------------------------------------------------------------------
// K3: 1x1 GEMM via bf16 MFMA, register-only (r7 proven). Used for Wc only.
// ---------------------------------------------------------------------------
template <int PRE, int AB16, int POST, int STATS>
__global__ __launch_bounds__(256) void gemm_mfma_kernel(
    const void* __restrict__ Avoid, const unsigned short* __restrict__ Wp,
    const float* __restrict__ bias, void* __restrict__ Yvoid, int O,
    const float* __restrict__ mu, const float* __restrict__ rs,
    const unsigned short* __restrict__ xtb, float* __restrict__ ps,
    float* __restrict__ pss) {
  __shared__ float sumb[128][2];
  __shared__ float sqb[128][2];
  const int tid = threadIdx.x;
  const int lane = tid & 63, wid = tid >> 6;
  const int wm = wid >> 1, wn = wid & 1;
  const int l15 = lane & 15, l4 = lane >> 4;
  const int og = blockIdx.x * 128;
  const int t0 = blockIdx.y * 128;
  const int bidx = t0 >> 15;
  const float* Af = (const float*)Avoid;
  const unsigned short* Ab = (const unsigned short*)Avoid;
  float* Yf = (float*)Yvoid;
  unsigned short* Yb = (unsigned short*)Yvoid;

  f32x4 acc[4][4];
  #pragma unroll
  for (int mt = 0; mt < 4; ++mt)
    #pragma unroll
    for (int nt = 0; nt < 4; ++nt)
      #pragma unroll
      for (int r = 0; r < 4; ++r) acc[mt][nt][r] = 0.f;

  #pragma unroll
  for (int ks = 0; ks < 4; ++ks) {
    const int kb = ks * 32 + l4 * 8;
    short8 a[4], bfr[4];
    float4 m0, m1, r0, r1;
    if constexpr (PRE == 1) {
      m0 = *(const float4*)(mu + bidx * 128 + kb);
      m1 = *(const float4*)(mu + bidx * 128 + kb + 4);
      r0 = *(const float4*)(rs + bidx * 128 + kb);
      r1 = *(const float4*)(rs + bidx * 128 + kb + 4);
    }
    #pragma unroll
    for (int mt = 0; mt < 4; ++mt) {
      const int tok = t0 + wm * 64 + mt * 16 + l15;
      float v[16];
      bool have = false;
      if constexpr (AB16 == 1) {
        if constexpr (PRE == 1) {
          bf16x16_load(Ab + (size_t)tok * 128 + kb, v);
          have = true;
        } else {
          a[mt] = *(const short8*)(Ab + (size_t)tok * 128 + kb);
        }
      } else {
        const float* ap = Af + (size_t)tok * 128 + kb;
        float4 v0 = *(const float4*)ap;
        float4 v1 = *(const float4*)(ap + 4);
        v[0] = v0.x; v[1] = v0.y; v[2] = v0.z; v[3] = v0.w;
        v[4] = v1.x; v[5] = v1.y; v[6] = v1.z; v[7] = v1.w;
        have = true;
      }
      if (have) {
        if constexpr (PRE == 1) {
          const float mm[8] = {m0.x, m0.y, m0.z, m0.w, m1.x, m1.y, m1.z, m1.w};
          const float rr[8] = {r0.x, r0.y, r0.z, r0.w, r1.x, r1.y, r1.z, r1.w};
          #pragma unroll
          for (int j = 0; j < 8; ++j) v[j] = gelu_f((v[j] - mm[j]) * rr[j]);
        }
        short8 t;
        #pragma unroll
        for (int j = 0; j < 8; ++j) t[j] = (short)f2bf(v[j]);
        a[mt] = t;
      }
    }
    #pragma unroll
    for (int nt = 0; nt < 4; ++nt) {
      const int o = og + wn * 64 + nt * 16 + l15;
      bfr[nt] = *(const short8*)(Wp + (size_t)o * 128 + kb);
    }
    #pragma unroll
    for (int mt = 0; mt < 4; ++mt)
      #pragma unroll
      for (int nt = 0; nt < 4; ++nt)
        acc[mt][nt] = __builtin_amdgcn_mfma_f32_16x16x32_bf16(a[mt], bfr[nt], acc[mt][nt], 0, 0, 0);
  }

  #pragma unroll
  for (int nt = 0; nt < 4; ++nt) {
    const int o = og + wn * 64 + nt * 16 + l15;
    const float bb = bias[o];
    float s = 0.f, q = 0.f;
    #pragma unroll
    for (int mt = 0; mt < 4; ++mt) {
      #pragma unroll
      for (int r = 0; r < 4; ++r) {
        const int t = t0 + wm * 64 + mt * 16 + l4 * 4 + r;
        const float v = acc[mt][nt][r] + bb;
        if constexpr (POST == 0) {
          Yf[(size_t)t * O + o] = v;
        } else if constexpr (POST == 2) {
          Yb[(size_t)t * O + o] = f2bf(v);
        }
        if constexpr (STATS) { s += v; q += v * v; }
      }
    }
    if constexpr (STATS) {
      s += __shfl_xor(s, 16); s += __shfl_xor(s, 32);
      q += __shfl_xor(q, 16); q += __shfl_xor(q, 32);
      if (l4 == 0) { sumb[o - og][wm] = s; sqb[o - og][wm] = q; }
    }
  }
  if constexpr (STATS) {
    __syncthreads();
    if (tid < 128) {
      ps[blockIdx.y * 128 + tid] = sumb[tid][0] + sumb[tid][1];
      pss[blockIdx.y * 128 + tid] = sqb[tid][0] + sqb[tid][1];
    }
  }
}

// ---------------------------------------------------------------------------
// K4: fused gate + qkv GEMM, v2. Block = 128 tokens; 4 waves 2x2.
// Phase 0: ga (LDS) = bf16 gelu(inorm(mpre))   [computed ONCE per element]
// Phase A: x_mod (LDS) = x * sigmoid(ga @ modw2^T + b2)
// Phase B: qkv[t][h*48+sec*16+ch] = x_mod @ qkv_w^T + qkv_b
// Both LDS tiles XOR-swizzled (byte col ^ ((tl&7)<<4)); 64KB total.
// ---------------------------------------------------------------------------
__global__ __launch_bounds__(256) void gateqkv_mfma_kernel(
    const unsigned short* __restrict__ mpreb, const unsigned short* __restrict__ modw2P,
    const float* __restrict__ mod_b2, const unsigned short* __restrict__ xtb,
    const unsigned short* __restrict__ qkvP, const float* __restrict__ qkv_b,
    unsigned short* __restrict__ qkvt, const float* __restrict__ mu,
    const float* __restrict__ rs) {
  __shared__ char ga[32768];  // gelu(inorm(mpre)) bf16, swizzled
  __shared__ char xm[32768];  // x_mod bf16, swizzled
  const int tid = threadIdx.x;
  const int lane = tid & 63, wid = tid >> 6;
  const int wm = wid >> 1, wn = wid & 1;
  const int l15 = lane & 15, l4 = lane >> 4;
  const int t0 = blockIdx.x * 128;
  const int bidx = t0 >> 15;

  // Phase 0: cooperative gelu(inorm) stage -- 2048 chunks of 8 bf16
  #pragma unroll
  for (int r = 0; r < 8; ++r) {
    const int c = r * 256 + tid;
    const int tl = c >> 4;            // token local 0..127
    const int kc = (c & 15) * 8;      // k offset
    float v[8];
    bf16x8_load(mpreb + (size_t)(t0 + tl) * 128 + kc, v);
    const float4 m0 = *(const float4*)(mu + bidx * 128 + kc);
    const float4 m1 = *(const float4*)(mu + bidx * 128 + kc + 4);
    const float4 r0 = *(const float4*)(rs + bidx * 128 + kc);
    const float4 r1 = *(const float4*)(rs + bidx * 128 + kc + 4);
    const float mm[8] = {m0.x, m0.y, m0.z, m0.w, m1.x, m1.y, m1.z, m1.w};
    const float rr[8] = {r0.x, r0.y, r0.z, r0.w, r1.x, r1.y, r1.z, r1.w};
    short8 t;
    #pragma unroll
    for (int j = 0; j < 8; ++j) t[j] = (short)f2bf(gelu_f((v[j] - mm[j]) * rr[j]));
    *(short8*)(ga + tl * 256 + ((kc * 2) ^ ((tl & 7) << 4))) = t;
  }
  __syncthreads();

  f32x4 acc[4][4];
  #pragma unroll
  for (int mt = 0; mt < 4; ++mt)
    #pragma unroll
    for (int nt = 0; nt < 4; ++nt)
      #pragma unroll
      for (int r = 0; r < 4; ++r) acc[mt][nt][r] = 0.f;

  // Phase A: gate GEMM (A from ga LDS, B = modw2P)
  #pragma unroll
  for (int ks = 0; ks < 4; ++ks) {
    const int kb = ks * 32 + l4 * 8;
    short8 a[4], bfr[4];
    #pragma unroll
    for (int mt = 0; mt < 4; ++mt) {
      const int tl = wm * 64 + mt * 16 + l15;
      a[mt] = *(const short8*)(ga + tl * 256 + ((kb * 2) ^ ((tl & 7) << 4)));
    }
    #pragma unroll
    for (int nt = 0; nt < 4; ++nt) {
      const int o = wn * 64 + nt * 16 + l15;
      bfr[nt] = *(const short8*)(modw2P + (size_t)o * 128 + kb);
    }
    #pragma unroll
    for (int mt = 0; mt < 4; ++mt)
      #pragma unroll
      for (int nt = 0; nt < 4; ++nt)
        acc[mt][nt] = __builtin_amdgcn_mfma_f32_16x16x32_bf16(a[mt], bfr[nt], acc[mt][nt], 0, 0, 0);
  }
  // epilogue A: x_mod -> swizzled LDS
  #pragma unroll
  for (int nt = 0; nt < 4; ++nt) {
    const int o = wn * 64 + nt * 16 + l15;
    const float bb = mod_b2[o];
    #pragma unroll
    for (int mt = 0; mt < 4; ++mt) {
      #pragma unroll
      for (int r = 0; r < 4; ++r) {
        const int tl = wm * 64 + mt * 16 + l4 * 4 + r;
        const int t = t0 + tl;
        const float v = sigmoid_f(acc[mt][nt][r] + bb) * bf2f(xtb[(size_t)t * 128 + o]);
        *(unsigned short*)(xm + tl * 256 + ((o * 2) ^ ((tl & 7) << 4))) = f2bf(v);
      }
    }
  }
  __syncthreads();

  // Phase B: qkv GEMM, 3 output chunks of 128
  for (int c = 0; c < 3; ++c) {
    #pragma unroll
    for (int mt = 0; mt < 4; ++mt)
      #pragma unroll
      for (int nt = 0; nt < 4; ++nt)
        #pragma unroll
        for (int r = 0; r < 4; ++r) acc[mt][nt][r] = 0.f;
    #pragma unroll
    for (int ks = 0; ks < 4; ++ks) {
      const int kb = ks * 32 + l4 * 8;
      short8 a[4], bfr[4];
      #pragma unroll
      for (int mt = 0; mt < 4; ++mt) {
        const int tl = wm * 64 + mt * 16 + l15;
        a[mt] = *(const short8*)(xm + tl * 256 + ((kb * 2) ^ ((tl & 7) << 4)));
      }
      #pragma unroll
      for (int nt = 0; nt < 4; ++nt) {
        const int o = c * 128 + wn * 64 + nt * 16 + l15;
        bfr[nt] = *(const short8*)(qkvP + (size_t)o * 128 + kb);
      }
      #pragma unroll
      for (int mt = 0; mt < 4; ++mt)
        #pragma unroll
        for (int nt = 0; nt < 4; ++nt)
          acc[mt][nt] = __builtin_amdgcn_mfma_f32_16x16x32_bf16(a[mt], bfr[nt], acc[mt][nt], 0, 0, 0);
    }
    #pragma unroll
    for (int nt = 0; nt < 4; ++nt) {
      const int o = c * 128 + wn * 64 + nt * 16 + l15;
      const float bb = qkv_b[o];
      const int hsub = (o & 127) >> 4, ch = o & 15;
      #pragma unroll
      for (int mt = 0; mt < 4; ++mt) {
        #pragma unroll
        for (int r = 0; r < 4; ++r) {
          const int t = t0 + wm * 64 + mt * 16 + l4 * 4 + r;
          qkvt[(size_t)t * 384 + hsub * 48 + c * 16 + ch] = f2bf(acc[mt][nt][r] + bb);
        }
      }
    }
  }
}

// ---------------------------------------------------------------------------
// K6: final projection over A0+A1+A2 (bf16), swapped orientation -> NCDHW
// ---------------------------------------------------------------------------
__global__ __launch_bounds__(256) void proj_mfma_kernel(
    const unsigned short* __restrict__ A0b, const unsigned short* __restrict__ A1b,
    const unsigned short* __restrict__ A2b, const unsigned short* __restrict__ Wp,
    const float* __restrict__ bias, float* __restrict__ out) {
  const int tid = threadIdx.x;
  const int lane = tid & 63, wid = tid >> 6;
  const int wm = wid >> 1, wn = wid & 1;
  const int l15 = lane & 15, l4 = lane >> 4;
  const int t0 = blockIdx.x * 128;

  f32x4 acc[4][4];
  #pragma unroll
  for (int mt = 0; mt < 4; ++mt)
    #pragma unroll
    for (int nt = 0; nt < 4; ++nt)
      #pragma unroll
      for (int r = 0; r < 4; ++r) acc[mt][nt][r] = 0.f;

  #pragma unroll
  for (int ks = 0; ks < 4; ++ks) {
    const int kb = ks * 32 + l4 * 8;
    short8 a[4], bfr[4];
    #pragma unroll
    for (int mt = 0; mt < 4; ++mt) {
      const int o = wm * 64 + mt * 16 + l15;
      a[mt] = *(const short8*)(Wp + (size_t)o * 128 + kb);
    }
    #pragma unroll
    for (int nt = 0; nt < 4; ++nt) {
      const int tok = t0 + wn * 64 + nt * 16 + l15;
      const size_t off = (size_t)tok * 128 + kb;
      short8 s0 = *(const short8*)(A0b + off);
      short8 s1 = *(const short8*)(A1b + off);
      short8 s2 = *(const short8*)(A2b + off);
      short8 r;
      #pragma unroll
      for (int i = 0; i < 8; ++i) {
        float f = bf2f((unsigned short)s0[i]) + bf2f((unsigned short)s1[i]) +
                  bf2f((unsigned short)s2[i]);
        r[i] = (short)f2bf(f);
      }
      bfr[nt] = r;
    }
    #pragma unroll
    for (int mt = 0; mt < 4; ++mt)
      #pragma unroll
      for (int nt = 0; nt < 4; ++nt)
        acc[mt][nt] = __builtin_amdgcn_mfma_f32_16x16x32_bf16(a[mt], bfr[nt], acc[mt][nt], 0, 0, 0);
  }

  #pragma unroll
  for (int nt = 0; nt < 4; ++nt) {
    const int tok = t0 + wn * 64 + nt * 16 + l15;
    const int dhw = tok & 32767, bB = tok >> 15;
    #pragma unroll
    for (int mt = 0; mt < 4; ++mt) {
      #pragma unroll
      for (int r = 0; r < 4; ++r) {
        const int o = wm * 64 + mt * 16 + l4 * 4 + r;
        out[((size_t)(bB * 128 + o) << 15) + dhw] = acc[mt][nt][r] + bias[o];
      }
    }
  }
}

// ---------------------------------------------------------------------------
// K7: axial attention via MFMA, v3 (r12/r13 proven). One 512-thread block per
// (seq, axial); 8 waves = 8 heads; coalesced interleaved-qkv staging.
// ---------------------------------------------------------------------------
__global__ __launch_bounds__(512) void attn_mfma_kernel(
    const unsigned short* __restrict__ qkvt, const float* __restrict__ Rbuf,
    const float* __restrict__ pbw, unsigned short* __restrict__ a0,
    unsigned short* __restrict__ a1, unsigned short* __restrict__ a2) {
  __shared__ unsigned short rows[32 * 392];  // pitch 392 ush = 784B (16B aligned)
  __shared__ unsigned short Vt[8][16 * 40];  // per-head [d][tok]
  __shared__ float Ot[8][32 * 20];           // per-head [tok][d]
  const int axial = blockIdx.y;
  const int seq = blockIdx.x;
  unsigned short* dstbuf = (axial == 0) ? a0 : ((axial == 1) ? a1 : a2);
  const int tid = threadIdx.x;
  const int lane = tid & 63, head = tid >> 6;
  const int tok = lane & 31, hi = lane >> 5;
  const int b = seq >> 10, rem = seq & 1023;
  const int u = rem >> 5, v = rem & 31;
  int base, stride, comp;
  if (axial == 0)      { base = (b << 15) + (u << 5) + v;         stride = 1024; comp = 2; }
  else if (axial == 1) { base = (b << 15) + (u << 10) + v;        stride = 32;   comp = 1; }
  else                 { base = (b << 15) + (u << 10) + (v << 5); stride = 1;    comp = 0; }

  #pragma unroll
  for (int p = 0; p < 3; ++p) {
    const int c = p * 512 + tid;
    const int r = c / 48, cw = c - r * 48;
    const size_t src = ((size_t)base + (size_t)r * stride) * 384 + (size_t)cw * 8;
    *(uint4*)((char*)rows + r * 784 + cw * 16) = *(const uint4*)(qkvt + src);
  }
  __syncthreads();

  const float* Rp = Rbuf + (axial * 8 + head) * 18;
  const float rq00 = fabsf(Rp[0]);
  const unsigned short* myrow = rows + tok * 392 + head * 48;
  short8 aq = *(const short8*)(myrow + hi * 8);
  short8 ak = *(const short8*)(myrow + 16 + hi * 8);
  short8 av = *(const short8*)(myrow + 32 + hi * 8);
  if (hi) {
    aq[7] = (short)f2bf(bf2f((unsigned short)aq[7]) * rq00);
    ak[7] = (short)f2bf(bf2f((unsigned short)ak[7]) * rq00);
  }
  #pragma unroll
  for (int e = 0; e < 8; ++e) Vt[head][(hi * 8 + e) * 40 + tok] = (unsigned short)av[e];

  f32x16 sacc;
  #pragma unroll
  for (int r = 0; r < 16; ++r) sacc[r] = 0.f;
  sacc = __builtin_amdgcn_mfma_f32_32x32x16_bf16(ak, aq, sacc, 0, 0, 0);
  const float wb = pbw[comp];
  float p[16];
  float mmax = -1e30f;
  #pragma unroll
  for (int r = 0; r < 16; ++r) {
    const int kk = (r & 3) + 4 * hi + 8 * (r >> 2);
    const float lin = -1.0f + (2.0f / 31.0f) * (float)kk;
    p[r] = sacc[r] * 0.25f - lin * wb;
    mmax = fmaxf(mmax, p[r]);
  }
  mmax = fmaxf(mmax, __shfl_xor(mmax, 32));
  float sum = 0.f;
  #pragma unroll
  for (int r = 0; r < 16; ++r) { p[r] = expf(p[r] - mmax); sum += p[r]; }
  sum += __shfl_xor(sum, 32);
  const float inv = 1.0f / sum;
  #pragma unroll
  for (int r = 0; r < 16; ++r) p[r] *= inv;
  unsigned pk[8], sw[8];
  #pragma unroll
  for (int j = 0; j < 8; ++j) {
    unsigned r_;
    asm("v_cvt_pk_bf16_f32 %0, %1, %2" : "=v"(r_) : "v"(p[2 * j]), "v"(p[2 * j + 1]));
    pk[j] = r_;
  }
  #pragma unroll
  for (int j = 0; j < 8; ++j) sw[j] = (unsigned)__shfl_xor((int)pk[j], 32);
  uint4 Fu, Gu;
  Fu.x = hi ? sw[2] : pk[0];
  Fu.y = hi ? sw[3] : pk[1];
  Fu.z = hi ? pk[2] : sw[0];
  Fu.w = hi ? pk[3] : sw[1];
  Gu.x = hi ? sw[6] : pk[4];
  Gu.y = hi ? sw[7] : pk[5];
  Gu.z = hi ? pk[6] : sw[4];
  Gu.w = hi ? pk[7] : sw[5];
  short8 Pf = *(short8*)&Fu;
  short8 Pg = *(short8*)&Gu;
  const unsigned short* vrow = Vt[head] + (tok & 15) * 40;
  short8 Bv0 = *(const short8*)(vrow + hi * 8);
  short8 Bv1 = *(const short8*)(vrow + 16 + hi * 8);
  f32x16 oacc;
  #pragma unroll
  for (int r = 0; r < 16; ++r) oacc[r] = 0.f;
  oacc = __builtin_amdgcn_mfma_f32_32x32x16_bf16(Pf, Bv0, oacc, 0, 0, 0);
  oacc = __builtin_amdgcn_mfma_f32_32x32x16_bf16(Pg, Bv1, oacc, 0, 0, 0);
  if (tok < 16) {
    #pragma unroll
    for (int r = 0; r < 16; ++r) {
      const int q = (r & 3) + 4 * hi + 8 * (r >> 2);
      Ot[head][q * 20 + tok] = oacc[r];
    }
  }
  if (lane < 32) {
    float o16[16], y16[16], Rv[9];
    #pragma unroll
    for (int j = 0; j < 16; ++j) o16[j] = Ot[head][lane * 20 + j];
    #pragma unroll
    for (int i = 0; i < 9; ++i) Rv[i] = Rp[9 + i];
    rot16(Rv, o16, y16);
    unsigned outw[8];
    #pragma unroll
    for (int j = 0; j < 8; ++j)
      outw[j] = ((unsigned)f2bf(y16[2 * j + 1]) << 16) | (unsigned)f2bf(y16[2 * j]);
    const size_t t2 = (size_t)base + (size_t)lane * stride;
    unsigned short* dst = dstbuf + t2 * 128 + head * 16;
    uint4 o0 = {outw[0], outw[1], outw[2], outw[3]};
    uint4 o1 = {outw[4], outw[5], outw[6], outw[7]};
    *(uint4*)dst = o0;
    *(uint4*)(dst + 8) = o1;
  }
}

// ---------------------------------------------------------------------------
extern "C" void kernel_launch(void* const* d_in, const int* in_sizes, int n_in,
                              void* d_out, int out_size, void* d_ws, size_t ws_size,
                              hipStream_t stream) {
  const float* x       = (const float*)d_in[0];
  const float* pos_emb = (const float*)d_in[1];
  const float* qkv_w   = (const float*)d_in[2];
  const float* qkv_b   = (const float*)d_in[3];
  const float* lp_w1   = (const float*)d_in[4];
  const float* lp_b1   = (const float*)d_in[5];
  const float* lp_w2   = (const float*)d_in[6];
  const float* lp_b2   = (const float*)d_in[7];
  const float* mod_w1  = (const float*)d_in[8];
  const float* mod_b1  = (const float*)d_in[9];
  const float* mod_w2  = (const float*)d_in[10];
  const float* mod_b2  = (const float*)d_in[11];
  // d_in[12] pa_w, d_in[13] pa_b: cancel in softmax (constant along key axis)
  const float* proj_w  = (const float*)d_in[14];
  const float* proj_b  = (const float*)d_in[15];
  const float* pbw     = (const float*)d_in[16];
  // d_in[17] pos_bias_b: cancels in softmax
  const float* Ad      = (const float*)d_in[18];
  const float* Ah      = (const float*)d_in[19];
  const float* Aw      = (const float*)d_in[20];
  const float* Rd      = (const float*)d_in[21];
  const float* Rh      = (const float*)d_in[22];
  const float* Rw      = (const float*)d_in[23];
  // d_in[24..26] t_d/t_h/t_w: cancel in rel (pairwise difference)

  float* ws = (float*)d_ws;
  unsigned short* lfb    = (unsigned short*)(ws + WS_R0);   // lf bf16
  unsigned short* A0b    = (unsigned short*)(ws + WS_A0);
  unsigned short* A1b    = (unsigned short*)(ws + WS_A1);
  unsigned short* A2b    = (unsigned short*)(ws + WS_A2);
  unsigned short* mpreb  = (unsigned short*)(ws + WS_MPREB);
  unsigned short* xtokb  = (unsigned short*)(ws + WS_XTOKB);
  unsigned short* inT    = (unsigned short*)(ws + WS_INT);
  unsigned short* qkvt   = (unsigned short*)(ws + WS_QKVH);
  unsigned short* convP  = (unsigned short*)(ws + WS_CONVP);
  unsigned short* qkvP   = (unsigned short*)(ws + WS_QKVP);
  unsigned short* WcP    = (unsigned short*)(ws + WS_WCP);
  unsigned short* modw2P = (unsigned short*)(ws + WS_MODW2P);
  unsigned short* projP  = (unsigned short*)(ws + WS_PROJP);
  float* bc     = ws + WS_BC;
  float* Rbuf   = ws + WS_RBUF;
  float* ps     = ws + WS_PS;
  float* pss    = ws + WS_PSS;
  float* mu1    = ws + WS_MU1;
  float* rs1    = ws + WS_RS1;
  float* mu2    = ws + WS_MU2;
  float* rs2    = ws + WS_RS2;

  // merged prep + transposes
  prep_transpose_kernel<<<2304, 256, 0, stream>>>(
      lp_w1, qkv_w, mod_w1, lp_w2, lp_b2, mod_b1, mod_w2, proj_w,
      Ad, Ah, Aw, Rd, Rh, Rw, x, pos_emb,
      convP, qkvP, WcP, modw2P, projP, bc, Rbuf, xtokb, inT);
  // lf (bf16) = circular conv3x3x3(pos_emb), fused fp32 stats partials
  conv_mfma_kernel<<<1024, 256, 0, stream>>>(inT, convP, lp_b1, lfb, ps, pss);
  stats_final_kernel<<<256, 64, 0, stream>>>(ps, pss, mu1, rs1, 512);
  // m_pre (bf16) = gelu(inorm(lf)) @ Wc^T + bc, fused stats partials
  gemm_mfma_kernel<1, 1, 2, 1><<<dim3(1, 512), 256, 0, stream>>>(
      lfb, WcP, bc, mpreb, 128, mu1, rs1, nullptr, ps, pss);
  stats_final_kernel<<<256, 64, 0, stream>>>(ps, pss, mu2, rs2, 256);
  // fused: ga = gelu(inorm(mpre)) (LDS, once); x_mod (LDS); qkv (bf16)
  gateqkv_mfma_kernel<<<512, 256, 0, stream>>>(
      mpreb, modw2P, mod_b2, xtokb, qkvP, qkv_b, qkvt, mu2, rs2);
  // attention: one 512-thread block per (seq, axial), 8 heads in-block
  attn_mfma_kernel<<<dim3(2048, 3), 512, 0, stream>>>(qkvt, Rbuf, pbw, A0b, A1b, A2b);
  proj_mfma_kernel<<<512, 256, 0, stream>>>(A0b, A1b, A2b, projP, proj_b, (float*)d_out);
}

// Round 15
// 218.475 us; speedup vs baseline: 1.4042x; 1.0436x over previous
//
#include <hip/hip_runtime.h>
#include <cstdint>
#include <cstddef>

// ---------------------------------------------------------------------------
// Problem constants: B=2, C=128, D=H=W=32, nh=8, hd=16, L=32
// Tokens: t = b*32768 + d*1024 + h*32 + w   (65536 tokens, 128 channels)
// ---------------------------------------------------------------------------

#define NTOK 65536
#define SPAT 32768

// ws offsets (floats). Same proven map as r7-r14 (136.4 MB).
#define WS_R0     0ull          // region: lf bf16 (8388608 ush) -> A0/A1
#define WS_A0     0ull          // 4194304 (8388608 ush)
#define WS_A1     4194304ull    // 4194304
#define WS_MPREB  8388608ull    // 4194304 (8388608 ush)
#define WS_A2     8388608ull    // 4194304 (overlays dead MPREB)
#define WS_XTOKB  12582912ull   // 4194304 (8388608 ush)
#define WS_INT    16777216ull   // 4194304 (8388608 ush): pos_emb bf16
#define WS_QKVH   20971520ull   // 12582912 (25165824 ush) [t][h*48+sec*16+ch]
#define WS_CONVP  33554432ull   // 221184 (442368 ush) [tap][dx][ks][l4][co][8]
#define WS_QKVP   33775616ull   // 24576  (49152 ush)
#define WS_WCP    33800192ull   // 8192
#define WS_MODW2P 33808384ull   // 8192
#define WS_PROJP  33816576ull   // 8192
#define WS_BC     33824768ull   // 128
#define WS_RBUF   33824896ull   // 432
#define WS_PS     33825328ull   // 131072 (1024 blocks x 128)
#define WS_PSS    33956400ull   // 131072
#define WS_MU1    34087472ull   // 256
#define WS_RS1    34087728ull   // 256
#define WS_MU2    34087984ull   // 256
#define WS_RS2    34088240ull   // 256
// total 34088496 floats = 136.4 MB

typedef __attribute__((ext_vector_type(8))) short short8;
typedef __attribute__((ext_vector_type(4))) float f32x4;
typedef __attribute__((ext_vector_type(16))) float f32x16;

// tanh-form gelu: branch-free, ~13 VALU ops (r14-proven; err << bf16 rounding)
__device__ __forceinline__ float gelu_f(float x) {
  float u = 0.79788456080286536f * (x + 0.044715f * x * x * x);
  u = fminf(u, 40.0f);                     // overflow guard (tanh->1)
  float e = __expf(2.0f * u);
  float t = (e - 1.0f) / (e + 1.0f);
  return 0.5f * x * (1.0f + t);
}
__device__ __forceinline__ float sigmoid_f(float x) {
  return 1.0f / (1.0f + __expf(-x));
}
__device__ __forceinline__ unsigned short f2bf(float x) {  // RNE f32->bf16
  unsigned int u = __float_as_uint(x);
  unsigned int r = u + 0x7fffu + ((u >> 16) & 1u);
  return (unsigned short)(r >> 16);
}
__device__ __forceinline__ float bf2f(unsigned short u) {
  return __uint_as_float(((unsigned int)u) << 16);
}
// 8 consecutive bf16 -> 8 fp32
__device__ __forceinline__ void bf16x8_load(const unsigned short* p, float* f) {
  const uint4 a = *(const uint4*)p;
  const unsigned int w[4] = {a.x, a.y, a.z, a.w};
  #pragma unroll
  for (int i = 0; i < 4; ++i) {
    f[2 * i] = __uint_as_float(w[i] << 16);
    f[2 * i + 1] = __uint_as_float(w[i] & 0xffff0000u);
  }
}
// async global->LDS, 16B per lane (dest must be wave-uniform base + lane*16)
__device__ __forceinline__ void gload_lds16(const void* g, void* l) {
  __builtin_amdgcn_global_load_lds(
      (const __attribute__((address_space(1))) unsigned int*)g,
      (__attribute__((address_space(3))) unsigned int*)l, 16, 0, 0);
}
__device__ __forceinline__ float dot3(const float* a, const float* b) {
  return a[0] * b[0] + a[1] * b[1] + a[2] * b[2];
}
__device__ __forceinline__ void cross3(const float* a, const float* b, float* c) {
  c[0] = a[1] * b[2] - a[2] * b[1];
  c[1] = a[2] * b[0] - a[0] * b[2];
  c[2] = a[0] * b[1] - a[1] * b[0];
}

// exact port of _r6_to_matrix for one head (6 floats in, 9 out row-major)
__device__ void r6_to_matrix(const float* r6, float* R) {
  float v1[3] = {r6[0], r6[1], r6[2]};
  float n1 = sqrtf(dot3(v1, v1));
  float inv1 = 1.0f / (n1 + 1e-7f);
  v1[0] *= inv1; v1[1] *= inv1; v1[2] *= inv1;
  float v2[3] = {r6[3], r6[4], r6[5]};
  float d = dot3(v2, v1);
  v2[0] -= d * v1[0]; v2[1] -= d * v1[1]; v2[2] -= d * v1[2];
  float n2 = sqrtf(dot3(v2, v2));
  float inv2 = 1.0f / (n2 + 1e-7f);
  v2[0] *= inv2; v2[1] *= inv2; v2[2] *= inv2;
  float v3[3]; cross3(v1, v2, v3);
  float cx[3]; cross3(v2, v3, cx);
  float det = dot3(v1, cx);
  if (det < 0.0f) { v3[0] = -v3[0]; v3[1] = -v3[1]; v3[2] = -v3[2]; }
  R[0] = v1[0]; R[1] = v1[1]; R[2] = v1[2];
  R[3] = v2[0]; R[4] = v2[1]; R[5] = v2[2];
  R[6] = v3[0]; R[7] = v3[1]; R[8] = v3[2];
}

// exact port of _ensure_matrix for one head (9 in row-major, 9 out)
__device__ void ensure_matrix(const float* Rin, float* Ro) {
  float a[3] = {Rin[0] + 1e-6f, Rin[1] + 1e-6f, Rin[2] + 1e-6f};
  float na = fmaxf(sqrtf(dot3(a, a)), 1e-12f);
  float v1[3] = {a[0] / na, a[1] / na, a[2] / na};
  float b0[3] = {Rin[3], Rin[4], Rin[5]};
  float d = dot3(b0, v1);
  float bb[3] = {b0[0] - d * v1[0] + 1e-6f, b0[1] - d * v1[1] + 1e-6f, b0[2] - d * v1[2] + 1e-6f};
  float nb = fmaxf(sqrtf(dot3(bb, bb)), 1e-12f);
  float v2[3] = {bb[0] / nb, bb[1] / nb, bb[2] / nb};
  float v3[3]; cross3(v1, v2, v3);
  float cx[3]; cross3(v2, v3, cx);
  float det = dot3(v1, cx);
  if (det < 0.0f) { v3[0] = -v3[0]; v3[1] = -v3[1]; v3[2] = -v3[2]; }
  float Rn[9] = {v1[0], v1[1], v1[2], v2[0], v2[1], v2[2], v3[0], v3[1], v3[2]};
  float T1[9], T2[9];
  for (int i = 0; i < 3; ++i)
    for (int j = 0; j < 3; ++j) {
      float s = 0.f;
      for (int k = 0; k < 3; ++k) s += Rn[k * 3 + i] * Rn[k * 3 + j];
      T1[i * 3 + j] = s;
    }
  for (int i = 0; i < 3; ++i)
    for (int j = 0; j < 3; ++j) {
      float s = 0.f;
      for (int k = 0; k < 3; ++k) s += T1[i * 3 + k] * Rn[j * 3 + k];
      T2[i * 3 + j] = s;
    }
  for (int i = 0; i < 9; ++i) Ro[i] = 0.5f * (Rn[i] + T2[i]);
}

// y = R_eff x for hd=16 (5 full 3x3 groups + scalar R00 on ch15)
__device__ __forceinline__ void rot16(const float* R, const float* x, float* y) {
  #pragma unroll
  for (int g = 0; g < 5; ++g) {
    float a = x[3 * g], b = x[3 * g + 1], c = x[3 * g + 2];
    y[3 * g + 0] = R[0] * a + R[1] * b + R[2] * c;
    y[3 * g + 1] = R[3] * a + R[4] * b + R[5] * c;
    y[3 * g + 2] = R[6] * a + R[7] * b + R[8] * c;
  }
  y[15] = R[0] * x[15];
}

// ---------------------------------------------------------------------------
// K0: merged prep (blocks 0..255) + transposes (blocks 256..2303)
// ---------------------------------------------------------------------------
__global__ __launch_bounds__(256) void prep_transpose_kernel(
    const float* __restrict__ lp_w1, const float* __restrict__ qkv_w,
    const float* __restrict__ mod_w1, const float* __restrict__ lp_w2,
    const float* __restrict__ lp_b2, const float* __restrict__ mod_b1,
    const float* __restrict__ mod_w2, const float* __restrict__ proj_w,
    const float* __restrict__ Ad, const float* __restrict__ Ah,
    const float* __restrict__ Aw, const float* __restrict__ Rd,
    const float* __restrict__ Rh, const float* __restrict__ Rw,
    const float* __restrict__ x, const float* __restrict__ pe,
    unsigned short* __restrict__ convP, unsigned short* __restrict__ qkvP,
    unsigned short* __restrict__ WcP, unsigned short* __restrict__ modw2P,
    unsigned short* __restrict__ projP, float* __restrict__ bc,
    float* __restrict__ Rbuf, unsigned short* __restrict__ xtokb,
    unsigned short* __restrict__ inT) {
  __shared__ float lds[32][132];
  if (blockIdx.x < 256) {
    int gid = blockIdx.x * 256 + threadIdx.x;  // 65536 threads
    for (int f = gid; f < 442368; f += 65536) {
      int e = f & 7;
      int co = (f >> 3) & 127;
      int rest = f >> 10;
      int l4 = rest & 3;
      int ks = (rest >> 2) & 3;
      int dxt = rest >> 4;
      int dx = dxt % 3;
      int tap = dxt / 3;
      int dz = tap / 3, dy = tap % 3;
      int ci = ks * 32 + l4 * 8 + e;
      convP[f] = f2bf(lp_w1[(co * 128 + ci) * 27 + dz * 9 + dy * 3 + dx]);
    }
    if (gid < 49152) qkvP[gid] = f2bf(qkv_w[gid]);
    if (gid < 16384) {
      modw2P[gid] = f2bf(mod_w2[gid]);
      projP[gid] = f2bf(proj_w[gid]);
      int o = gid >> 7, i = gid & 127;
      float s = 0.f;
      for (int c = 0; c < 128; ++c) s += mod_w1[o * 128 + c] * lp_w2[c * 128 + i];
      WcP[gid] = f2bf(s);
    }
    if (gid < 128) {
      float s = 0.f;
      for (int c = 0; c < 128; ++c) s += mod_w1[gid * 128 + c] * lp_b2[c];
      bc[gid] = s + mod_b1[gid];
    }
    if (blockIdx.x == 0 && threadIdx.x >= 224 && threadIdx.x < 248) {
      int tid = threadIdx.x - 224;
      int ax = tid >> 3, h = tid & 7;
      const float* A = (ax == 0) ? Ad : ((ax == 1) ? Ah : Aw);
      const float* R = (ax == 0) ? Rd : ((ax == 1) ? Rh : Rw);
      float Rq[9], Rv[9];
      r6_to_matrix(A + h * 6, Rq);
      ensure_matrix(R + h * 9, Rv);
      float* dst = Rbuf + (ax * 8 + h) * 18;
      for (int i = 0; i < 9; ++i) { dst[i] = Rq[i]; dst[9 + i] = Rv[i]; }
    }
    return;
  }
  // transpose path
  int blk = blockIdx.x - 256;  // b*1024 + d*32 + h
  int b = blk >> 10;
  int dh = blk & 1023;
  int tid = threadIdx.x;
  size_t planebase = ((size_t)b << 22) + ((size_t)dh << 5);
  size_t tb = ((size_t)blk) << 5;
  #pragma unroll
  for (int r = 0; r < 16; ++r) {
    int idx = r * 256 + tid;
    int ci = idx >> 5, w = idx & 31;
    lds[w][ci] = x[planebase + ((size_t)ci << 15) + w];
  }
  __syncthreads();
  #pragma unroll
  for (int r = 0; r < 16; ++r) {
    int idx = r * 256 + tid;
    int w = idx >> 7, ci = idx & 127;
    xtokb[(tb + w) * 128 + ci] = f2bf(lds[w][ci]);
  }
  __syncthreads();
  #pragma unroll
  for (int r = 0; r < 16; ++r) {
    int idx = r * 256 + tid;
    int ci = idx >> 5, w = idx & 31;
    lds[w][ci] = pe[planebase + ((size_t)ci << 15) + w];
  }
  __syncthreads();
  #pragma unroll
  for (int r = 0; r < 16; ++r) {
    int idx = r * 256 + tid;
    int w = idx >> 7, ci = idx & 127;
    inT[(tb + w) * 128 + ci] = f2bf(lds[w][ci]);
  }
}

// ---------------------------------------------------------------------------
// K1: 3x3x3 circular conv via bf16 MFMA, v7 + XCD swizzle (r13/r14 proven).
// ---------------------------------------------------------------------------
__global__ __launch_bounds__(256, 4) void conv_mfma_kernel(
    const unsigned short* __restrict__ inT, const unsigned short* __restrict__ Bp,
    const float* __restrict__ b1, unsigned short* __restrict__ out,
    float* __restrict__ ps, float* __restrict__ pss) {
  __shared__ unsigned short Als[16384];  // 32KB: 4 rows x 32 w x 128 ci, swizzled
  __shared__ float sumb[128];
  __shared__ float sqb[128];
  const int orig = blockIdx.x;
  const int blk = ((orig & 7) << 7) + (orig >> 3);  // XCD-chunked bijective swizzle
  const int b = blk >> 9, d = (blk >> 4) & 31, hg = blk & 15;
  const int h0 = hg << 1;                 // 2 output h-rows
  const int tid = threadIdx.x;
  const int lane = tid & 63;
  const int wid = tid >> 6;               // N-split: wave owns co [wid*32, wid*32+32)
  const int l15 = lane & 15, l4 = lane >> 4;

  f32x4 acc[4][2];
  #pragma unroll
  for (int mt = 0; mt < 4; ++mt)
    #pragma unroll
    for (int nt = 0; nt < 2; ++nt)
      #pragma unroll
      for (int r = 0; r < 4; ++r) acc[mt][nt][r] = 0.f;

  int mw[4], mhh[4];
  #pragma unroll
  for (int mt = 0; mt < 4; ++mt) {
    int m = mt * 16 + l15;                // tokens 0..63
    mhh[mt] = m >> 5;
    mw[mt] = m & 31;
  }
  const size_t tokbase = ((size_t)b << 15) + ((size_t)d << 10) + ((size_t)h0 << 5);

  auto stage = [&](int dz) {
    const int zr = (d + dz + 31) & 31;
    #pragma unroll
    for (int p = 0; p < 8; ++p) {
      const int g = p * 256 + tid;        // 2048 chunks of 16B
      const int tok = g >> 4, gi = g & 15;
      const int r = tok >> 5, w = tok & 31;
      const int yr = (h0 + r + 31) & 31;
      const size_t srcbyte = ((((size_t)b << 15) + ((size_t)zr << 10) + ((size_t)yr << 5) + w) << 8)
                             + (size_t)((gi ^ (w & 7)) << 4);
      gload_lds16((const char*)inT + srcbyte, (char*)Als + (size_t)g * 16);
    }
  };

  auto compute = [&](int dz) {
    #pragma unroll
    for (int dy = 0; dy < 3; ++dy) {
      const int tap = dz * 3 + dy;
      #pragma unroll
      for (int dx = 0; dx < 3; ++dx) {
        int abase[4], asw[4];
        #pragma unroll
        for (int mt = 0; mt < 4; ++mt) {
          const int wsft = (mw[mt] + dx + 31) & 31;
          const int stok = (mhh[mt] + dy) * 32 + wsft;
          abase[mt] = stok * 256;
          asw[mt] = (wsft & 7) << 4;
        }
        #pragma unroll
        for (int ks = 0; ks < 4; ++ks) {
          const int k2 = (ks * 32 + l4 * 8) * 2;
          const int bbase = (((tap * 3 + dx) * 4 + ks) * 4 + l4) * 1024;
          short8 afr[4], bfr[2];
          #pragma unroll
          for (int nt = 0; nt < 2; ++nt) {
            const int co = wid * 32 + nt * 16 + l15;
            bfr[nt] = *(const short8*)(Bp + bbase + co * 8);
          }
          #pragma unroll
          for (int mt = 0; mt < 4; ++mt)
            afr[mt] = *(const short8*)((const char*)Als + abase[mt] + (k2 ^ asw[mt]));
          __builtin_amdgcn_s_setprio(1);
          #pragma unroll
          for (int mt = 0; mt < 4; ++mt)
            #pragma unroll
            for (int nt = 0; nt < 2; ++nt)
              acc[mt][nt] = __builtin_amdgcn_mfma_f32_16x16x32_bf16(afr[mt], bfr[nt],
                                                                    acc[mt][nt], 0, 0, 0);
          __builtin_amdgcn_s_setprio(0);
        }
      }
    }
  };

  for (int dz = 0; dz < 3; ++dz) {
    stage(dz);
    __syncthreads();
    compute(dz);
    if (dz < 2) __syncthreads();
  }

  #pragma unroll
  for (int nt = 0; nt < 2; ++nt) {
    const int co = wid * 32 + nt * 16 + l15;
    const float bias = b1[co];
    float s = 0.f, q = 0.f;
    #pragma unroll
    for (int mt = 0; mt < 4; ++mt) {
      #pragma unroll
      for (int r = 0; r < 4; ++r) {
        const int m = mt * 16 + l4 * 4 + r;
        const float v = acc[mt][nt][r] + bias;
        out[(tokbase + m) * 128 + co] = f2bf(v);
        s += v; q += v * v;
      }
    }
    s += __shfl_xor(s, 16); s += __shfl_xor(s, 32);
    q += __shfl_xor(q, 16); q += __shfl_xor(q, 32);
    if (l4 == 0) { sumb[co] = s; sqb[co] = q; }
  }
  __syncthreads();
  if (tid < 128) {
    ps[blk * 128 + tid] = sumb[tid];
    pss[blk * 128 + tid] = sqb[tid];
  }
}

// ---------------------------------------------------------------------------
// K2: stats finalize, parallel
// ---------------------------------------------------------------------------
__global__ __launch_bounds__(64) void stats_final_kernel(
    const float* __restrict__ ps, const float* __restrict__ pss,
    float* __restrict__ mu, float* __restrict__ rs, int nb) {
  const int pair = blockIdx.x;  // b*128 + c
  const int b = pair >> 7, c = pair & 127;
  const int lane = threadIdx.x;
  float s = 0.f, ss = 0.f;
  for (int j = lane; j < nb; j += 64) {
    const int idx = ((b * nb + j) << 7) + c;
    s += ps[idx];
    ss += pss[idx];
  }
  #pragma unroll
  for (int o = 32; o > 0; o >>= 1) {
    s += __shfl_xor(s, o);
    ss += __shfl_xor(ss, o);
  }
  if (lane == 0) {
    float m = s * (1.0f / 32768.0f);
    float v = ss * (1.0f / 32768.0f) - m * m;
    mu[pair] = m;
    rs[pair] = rsqrtf(v + 1e-5f);
  }
}

// ---------------------------------------------------------------------------
// K3: Wc GEMM with LDS-dedup gelu (gateqkv Phase-0 pattern) + fused stats.
// mpre = gelu(inorm(lf)) @ Wc^T + bc ; ga computed ONCE per element.
// Block = 128 tokens; 4 waves 2x2; grid 512.
// ---------------------------------------------------------------------------
__global__ __launch_bounds__(256) void wc_mfma_kernel(
    const unsigned short* __restrict__ lfb, const unsigned short* __restrict__ WcP,
    const float* __restrict__ bc, unsigned short* __restrict__ mpreb,
    const float* __restrict__ mu, const float* __restrict__ rs,
    float* __restrict__ ps, float* __restrict__ pss) {
  __shared__ char ga[32768];  // gelu(inorm(lf)) bf16, swizzled
  __shared__ float sumb[128][2];
  __shared__ float sqb[128][2];
  const int tid = threadIdx.x;
  const int lane = tid & 63, wid = tid >> 6;
  const int wm = wid >> 1, wn = wid & 1;
  const int l15 = lane & 15, l4 = lane >> 4;
  const int t0 = blockIdx.x * 128;
  const int bidx = t0 >> 15;

  // Phase 0: cooperative gelu(inorm) stage -- 2048 chunks of 8 bf16
  #pragma unroll
  for (int r = 0; r < 8; ++r) {
    const int c = r * 256 + tid;
    const int tl = c >> 4;
    const int kc = (c & 15) * 8;
    float v[8];
    bf16x8_load(lfb + (size_t)(t0 + tl) * 128 + kc, v);
    const float4 m0 = *(const float4*)(mu + bidx * 128 + kc);
    const float4 m1 = *(const float4*)(mu + bidx * 128 + kc + 4);
    const float4 r0 = *(const float4*)(rs + bidx * 128 + kc);
    const float4 r1 = *(const float4*)(rs + bidx * 128 + kc + 4);
    const float mm[8] = {m0.x, m0.y, m0.z, m0.w, m1.x, m1.y, m1.z, m1.w};
    const float rr[8] = {r0.x, r0.y, r0.z, r0.w, r1.x, r1.y, r1.z, r1.w};
    short8 t;
    #pragma unroll
    for (int j = 0; j < 8; ++j) t[j] = (short)f2bf(gelu_f((v[j] - mm[j]) * rr[j]));
    *(short8*)(ga + tl * 256 + ((kc * 2) ^ ((tl & 7) << 4))) = t;
  }
  __syncthreads();

  f32x4 acc[4][4];
  #pragma unroll
  for (int mt = 0; mt < 4; ++mt)
    #pragma unroll
    for (int nt = 0; nt < 4; ++nt)
      #pragma unroll
      for (int r = 0; r < 4; ++r) acc[mt][nt][r] = 0.f;

  #pragma unroll
  for (int ks = 0; ks < 4; ++ks) {
    const int kb = ks * 32 + l4 * 8;
    short8 a[4], bfr[4];
    #pragma unroll
    for (int mt = 0; mt < 4; ++mt) {
      const int tl = wm * 64 + mt * 16 + l15;
      a[mt] = *(const short8*)(ga + tl * 256 + ((kb * 2) ^ ((tl & 7) << 4)));
    }
    #pragma unroll
    for (int nt = 0; nt < 4; ++nt) {
      const int o = wn * 64 + nt * 16 + l15;
      bfr[nt] = *(const short8*)(WcP + (size_t)o * 128 + kb);
    }
    #pragma unroll
    for (int mt = 0; mt < 4; ++mt)
      #pragma unroll
      for (int nt = 0; nt < 4; ++nt)
        acc[mt][nt] = __builtin_amdgcn_mfma_f32_16x16x32_bf16(a[mt], bfr[nt], acc[mt][nt], 0, 0, 0);
  }

  // epilogue: bias + bf16 store + fused fp32 stats
  #pragma unroll
  for (int nt = 0; nt < 4; ++nt) {
    const int o = wn * 64 + nt * 16 + l15;
    const float bb = bc[o];
    float s = 0.f, q = 0.f;
    #pragma unroll
    for (int mt = 0; mt < 4; ++mt) {
      #pragma unroll
      for (int r = 0; r < 4; ++r) {
        const int t = t0 + wm * 64 + mt * 16 + l4 * 4 + r;
        const float v = acc[mt][nt][r] + bb;
        mpreb[(size_t)t * 128 + o] = f2bf(v);
        s += v; q += v * v;
      }
    }
    s += __shfl_xor(s, 16); s += __shfl_xor(s, 32);
    q += __shfl_xor(q, 16); q += __shfl_xor(q, 32);
    if (l4 == 0) { sumb[o][wm] = s; sqb[o][wm] = q; }
  }
  __syncthreads();
  if (tid < 128) {
    ps[blockIdx.x * 128 + tid] = sumb[tid][0] + sumb[tid][1];
    pss[blockIdx.x * 128 + tid] = sqb[tid][0] + sqb[tid][1];
  }
}

// ---------------------------------------------------------------------------
// K4: fused gate + qkv GEMM, v2 (r14 proven).
// ---------------------------------------------------------------------------
__global__ __launch_bounds__(256) void gateqkv_mfma_kernel(
    const unsigned short* __restrict__ mpreb, const unsigned short* __restrict__ modw2P,
    const float* __restrict__ mod_b2, const unsigned short* __restrict__ xtb,
    const unsigned short* __restrict__ qkvP, const float* __restrict__ qkv_b,
    unsigned short* __restrict__ qkvt, const float* __restrict__ mu,
    const float* __restrict__ rs) {
  __shared__ char ga[32768];  // gelu(inorm(mpre)) bf16, swizzled
  __shared__ char xm[32768];  // x_mod bf16, swizzled
  const int tid = threadIdx.x;
  const int lane = tid & 63, wid = tid >> 6;
  const int wm = wid >> 1, wn = wid & 1;
  const int l15 = lane & 15, l4 = lane >> 4;
  const int t0 = blockIdx.x * 128;
  const int bidx = t0 >> 15;

  // Phase 0: cooperative gelu(inorm) stage -- 2048 chunks of 8 bf16
  #pragma unroll
  for (int r = 0; r < 8; ++r) {
    const int c = r * 256 + tid;
    const int tl = c >> 4;            // token local 0..127
    const int kc = (c & 15) * 8;      // k offset
    float v[8];
    bf16x8_load(mpreb + (size_t)(t0 + tl) * 128 + kc, v);
    const float4 m0 = *(const float4*)(mu + bidx * 128 + kc);
    const float4 m1 = *(const float4*)(mu + bidx * 128 + kc + 4);
    const float4 r0 = *(const float4*)(rs + bidx * 128 + kc);
    const float4 r1 = *(const float4*)(rs + bidx * 128 + kc + 4);
    const float mm[8] = {m0.x, m0.y, m0.z, m0.w, m1.x, m1.y, m1.z, m1.w};
    const float rr[8] = {r0.x, r0.y, r0.z, r0.w, r1.x, r1.y, r1.z, r1.w};
    short8 t;
    #pragma unroll
    for (int j = 0; j < 8; ++j) t[j] = (short)f2bf(gelu_f((v[j] - mm[j]) * rr[j]));
    *(short8*)(ga + tl * 256 + ((kc * 2) ^ ((tl & 7) << 4))) = t;
  }
  __syncthreads();

  f32x4 acc[4][4];
  #pragma unroll
  for (int mt = 0; mt < 4; ++mt)
    #pragma unroll
    for (int nt = 0; nt < 4; ++nt)
      #pragma unroll
      for (int r = 0; r < 4; ++r) acc[mt][nt][r] = 0.f;

  // Phase A: gate GEMM (A from ga LDS, B = modw2P)
  #pragma unroll
  for (int ks = 0; ks < 4; ++ks) {
    const int kb = ks * 32 + l4 * 8;
    short8 a[4], bfr[4];
    #pragma unroll
    for (int mt = 0; mt < 4; ++mt) {
      const int tl = wm * 64 + mt * 16 + l15;
      a[mt] = *(const short8*)(ga + tl * 256 + ((kb * 2) ^ ((tl & 7) << 4)));
    }
    #pragma unroll
    for (int nt = 0; nt < 4; ++nt) {
      const int o = wn * 64 + nt * 16 + l15;
      bfr[nt] = *(const short8*)(modw2P + (size_t)o * 128 + kb);
    }
    #pragma unroll
    for (int mt = 0; mt < 4; ++mt)
      #pragma unroll
      for (int nt = 0; nt < 4; ++nt)
        acc[mt][nt] = __builtin_amdgcn_mfma_f32_16x16x32_bf16(a[mt], bfr[nt], acc[mt][nt], 0, 0, 0);
  }
  // epilogue A: x_mod -> swizzled LDS
  #pragma unroll
  for (int nt = 0; nt < 4; ++nt) {
    const int o = wn * 64 + nt * 16 + l15;
    const float bb = mod_b2[o];
    #pragma unroll
    for (int mt = 0; mt < 4; ++mt) {
      #pragma unroll
      for (int r = 0; r < 4; ++r) {
        const int tl = wm * 64 + mt * 16 + l4 * 4 + r;
        const int t = t0 + tl;
        const float v = sigmoid_f(acc[mt][nt][r] + bb) * bf2f(xtb[(size_t)t * 128 + o]);
        *(unsigned short*)(xm + tl * 256 + ((o * 2) ^ ((tl & 7) << 4))) = f2bf(v);
      }
    }
  }
  __syncthreads();

  // Phase B: qkv GEMM, 3 output chunks of 128
  for (int c = 0; c < 3; ++c) {
    #pragma unroll
    for (int mt = 0; mt < 4; ++mt)
      #pragma unroll
      for (int nt = 0; nt < 4; ++nt)
        #pragma unroll
        for (int r = 0; r < 4; ++r) acc[mt][nt][r] = 0.f;
    #pragma unroll
    for (int ks = 0; ks < 4; ++ks) {
      const int kb = ks * 32 + l4 * 8;
      short8 a[4], bfr[4];
      #pragma unroll
      for (int mt = 0; mt < 4; ++mt) {
        const int tl = wm * 64 + mt * 16 + l15;
        a[mt] = *(const short8*)(xm + tl * 256 + ((kb * 2) ^ ((tl & 7) << 4)));
      }
      #pragma unroll
      for (int nt = 0; nt < 4; ++nt) {
        const int o = c * 128 + wn * 64 + nt * 16 + l15;
        bfr[nt] = *(const short8*)(qkvP + (size_t)o * 128 + kb);
      }
      #pragma unroll
      for (int mt = 0; mt < 4; ++mt)
        #pragma unroll
        for (int nt = 0; nt < 4; ++nt)
          acc[mt][nt] = __builtin_amdgcn_mfma_f32_16x16x32_bf16(a[mt], bfr[nt], acc[mt][nt], 0, 0, 0);
    }
    #pragma unroll
    for (int nt = 0; nt < 4; ++nt) {
      const int o = c * 128 + wn * 64 + nt * 16 + l15;
      const float bb = qkv_b[o];
      const int hsub = (o & 127) >> 4, ch = o & 15;
      #pragma unroll
      for (int mt = 0; mt < 4; ++mt) {
        #pragma unroll
        for (int r = 0; r < 4; ++r) {
          const int t = t0 + wm * 64 + mt * 16 + l4 * 4 + r;
          qkvt[(size_t)t * 384 + hsub * 48 + c * 16 + ch] = f2bf(acc[mt][nt][r] + bb);
        }
      }
    }
  }
}

// ---------------------------------------------------------------------------
// K6: final projection over A0+A1+A2 (bf16), swapped orientation -> NCDHW
// ---------------------------------------------------------------------------
__global__ __launch_bounds__(256) void proj_mfma_kernel(
    const unsigned short* __restrict__ A0b, const unsigned short* __restrict__ A1b,
    const unsigned short* __restrict__ A2b, const unsigned short* __restrict__ Wp,
    const float* __restrict__ bias, float* __restrict__ out) {
  const int tid = threadIdx.x;
  const int lane = tid & 63, wid = tid >> 6;
  const int wm = wid >> 1, wn = wid & 1;
  const int l15 = lane & 15, l4 = lane >> 4;
  const int t0 = blockIdx.x * 128;

  f32x4 acc[4][4];
  #pragma unroll
  for (int mt = 0; mt < 4; ++mt)
    #pragma unroll
    for (int nt = 0; nt < 4; ++nt)
      #pragma unroll
      for (int r = 0; r < 4; ++r) acc[mt][nt][r] = 0.f;

  #pragma unroll
  for (int ks = 0; ks < 4; ++ks) {
    const int kb = ks * 32 + l4 * 8;
    short8 a[4], bfr[4];
    #pragma unroll
    for (int mt = 0; mt < 4; ++mt) {
      const int o = wm * 64 + mt * 16 + l15;
      a[mt] = *(const short8*)(Wp + (size_t)o * 128 + kb);
    }
    #pragma unroll
    for (int nt = 0; nt < 4; ++nt) {
      const int tok = t0 + wn * 64 + nt * 16 + l15;
      const size_t off = (size_t)tok * 128 + kb;
      short8 s0 = *(const short8*)(A0b + off);
      short8 s1 = *(const short8*)(A1b + off);
      short8 s2 = *(const short8*)(A2b + off);
      short8 r;
      #pragma unroll
      for (int i = 0; i < 8; ++i) {
        float f = bf2f((unsigned short)s0[i]) + bf2f((unsigned short)s1[i]) +
                  bf2f((unsigned short)s2[i]);
        r[i] = (short)f2bf(f);
      }
      bfr[nt] = r;
    }
    #pragma unroll
    for (int mt = 0; mt < 4; ++mt)
      #pragma unroll
      for (int nt = 0; nt < 4; ++nt)
        acc[mt][nt] = __builtin_amdgcn_mfma_f32_16x16x32_bf16(a[mt], bfr[nt], acc[mt][nt], 0, 0, 0);
  }

  #pragma unroll
  for (int nt = 0; nt < 4; ++nt) {
    const int tok = t0 + wn * 64 + nt * 16 + l15;
    const int dhw = tok & 32767, bB = tok >> 15;
    #pragma unroll
    for (int mt = 0; mt < 4; ++mt) {
      #pragma unroll
      for (int r = 0; r < 4; ++r) {
        const int o = wm * 64 + mt * 16 + l4 * 4 + r;
        out[((size_t)(bB * 128 + o) << 15) + dhw] = acc[mt][nt][r] + bias[o];
      }
    }
  }
}

// ---------------------------------------------------------------------------
// K7: axial attention via MFMA, v4. One 512-thread block per (seq, axial);
// 8 waves = 8 heads. LDS: Ot overlays the dead staging buffer (55->35 KB,
// 2->4 blocks/CU). One extra barrier separates last rows-read from Ot-write.
// ---------------------------------------------------------------------------
__global__ __launch_bounds__(512) void attn_mfma_kernel(
    const unsigned short* __restrict__ qkvt, const float* __restrict__ Rbuf,
    const float* __restrict__ pbw, unsigned short* __restrict__ a0,
    unsigned short* __restrict__ a1, unsigned short* __restrict__ a2) {
  __shared__ char shb[32 * 784];             // rows staging -> Ot (overlay)
  __shared__ unsigned short Vt[8][16 * 40];  // per-head [d][tok]
  unsigned short* rows = (unsigned short*)shb;   // pitch 392 ush
  float* OtA = (float*)shb;                      // [head*640 + q*20 + tok]
  const int axial = blockIdx.y;
  const int seq = blockIdx.x;
  unsigned short* dstbuf = (axial == 0) ? a0 : ((axial == 1) ? a1 : a2);
  const int tid = threadIdx.x;
  const int lane = tid & 63, head = tid >> 6;
  const int tok = lane & 31, hi = lane >> 5;
  const int b = seq >> 10, rem = seq & 1023;
  const int u = rem >> 5, v = rem & 31;
  int base, stride, comp;
  if (axial == 0)      { base = (b << 15) + (u << 5) + v;         stride = 1024; comp = 2; }
  else if (axial == 1) { base = (b << 15) + (u << 10) + v;        stride = 32;   comp = 1; }
  else                 { base = (b << 15) + (u << 10) + (v << 5); stride = 1;    comp = 0; }

  #pragma unroll
  for (int p = 0; p < 3; ++p) {
    const int c = p * 512 + tid;
    const int r = c / 48, cw = c - r * 48;
    const size_t src = ((size_t)base + (size_t)r * stride) * 384 + (size_t)cw * 8;
    *(uint4*)((char*)rows + r * 784 + cw * 16) = *(const uint4*)(qkvt + src);
  }
  __syncthreads();

  const float* Rp = Rbuf + (axial * 8 + head) * 18;
  const float rq00 = fabsf(Rp[0]);
  const unsigned short* myrow = rows + tok * 392 + head * 48;
  short8 aq = *(const short8*)(myrow + hi * 8);
  short8 ak = *(const short8*)(myrow + 16 + hi * 8);
  short8 av = *(const short8*)(myrow + 32 + hi * 8);
  if (hi) {
    aq[7] = (short)f2bf(bf2f((unsigned short)aq[7]) * rq00);
    ak[7] = (short)f2bf(bf2f((unsigned short)ak[7]) * rq00);
  }
  #pragma unroll
  for (int e = 0; e < 8; ++e) Vt[head][(hi * 8 + e) * 40 + tok] = (unsigned short)av[e];
  __syncthreads();  // all rows reads complete; shb may now be reused as Ot

  f32x16 sacc;
  #pragma unroll
  for (int r = 0; r < 16; ++r) sacc[r] = 0.f;
  sacc = __builtin_amdgcn_mfma_f32_32x32x16_bf16(ak, aq, sacc, 0, 0, 0);
  const float wb = pbw[comp];
  float p[16];
  float mmax = -1e30f;
  #pragma unroll
  for (int r = 0; r < 16; ++r) {
    const int kk = (r & 3) + 4 * hi + 8 * (r >> 2);
    const float lin = -1.0f + (2.0f / 31.0f) * (float)kk;
    p[r] = sacc[r] * 0.25f - lin * wb;
    mmax = fmaxf(mmax, p[r]);
  }
  mmax = fmaxf(mmax, __shfl_xor(mmax, 32));
  float sum = 0.f;
  #pragma unroll
  for (int r = 0; r < 16; ++r) { p[r] = expf(p[r] - mmax); sum += p[r]; }
  sum += __shfl_xor(sum, 32);
  const float inv = 1.0f / sum;
  #pragma unroll
  for (int r = 0; r < 16; ++r) p[r] *= inv;
  unsigned pk[8], sw[8];
  #pragma unroll
  for (int j = 0; j < 8; ++j) {
    unsigned r_;
    asm("v_cvt_pk_bf16_f32 %0, %1, %2" : "=v"(r_) : "v"(p[2 * j]), "v"(p[2 * j + 1]));
    pk[j] = r_;
  }
  #pragma unroll
  for (int j = 0; j < 8; ++j) sw[j] = (unsigned)__shfl_xor((int)pk[j], 32);
  uint4 Fu, Gu;
  Fu.x = hi ? sw[2] : pk[0];
  Fu.y = hi ? sw[3] : pk[1];
  Fu.z = hi ? pk[2] : sw[0];
  Fu.w = hi ? pk[3] : sw[1];
  Gu.x = hi ? sw[6] : pk[4];
  Gu.y = hi ? sw[7] : pk[5];
  Gu.z = hi ? pk[6] : sw[4];
  Gu.w = hi ? pk[7] : sw[5];
  short8 Pf = *(short8*)&Fu;
  short8 Pg = *(short8*)&Gu;
  const unsigned short* vrow = Vt[head] + (tok & 15) * 40;
  short8 Bv0 = *(const short8*)(vrow + hi * 8);
  short8 Bv1 = *(const short8*)(vrow + 16 + hi * 8);
  f32x16 oacc;
  #pragma unroll
  for (int r = 0; r < 16; ++r) oacc[r] = 0.f;
  oacc = __builtin_amdgcn_mfma_f32_32x32x16_bf16(Pf, Bv0, oacc, 0, 0, 0);
  oacc = __builtin_amdgcn_mfma_f32_32x32x16_bf16(Pg, Bv1, oacc, 0, 0, 0);
  if (tok < 16) {
    #pragma unroll
    for (int r = 0; r < 16; ++r) {
      const int q = (r & 3) + 4 * hi + 8 * (r >> 2);
      OtA[head * 640 + q * 20 + tok] = oacc[r];
    }
  }
  // OtA[head] written & read by the same wave: same-wave LDS ordering suffices
  if (lane < 32) {
    float o16[16], y16[16], Rv[9];
    #pragma unroll
    for (int j = 0; j < 16; ++j) o16[j] = OtA[head * 640 + lane * 20 + j];
    #pragma unroll
    for (int i = 0; i < 9; ++i) Rv[i] = Rp[9 + i];
    rot16(Rv, o16, y16);
    unsigned outw[8];
    #pragma unroll
    for (int j = 0; j < 8; ++j)
      outw[j] = ((unsigned)f2bf(y16[2 * j + 1]) << 16) | (unsigned)f2bf(y16[2 * j]);
    const size_t t2 = (size_t)base + (size_t)lane * stride;
    unsigned short* dst = dstbuf + t2 * 128 + head * 16;
    uint4 o0 = {outw[0], outw[1], outw[2], outw[3]};
    uint4 o1 = {outw[4], outw[5], outw[6], outw[7]};
    *(uint4*)dst = o0;
    *(uint4*)(dst + 8) = o1;
  }
}

// ---------------------------------------------------------------------------
extern "C" void kernel_launch(void* const* d_in, const int* in_sizes, int n_in,
                              void* d_out, int out_size, void* d_ws, size_t ws_size,
                              hipStream_t stream) {
  const float* x       = (const float*)d_in[0];
  const float* pos_emb = (const float*)d_in[1];
  const float* qkv_w   = (const float*)d_in[2];
  const float* qkv_b   = (const float*)d_in[3];
  const float* lp_w1   = (const float*)d_in[4];
  const float* lp_b1   = (const float*)d_in[5];
  const float* lp_w2   = (const float*)d_in[6];
  const float* lp_b2   = (const float*)d_in[7];
  const float* mod_w1  = (const float*)d_in[8];
  const float* mod_b1  = (const float*)d_in[9];
  const float* mod_w2  = (const float*)d_in[10];
  const float* mod_b2  = (const float*)d_in[11];
  // d_in[12] pa_w, d_in[13] pa_b: cancel in softmax (constant along key axis)
  const float* proj_w  = (const float*)d_in[14];
  const float* proj_b  = (const float*)d_in[15];
  const float* pbw     = (const float*)d_in[16];
  // d_in[17] pos_bias_b: cancels in softmax
  const float* Ad      = (const float*)d_in[18];
  const float* Ah      = (const float*)d_in[19];
  const float* Aw      = (const float*)d_in[20];
  const float* Rd      = (const float*)d_in[21];
  const float* Rh      = (const float*)d_in[22];
  const float* Rw      = (const float*)d_in[23];
  // d_in[24..26] t_d/t_h/t_w: cancel in rel (pairwise difference)

  float* ws = (float*)d_ws;
  unsigned short* lfb    = (unsigned short*)(ws + WS_R0);   // lf bf16
  unsigned short* A0b    = (unsigned short*)(ws + WS_A0);
  unsigned short* A1b    = (unsigned short*)(ws + WS_A1);
  unsigned short* A2b    = (unsigned short*)(ws + WS_A2);
  unsigned short* mpreb  = (unsigned short*)(ws + WS_MPREB);
  unsigned short* xtokb  = (unsigned short*)(ws + WS_XTOKB);
  unsigned short* inT    = (unsigned short*)(ws + WS_INT);
  unsigned short* qkvt   = (unsigned short*)(ws + WS_QKVH);
  unsigned short* convP  = (unsigned short*)(ws + WS_CONVP);
  unsigned short* qkvP   = (unsigned short*)(ws + WS_QKVP);
  unsigned short* WcP    = (unsigned short*)(ws + WS_WCP);
  unsigned short* modw2P = (unsigned short*)(ws + WS_MODW2P);
  unsigned short* projP  = (unsigned short*)(ws + WS_PROJP);
  float* bc     = ws + WS_BC;
  float* Rbuf   = ws + WS_RBUF;
  float* ps     = ws + WS_PS;
  float* pss    = ws + WS_PSS;
  float* mu1    = ws + WS_MU1;
  float* rs1    = ws + WS_RS1;
  float* mu2    = ws + WS_MU2;
  float* rs2    = ws + WS_RS2;

  // merged prep + transposes
  prep_transpose_kernel<<<2304, 256, 0, stream>>>(
      lp_w1, qkv_w, mod_w1, lp_w2, lp_b2, mod_b1, mod_w2, proj_w,
      Ad, Ah, Aw, Rd, Rh, Rw, x, pos_emb,
      convP, qkvP, WcP, modw2P, projP, bc, Rbuf, xtokb, inT);
  // lf (bf16) = circular conv3x3x3(pos_emb), fused fp32 stats partials
  conv_mfma_kernel<<<1024, 256, 0, stream>>>(inT, convP, lp_b1, lfb, ps, pss);
  stats_final_kernel<<<256, 64, 0, stream>>>(ps, pss, mu1, rs1, 512);
  // m_pre (bf16) = gelu(inorm(lf)) @ Wc^T + bc (LDS-dedup gelu, fused stats)
  wc_mfma_kernel<<<512, 256, 0, stream>>>(lfb, WcP, bc, mpreb, mu1, rs1, ps, pss);
  stats_final_kernel<<<256, 64, 0, stream>>>(ps, pss, mu2, rs2, 256);
  // fused: ga = gelu(inorm(mpre)) (LDS, once); x_mod (LDS); qkv (bf16)
  gateqkv_mfma_kernel<<<512, 256, 0, stream>>>(
      mpreb, modw2P, mod_b2, xtokb, qkvP, qkv_b, qkvt, mu2, rs2);
  // attention: one 512-thread block per (seq, axial), 8 heads in-block
  attn_mfma_kernel<<<dim3(2048, 3), 512, 0, stream>>>(qkvt, Rbuf, pbw, A0b, A1b, A2b);
  proj_mfma_kernel<<<512, 256, 0, stream>>>(A0b, A1b, A2b, projP, proj_b, (float*)d_out);
}